// Round 3
// baseline (358.758 us; speedup 1.0000x reference)
//
#include <hip/hip_runtime.h>
#include <math.h>

// Sizes (fixed for this problem)
#define B 2
#define T 2048
#define H 1024
#define NH 16
#define HD 64
#define FF 4096
#define M_TOK (B*T)          // 4096 token rows
#define LOG2E 1.4426950408889634f

typedef unsigned short u16;
typedef __attribute__((ext_vector_type(8))) short bf16x8;
typedef __attribute__((ext_vector_type(4))) float f32x4;

// counted-vmcnt barrier: wait until only N of this wave's vmem ops remain,
// then workgroup barrier. Single asm with "memory" clobber so no memory op
// (gload_lds / ds_read) is reordered across it.
// NOTE (r8-r10 lesson): counted-vmcnt pipelines are only safe when EVERY
// LDS buffer is >=3 slots deep (overwrite target >=2 iterations stale).
// NOTE (R2 lesson): direct-to-register global V loads regress badly — the
// strided fragment pattern (rows T apart) turns each wave load into 16
// scattered L1 lines; keep V in LDS.
#define WAITBAR3  asm volatile("s_waitcnt vmcnt(3)\n\ts_barrier" ::: "memory")
#define WAITBAR4  asm volatile("s_waitcnt vmcnt(4)\n\ts_barrier" ::: "memory")
#define WAITBAR0  asm volatile("s_waitcnt vmcnt(0)\n\ts_barrier" ::: "memory")

__device__ __forceinline__ u16 f2bf(float f) {
  union { float f; unsigned u; } v; v.f = f;
  const unsigned r = (v.u + 0x7FFFu + ((v.u >> 16) & 1u)) >> 16;
  return (u16)r;
}
__device__ __forceinline__ float bf2f(u16 h) {
  union { unsigned u; float f; } v; v.u = ((unsigned)h) << 16;
  return v.f;
}
__device__ __forceinline__ unsigned cvt_pk_bf16(float lo, float hi) {
  unsigned r;
  asm("v_cvt_pk_bf16_f32 %0, %1, %2" : "=v"(r) : "v"(lo), "v"(hi));
  return r;
}
__device__ __forceinline__ float m3(float a, float b, float c) {
  return fmaxf(fmaxf(a, b), c);      // clang fuses to v_max3_f32
}
// async global->LDS, 16B per lane; dest = wave-uniform base + lane*16
__device__ __forceinline__ void gload16(const u16* g, u16* l) {
  __builtin_amdgcn_global_load_lds(
      (const __attribute__((address_space(1))) unsigned int*)g,
      (__attribute__((address_space(3))) unsigned int*)l, 16, 0, 0);
}

// ---------------------------------------------------------------------------
// split fp32 -> bf16 hi + bf16 lo (Dekker split; hi+lo ~ fp32 accurate)
// ---------------------------------------------------------------------------
__global__ __launch_bounds__(256) void split_hl(
    const float* __restrict__ in, u16* __restrict__ oh, u16* __restrict__ ol)
{
  const size_t i = ((size_t)blockIdx.x * 256 + threadIdx.x) * 4;
  const float4 v = *(const float4*)(in + i);
  union { u16 s[4]; uint2 u; } h, l;
  const float f[4] = {v.x, v.y, v.z, v.w};
#pragma unroll
  for (int j = 0; j < 4; ++j) {
    const u16 hb = f2bf(f[j]); h.s[j] = hb; l.s[j] = f2bf(f[j] - bf2f(hb));
  }
  *(uint2*)(oh + i) = h.u;
  *(uint2*)(ol + i) = l.u;
}

// ---------------------------------------------------------------------------
// transpose-convert: in [K][N] fp32 -> out [N][K] bf16 (hi, + lo if SPLIT)
// ---------------------------------------------------------------------------
template<int SPLIT>
__global__ __launch_bounds__(256) void transpose_bf16(
    const float* __restrict__ in, u16* __restrict__ oh, u16* __restrict__ ol,
    int K, int N)
{
  __shared__ float tile[64][69];
  const int k0 = blockIdx.y * 64, n0 = blockIdx.x * 64;
  const int tid = threadIdx.x;
  const int r = tid >> 4, c4 = (tid & 15) * 4;
#pragma unroll
  for (int i = 0; i < 4; ++i) {
    const float4 v = *(const float4*)(in + (size_t)(k0 + i*16 + r) * N + n0 + c4);
    tile[i*16+r][c4]   = v.x; tile[i*16+r][c4+1] = v.y;
    tile[i*16+r][c4+2] = v.z; tile[i*16+r][c4+3] = v.w;
  }
  __syncthreads();
  const int n = tid >> 2, kq = tid & 3;
  union { u16 s[8]; int4 v; } ph0, ph1, pl0, pl1;
#pragma unroll
  for (int j = 0; j < 8; ++j) {
    const float f0 = tile[kq*16 + j][n];
    const float f1 = tile[kq*16 + 8 + j][n];
    const u16 h0 = f2bf(f0), h1 = f2bf(f1);
    ph0.s[j] = h0; ph1.s[j] = h1;
    if (SPLIT) { pl0.s[j] = f2bf(f0 - bf2f(h0)); pl1.s[j] = f2bf(f1 - bf2f(h1)); }
  }
  u16* po = oh + (size_t)(n0 + n) * K + k0 + kq * 16;
  *(int4*)po = ph0.v; *(int4*)(po + 8) = ph1.v;
  if (SPLIT) {
    u16* pl = ol + (size_t)(n0 + n) * K + k0 + kq * 16;
    *(int4*)pl = pl0.v; *(int4*)(pl + 8) = pl1.v;
  }
}

// ---------------------------------------------------------------------------
// MFMA GEMM: C[M,N] = (A @ B^T) * bias[N]  (A [M][K] bf16, B [N][K] bf16)
// 128x128 tile, BK=32, global_load_lds staging, XCD-chunked 1-D grid.
// DEEP3 (non-split only): 3-slot LDS + counted vmcnt(4) barriers. 24KB.
// SPLIT: 2-phase double-buffered (__syncthreads drains vmcnt -> safe).
// PARTIAL: split-K=2 over blockIdx.y; raw fp32 partials (no bias/relu).
// QKV3: V fragments (qkv k-index 2) skip the hi/lo correction MFMAs, and
//       their Bl staging chunks are skipped entirely (never read).
// ---------------------------------------------------------------------------
__device__ __forceinline__ int swz(int r, int kq) {
  return r * 32 + ((kq ^ ((r >> 1) & 3)) * 8);
}

template<int SPLIT, int RELU, int OBF, int QKV3, int DEEP3, int PARTIAL>
__global__ __launch_bounds__(256) void mfma_gemm(
    const u16* __restrict__ Ah, const u16* __restrict__ Al,
    const u16* __restrict__ Bh, const u16* __restrict__ Bl,
    const float* __restrict__ bias,
    float* __restrict__ Cf, u16* __restrict__ Cb,
    int M, int N, int K)
{
  __shared__ u16 lds[DEEP3 ? 24576 : (SPLIT ? 32768 : 16384)];
  const int BUFSZ = SPLIT ? 16384 : 8192;
  const int tid = threadIdx.x;
  // XCD-chunked decode: xcd=bid&7 owns M-panels [4*xcd, 4*xcd+4)
  const int bid = blockIdx.x;
  const int xcd = bid & 7;
  const int idx = bid >> 3;
  const int row0 = (xcd * 4 + (idx & 3)) * 128;
  const int col0 = (idx >> 2) * 128;
  const int wv = tid >> 6, lane = tid & 63;
  const int wr = wv >> 1, wc = wv & 1;
  const int kq = lane >> 4, fr = lane & 15;

  int kb = 0, kE = K;
  if (PARTIAL) {
    const int khf = blockIdx.y;
    kb = khf * (K >> 1); kE = kb + (K >> 1);
    Cf += (size_t)khf * ((size_t)M * N);
  }

  f32x4 acc[4][4] = {};

  // stage one 128x32 bf16 array (8 chunks of 1KB); wave wv does chunks 2wv,2wv+1
#define GSTAGE(lbase, gb, rowbase, kk) do { \
    _Pragma("unroll") \
    for (int t_ = 0; t_ < 2; ++t_) { \
      const int c_ = wv * 2 + t_; \
      const int idx_ = c_ * 64 + lane; \
      const int r_ = idx_ >> 2; \
      const int kq_ = (idx_ & 3) ^ ((r_ >> 1) & 3); \
      gload16((gb) + (size_t)((rowbase) + r_) * K + (kk) + kq_ * 8, \
              &lds[(lbase) + c_ * 512]); \
    } } while (0)

  // Bl staging with V-group chunk skip (chunk c covers 16-col group
  // (col0>>4)+c; k-index %3==2 groups never read their b_l fragments).
#define BLSTAGE(lbase, kk) do { \
    _Pragma("unroll") \
    for (int t_ = 0; t_ < 2; ++t_) { \
      const int c_ = wv * 2 + t_; \
      if (!QKV3 || ((((col0 >> 4) + c_) % 3) != 2)) { \
        const int idx_ = c_ * 64 + lane; \
        const int r_ = idx_ >> 2; \
        const int kq_ = (idx_ & 3) ^ ((r_ >> 1) & 3); \
        gload16(Bl + (size_t)(col0 + r_) * K + (kk) + kq_ * 8, \
                &lds[(lbase) + c_ * 512]); \
      } } } while (0)

  if (DEEP3) {
    // ---- 3-deep counted-vmcnt pipeline (non-split only; all slots 3-deep,
    // overwrite target is 2 iterations stale -> no write-after-read hazard) ----
    const int nk = (kE - kb) >> 5;
    GSTAGE(0, Ah, row0, kb);            GSTAGE(4096, Bh, col0, kb);
    GSTAGE(8192, Ah, row0, kb + 32);    GSTAGE(8192 + 4096, Bh, col0, kb + 32);
    WAITBAR4;                            // stage 0 ready; stage 1 in flight
    int cslot = 0, islot = 2;
    for (int i = 0; i < nk; ++i) {
      if (i + 2 < nk) {
        const int kk = kb + (i + 2) * 32;
        GSTAGE(islot * 8192, Ah, row0, kk);
        GSTAGE(islot * 8192 + 4096, Bh, col0, kk);
        islot = (islot == 2) ? 0 : islot + 1;
      }
      const int rb = cslot * 8192;
      bf16x8 a_h[4];
#pragma unroll
      for (int m = 0; m < 4; ++m)
        a_h[m] = *(const bf16x8*)&lds[rb + swz(wr*64 + m*16 + fr, kq)];
#pragma unroll
      for (int n = 0; n < 4; ++n) {
        const bf16x8 b_h = *(const bf16x8*)&lds[rb + 4096 + swz(wc*64 + n*16 + fr, kq)];
#pragma unroll
        for (int m = 0; m < 4; ++m)
          acc[m][n] = __builtin_amdgcn_mfma_f32_16x16x32_bf16(a_h[m], b_h, acc[m][n], 0, 0, 0);
      }
      cslot = (cslot == 2) ? 0 : cslot + 1;
      if (i + 1 < nk) { if (i + 2 < nk) WAITBAR4; else WAITBAR0; }
    }
  } else {
    // ---- 2-phase double-buffered (__syncthreads drains all counters) ----
    GSTAGE(0, Ah, row0, kb);
    GSTAGE(4096, Bh, col0, kb);
    if (SPLIT) { GSTAGE(8192, Al, row0, kb); BLSTAGE(12288, kb); }
    __syncthreads();

    int cur = 0;
    for (int k0 = kb; k0 < kE; k0 += 32) {
      const int nxt = cur ^ 1;
      if (k0 + 32 < kE) {
        GSTAGE(nxt*BUFSZ, Ah, row0, k0 + 32);
        GSTAGE(nxt*BUFSZ + 4096, Bh, col0, k0 + 32);
        if (SPLIT) { GSTAGE(nxt*BUFSZ + 8192, Al, row0, k0 + 32);
                     BLSTAGE(nxt*BUFSZ + 12288, k0 + 32); }
      }
      const int rb = cur * BUFSZ;
      bf16x8 a_h[4], a_l[4];
#pragma unroll
      for (int m = 0; m < 4; ++m) {
        a_h[m] = *(const bf16x8*)&lds[rb + swz(wr*64 + m*16 + fr, kq)];
        if (SPLIT) a_l[m] = *(const bf16x8*)&lds[rb + 8192 + swz(wr*64 + m*16 + fr, kq)];
      }
#pragma unroll
      for (int n = 0; n < 4; ++n) {
        const bf16x8 b_h = *(const bf16x8*)&lds[rb + 4096 + swz(wc*64 + n*16 + fr, kq)];
#pragma unroll
        for (int m = 0; m < 4; ++m)
          acc[m][n] = __builtin_amdgcn_mfma_f32_16x16x32_bf16(a_h[m], b_h, acc[m][n], 0, 0, 0);
        if (SPLIT) {
          const bool dolo = !QKV3 || ((((col0 >> 4) + wc * 4 + n) % 3) != 2);
          if (dolo) {
            const bf16x8 b_l = *(const bf16x8*)&lds[rb + 12288 + swz(wc*64 + n*16 + fr, kq)];
#pragma unroll
            for (int m = 0; m < 4; ++m) {
              acc[m][n] = __builtin_amdgcn_mfma_f32_16x16x32_bf16(a_h[m], b_l, acc[m][n], 0, 0, 0);
              acc[m][n] = __builtin_amdgcn_mfma_f32_16x16x32_bf16(a_l[m], b_h, acc[m][n], 0, 0, 0);
            }
          }
        }
      }
      __syncthreads();
      cur = nxt;
    }
  }
#undef GSTAGE
#undef BLSTAGE

  const int orow0 = row0 + wr * 64, ocol0 = col0 + wc * 64;
#pragma unroll
  for (int n = 0; n < 4; ++n) {
    const int col = ocol0 + n * 16 + fr;
    const float bs = PARTIAL ? 1.0f : bias[col];
#pragma unroll
    for (int m = 0; m < 4; ++m) {
      const int rbase = orow0 + m * 16 + (lane >> 4) * 4;
#pragma unroll
      for (int j = 0; j < 4; ++j) {
        float v = acc[m][n][j] * bs;
        if (RELU) v = fmaxf(v, 0.0f);
        const size_t off = (size_t)(rbase + j) * N + col;
        if (OBF) Cb[off] = f2bf(v); else Cf[off] = v;
      }
    }
  }
}

// ---------------------------------------------------------------------------
// Repack qkv [B,T,3072] -> bf16 arrays: Qh/Ql (scaled by log2e/32, split),
// Kh/Kl (split), Vb (bf16), all [B*NH][T][HD]. Channel o = d*48 + k*16 + h.
// ---------------------------------------------------------------------------
__global__ __launch_bounds__(256) void repack_qkv(
    const float* __restrict__ qkv,
    u16* __restrict__ Qh, u16* __restrict__ Ql,
    u16* __restrict__ Kh, u16* __restrict__ Kl, u16* __restrict__ Vb)
{
  const int bt = blockIdx.x;
  const int b = bt >> 11, t = bt & (T - 1);
  const int tid = threadIdx.x;
  __shared__ float Ls[3 * H];
  const float* src = qkv + (size_t)bt * (3 * H);
#pragma unroll
  for (int i = 0; i < 3; ++i) {
    const int c4 = i * 256 + tid;
    *(float4*)&Ls[c4 * 4] = *(const float4*)(src + c4 * 4);
  }
  __syncthreads();
  const float qscale = LOG2E / 32.0f;
#pragma unroll
  for (int i = 0; i < 4; ++i) {
    const int j = i * 256 + tid;
    const int h = j >> 6, d = j & 63;
    const size_t dst = (((size_t)(b * NH + h)) * T + t) * HD + d;
    const float q = Ls[d * 48 + h] * qscale;
    const u16 qhb = f2bf(q);
    Qh[dst] = qhb; Ql[dst] = f2bf(q - bf2f(qhb));
    const float k = Ls[d * 48 + 16 + h];
    const u16 khb = f2bf(k);
    Kh[dst] = khb; Kl[dst] = f2bf(k - bf2f(khb));
    Vb[dst] = f2bf(Ls[d * 48 + 32 + h]);
  }
}

// ---------------------------------------------------------------------------
// Vb [bh][T][HD] bf16 -> VT [bh][HD][T] bf16 (64x64 tiles via LDS)
// ---------------------------------------------------------------------------
__global__ __launch_bounds__(256) void vtrans(
    const u16* __restrict__ Vb, u16* __restrict__ VT)
{
  __shared__ u16 Ls[64][72];
  const int bh = blockIdx.y, t0 = blockIdx.x * 64;
  const int tid = threadIdx.x;
  const int r = tid >> 2, c = (tid & 3) * 16;
  const size_t src = ((size_t)bh * T + t0 + r) * HD + c;
  *(int4*)&Ls[r][c]     = *(const int4*)(Vb + src);
  *(int4*)&Ls[r][c + 8] = *(const int4*)(Vb + src + 8);
  __syncthreads();
  const int d = tid >> 2, tc = (tid & 3) * 16;
  u16 buf[16];
#pragma unroll
  for (int i = 0; i < 16; ++i) buf[i] = Ls[tc + i][d];
  u16* dst = VT + ((size_t)bh * HD + d) * T + t0 + tc;
  *(int4*)dst       = *(int4*)&buf[0];
  *(int4*)(dst + 8) = *(int4*)&buf[8];
}

// ---------------------------------------------------------------------------
// sigma: LDS K-row r holds key sigma(r) so that the QK^T C-layout hands each
// lane exactly the 8-consecutive-key fragments PV's B-operand needs.
// ---------------------------------------------------------------------------
__device__ __forceinline__ int sigma_k(int r) {
  return ((r >> 5) << 5) | (((r >> 2) & 3) << 3) | (((r >> 4) & 1) << 2) | (r & 3);
}

// ---------------------------------------------------------------------------
// MFMA flash attention, swapped-operand, SPLIT-KV=2.
// 8 waves x 32 q-rows (512 threads, 2 q-frags/wave so K/V LDS reads are
// amortized over 2x the rows — R2 lesson: 16-row waves made LDS the 66%-busy
// bottleneck). Block covers 256 q-rows and HALF the KV range (blockIdx.y);
// grid (256,2) -> 2 blocks/CU -> 16 waves/CU (4/SIMD). Writes UNNORMALIZED
// partial O + per-row (m, lsum); merge happens fused in ln_residual_att.
// K hi/lo + VT staged in LDS, 3-deep counted-vmcnt pipeline (24KB/slot,
// 72KB total). XCD-clustered grid; defer-max (THR=8); lsum via ones-A MFMA.
// ---------------------------------------------------------------------------
__global__ __launch_bounds__(512, 4) void flash_attn_mfma(
    const u16* __restrict__ Qh, const u16* __restrict__ Ql,
    const u16* __restrict__ Kh, const u16* __restrict__ Kl,
    const u16* __restrict__ VT, float* __restrict__ Pp,
    float* __restrict__ Ms, float* __restrict__ Lsum)
{
  __shared__ u16 sm[3 * 12288];  // slot: KH [0,4K) | KL [4K,8K) | VT [8K,12K) u16
  // XCD-clustered decode: xcd = i&7 owns heads 4*xcd..4*xcd+3
  const int i = blockIdx.x;          // 256 = 32 bh x 8 row-chunks
  const int hf = blockIdx.y;         // KV half
  const int slot = i >> 3;
  const int bh = (i & 7) * 4 + (slot >> 3);
  const int row0 = (slot & 7) * 256;
  const int tid = threadIdx.x, wave = tid >> 6, lane = tid & 63;
  const int fr = lane & 15, kq = lane >> 4;

  // Q fragments (B-operand: col=q=fr, k=d=kq*8 within ks*32); wave owns
  // q-rows [row0 + wave*32, +32), two 16-row frags qf=0,1
  bf16x8 qh[2][2], ql[2][2];
#pragma unroll
  for (int qf = 0; qf < 2; ++qf) {
    const size_t qoff = ((size_t)bh * T + row0 + wave*32 + qf*16 + fr) * HD + kq*8;
#pragma unroll
    for (int ks = 0; ks < 2; ++ks) {
      qh[qf][ks] = *(const bf16x8*)(Qh + qoff + ks*32);
      ql[qf][ks] = *(const bf16x8*)(Ql + qoff + ks*32);
    }
  }

  bf16x8 ones8;
#pragma unroll
  for (int z = 0; z < 8; ++z) ones8[z] = (short)0x3F80;

  f32x4 o[2][4] = {};
  f32x4 oex[2] = {};                       // lsum accumulators (all 4 rows equal)
  float m_[2] = {-1e30f, -1e30f};

  // staging: wave w stages chunk w (1KB) of each of the 3 arrays (8 waves
  // cover the 8 chunks). Global pointers advance by a constant per KV tile.
  const int c_ = wave;
  const int r0_ = c_ * 8 + (lane >> 3), s_ = lane & 7;
  const int cd0 = s_ ^ (r0_ & 7);
  const int k0_ = sigma_k(r0_);
  const int kvbase = hf * (T / 2);
  const u16* pKh0 = Kh + ((size_t)bh*T + kvbase + k0_)*HD + cd0*8;
  const u16* pKl0 = Kl + ((size_t)bh*T + kvbase + k0_)*HD + cd0*8;
  const u16* pV0  = VT + ((size_t)bh*HD + r0_)*T + kvbase + cd0*8;

#define FSTAGE(sb) do { \
    gload16(pKh0, &sm[(sb) + c_*512]); \
    gload16(pKl0, &sm[(sb) + 4096 + c_*512]); \
    gload16(pV0,  &sm[(sb) + 8192 + c_*512]); \
    pKh0 += 64*HD; pKl0 += 64*HD; pV0 += 64; \
  } while (0)

  FSTAGE(0);
  FSTAGE(12288);
  WAITBAR3;                  // tile 0 ready (3 loads/wave); tile 1 in flight
  int cslot = 0, islot = 2;

  const int NT = (T / 2) / 64;             // 16 tiles per KV half
  for (int t = 0; t < NT; ++t) {
    if (t + 2 < NT) {
      FSTAGE(islot * 12288);
      islot = (islot == 2) ? 0 : islot + 1;
    }
    const u16* smb = &sm[cslot * 12288];

    // ---- QK^T (swapped): s[qf][n], keys sigma(16n+4kq+jj), q=fr
    f32x4 s[2][4] = {};
    __builtin_amdgcn_s_setprio(1);
#pragma unroll
    for (int ks = 0; ks < 2; ++ks) {
#pragma unroll
      for (int n = 0; n < 4; ++n) {
        const int kr = n * 16 + fr;
        const int sl = ((ks*4 + kq) ^ (kr & 7)) * 8;
        const bf16x8 kh_ = *(const bf16x8*)&smb[kr*64 + sl];
        const bf16x8 kl_ = *(const bf16x8*)&smb[4096 + kr*64 + sl];
        s[0][n] = __builtin_amdgcn_mfma_f32_16x16x32_bf16(kh_, qh[0][ks], s[0][n], 0, 0, 0);
        s[1][n] = __builtin_amdgcn_mfma_f32_16x16x32_bf16(kh_, qh[1][ks], s[1][n], 0, 0, 0);
        s[0][n] = __builtin_amdgcn_mfma_f32_16x16x32_bf16(kl_, qh[0][ks], s[0][n], 0, 0, 0);
        s[1][n] = __builtin_amdgcn_mfma_f32_16x16x32_bf16(kl_, qh[1][ks], s[1][n], 0, 0, 0);
        s[0][n] = __builtin_amdgcn_mfma_f32_16x16x32_bf16(kh_, ql[0][ks], s[0][n], 0, 0, 0);
        s[1][n] = __builtin_amdgcn_mfma_f32_16x16x32_bf16(kh_, ql[1][ks], s[1][n], 0, 0, 0);
      }
    }
    __builtin_amdgcn_s_setprio(0);

    // ---- hoist V^T fragments (shared by both q-frags)
    bf16x8 vf[2][4];
#pragma unroll
    for (int ks = 0; ks < 2; ++ks)
#pragma unroll
      for (int n = 0; n < 4; ++n) {
        const int dr = n * 16 + fr;
        vf[ks][n] = *(const bf16x8*)&smb[8192 + dr*64 + (((ks*4 + kq) ^ (dr & 7)) * 8)];
      }

    // ---- per q-frag: defer-max softmax + in-reg P -> PV (+ lsum MFMA)
#pragma unroll
    for (int qf = 0; qf < 2; ++qf) {
      const float g0 = m3(s[qf][0][0], s[qf][0][1], s[qf][0][2]);
      const float g1 = m3(s[qf][0][3], s[qf][1][0], s[qf][1][1]);
      const float g2 = m3(s[qf][1][2], s[qf][1][3], s[qf][2][0]);
      const float g3 = m3(s[qf][2][1], s[qf][2][2], s[qf][2][3]);
      const float g4 = m3(s[qf][3][0], s[qf][3][1], s[qf][3][2]);
      float mx = fmaxf(m3(g0, g1, g2), m3(g3, g4, s[qf][3][3]));
      mx = fmaxf(mx, __shfl_xor(mx, 16));
      mx = fmaxf(mx, __shfl_xor(mx, 32));
      if (!__all(mx <= m_[qf] + 8.0f)) {      // record tile (~10%): rescale
        const float mn = fmaxf(m_[qf], mx);
        const float fsc = exp2f(m_[qf] - mn);
        m_[qf] = mn;
#pragma unroll
        for (int n = 0; n < 4; ++n) {
          o[qf][n][0] *= fsc; o[qf][n][1] *= fsc;
          o[qf][n][2] *= fsc; o[qf][n][3] *= fsc;
        }
        oex[qf][0] *= fsc; oex[qf][1] *= fsc;
        oex[qf][2] *= fsc; oex[qf][3] *= fsc;
      }

      float p[4][4];
#pragma unroll
      for (int n = 0; n < 4; ++n)
#pragma unroll
        for (int jj = 0; jj < 4; ++jj)
          p[n][jj] = exp2f(s[qf][n][jj] - m_[qf]);

      unsigned pk[4][2];
#pragma unroll
      for (int n = 0; n < 4; ++n) {
        pk[n][0] = cvt_pk_bf16(p[n][0], p[n][1]);
        pk[n][1] = cvt_pk_bf16(p[n][2], p[n][3]);
      }
      __builtin_amdgcn_s_setprio(1);
#pragma unroll
      for (int ks = 0; ks < 2; ++ks) {
        union { unsigned u[4]; bf16x8 v; } pb;
        pb.u[0] = pk[2*ks][0];   pb.u[1] = pk[2*ks][1];
        pb.u[2] = pk[2*ks+1][0]; pb.u[3] = pk[2*ks+1][1];
#pragma unroll
        for (int n = 0; n < 4; ++n)
          o[qf][n] = __builtin_amdgcn_mfma_f32_16x16x32_bf16(vf[ks][n], pb.v, o[qf][n], 0, 0, 0);
        oex[qf] = __builtin_amdgcn_mfma_f32_16x16x32_bf16(ones8, pb.v, oex[qf], 0, 0, 0);
      }
      __builtin_amdgcn_s_setprio(0);
    }
    cslot = (cslot == 2) ? 0 : cslot + 1;
    if (t + 1 < NT) { if (t + 2 < NT) WAITBAR3; else WAITBAR0; }
  }
#undef FSTAGE

  // ---- epilogue: UNNORMALIZED partial store + per-row stats.
  // O^T frag has q=fr, d = 16n + 4kq + jj (jj contiguous).
  const size_t pbase = ((size_t)hf * (B*NH) + bh) * T;
#pragma unroll
  for (int qf = 0; qf < 2; ++qf) {
    const size_t qrow = pbase + row0 + wave*32 + qf*16 + fr;
#pragma unroll
    for (int n = 0; n < 4; ++n) {
      float4 ov;
      ov.x = o[qf][n][0]; ov.y = o[qf][n][1];
      ov.z = o[qf][n][2]; ov.w = o[qf][n][3];
      *(float4*)(Pp + qrow * HD + n * 16 + kq * 4) = ov;
    }
    if (kq == 0) { Ms[qrow] = m_[qf]; Lsum[qrow] = oex[qf][0]; }
  }
}

// ---------------------------------------------------------------------------
// Fused split-KV merge + residual + LN:
//   att = (o0*e2^(m0-M) + o1*e2^(m1-M)) / (l0*e2^(m0-M) + l1*e2^(m1-M))
//   out = LN(x + att) * gamma + beta; ddof=1, eps on std. + bf16 copy.
// Pp layout [2][B*NH][T][HD] fp32 (unnormalized), Ms/Ls [2][B*NH*T].
// ---------------------------------------------------------------------------
__global__ __launch_bounds__(256) void ln_residual_att(
    const float* __restrict__ A, const float* __restrict__ Pp,
    const float* __restrict__ Ms, const float* __restrict__ Lsum,
    const float* __restrict__ gamma, const float* __restrict__ beta,
    float* __restrict__ out, u16* __restrict__ obf)
{
  const int row = blockIdx.x, tid = threadIdx.x;  // row = b*T + t
  const int wave = tid >> 6, lane = tid & 63;
  const int b = row >> 11, t = row & (T - 1);
  const int h = tid >> 4;            // (tid*4)/64
  const int d = (tid & 15) * 4;
  const size_t s0 = ((size_t)(b * NH + h)) * T + t;
  const size_t s1 = s0 + (size_t)(B * NH) * T;
  const float m0v = Ms[s0], m1v = Ms[s1];
  const float l0v = Lsum[s0], l1v = Lsum[s1];
  const float Mf = fmaxf(m0v, m1v);
  const float w0 = exp2f(m0v - Mf), w1 = exp2f(m1v - Mf);
  const float invl = 1.0f / (l0v * w0 + l1v * w1);
  const float4 o0 = *(const float4*)(Pp + s0 * HD + d);
  const float4 o1 = *(const float4*)(Pp + s1 * HD + d);
  const size_t off = (size_t)row * H + tid * 4;
  const float4 av = *(const float4*)(A + off);
  float4 y;
  y.x = av.x + (o0.x * w0 + o1.x * w1) * invl;
  y.y = av.y + (o0.y * w0 + o1.y * w1) * invl;
  y.z = av.z + (o0.z * w0 + o1.z * w1) * invl;
  y.w = av.w + (o0.w * w0 + o1.w * w1) * invl;
  float s  = y.x + y.y + y.z + y.w;
  float ss = y.x*y.x + y.y*y.y + y.z*y.z + y.w*y.w;
#pragma unroll
  for (int o = 32; o >= 1; o >>= 1) { s += __shfl_xor(s, o); ss += __shfl_xor(ss, o); }
  __shared__ float red[2][4];
  if (lane == 0) { red[0][wave] = s; red[1][wave] = ss; }
  __syncthreads();
  s  = red[0][0] + red[0][1] + red[0][2] + red[0][3];
  ss = red[1][0] + red[1][1] + red[1][2] + red[1][3];
  const float mean = s * (1.0f / (float)H);
  float var = (ss - (float)H * mean * mean) * (1.0f / (float)(H - 1));
  var = fmaxf(var, 0.0f);
  const float inv = 1.0f / (sqrtf(var) + 1e-6f);
  const float4 gv = *(const float4*)(gamma + tid * 4);
  const float4 be = *(const float4*)(beta + tid * 4);
  float4 o;
  o.x = gv.x * (y.x - mean) * inv + be.x;
  o.y = gv.y * (y.y - mean) * inv + be.y;
  o.z = gv.z * (y.z - mean) * inv + be.z;
  o.w = gv.w * (y.w - mean) * inv + be.w;
  *(float4*)(out + off) = o;
  if (obf) {
    union { u16 s[4]; uint2 u; } pk;
    pk.s[0] = f2bf(o.x); pk.s[1] = f2bf(o.y); pk.s[2] = f2bf(o.z); pk.s[3] = f2bf(o.w);
    *(uint2*)(obf + off) = pk.u;
  }
}

// ---------------------------------------------------------------------------
// split-K merge + LN: out = LN(a + (pA+pB)*bb) * gamma + beta
// ---------------------------------------------------------------------------
__global__ __launch_bounds__(256) void ln_residual_sk(
    const float* __restrict__ A, const float* __restrict__ PA,
    const float* __restrict__ PB, const float* __restrict__ bb,
    const float* __restrict__ gamma, const float* __restrict__ beta,
    float* __restrict__ out)
{
  const int row = blockIdx.x, tid = threadIdx.x;
  const int wave = tid >> 6, lane = tid & 63;
  const size_t off = (size_t)row * H + tid * 4;
  const float4 av = *(const float4*)(A + off);
  const float4 pa = *(const float4*)(PA + off);
  const float4 pb = *(const float4*)(PB + off);
  const float4 bw = *(const float4*)(bb + tid * 4);
  float4 y;
  y.x = av.x + (pa.x + pb.x) * bw.x;
  y.y = av.y + (pa.y + pb.y) * bw.y;
  y.z = av.z + (pa.z + pb.z) * bw.z;
  y.w = av.w + (pa.w + pb.w) * bw.w;
  float s  = y.x + y.y + y.z + y.w;
  float ss = y.x*y.x + y.y*y.y + y.z*y.z + y.w*y.w;
#pragma unroll
  for (int o = 32; o >= 1; o >>= 1) { s += __shfl_xor(s, o); ss += __shfl_xor(ss, o); }
  __shared__ float red[2][4];
  if (lane == 0) { red[0][wave] = s; red[1][wave] = ss; }
  __syncthreads();
  s  = red[0][0] + red[0][1] + red[0][2] + red[0][3];
  ss = red[1][0] + red[1][1] + red[1][2] + red[1][3];
  const float mean = s * (1.0f / (float)H);
  float var = (ss - (float)H * mean * mean) * (1.0f / (float)(H - 1));
  var = fmaxf(var, 0.0f);
  const float inv = 1.0f / (sqrtf(var) + 1e-6f);
  const float4 gv = *(const float4*)(gamma + tid * 4);
  const float4 be = *(const float4*)(beta + tid * 4);
  float4 o;
  o.x = gv.x * (y.x - mean) * inv + be.x;
  o.y = gv.y * (y.y - mean) * inv + be.y;
  o.z = gv.z * (y.z - mean) * inv + be.z;
  o.w = gv.w * (y.w - mean) * inv + be.w;
  *(float4*)(out + off) = o;
}

// ---------------------------------------------------------------------------
extern "C" void kernel_launch(void* const* d_in, const int* in_sizes, int n_in,
                              void* d_out, int out_size, void* d_ws, size_t ws_size,
                              hipStream_t stream)
{
  const float* x    = (const float*)d_in[0];
  const float* Wqkv = (const float*)d_in[1];
  const float* bqkv = (const float*)d_in[2];
  const float* W1   = (const float*)d_in[3];
  const float* b1   = (const float*)d_in[4];
  const float* W2   = (const float*)d_in[5];
  const float* b2   = (const float*)d_in[6];
  const float* g1   = (const float*)d_in[7];
  const float* be1  = (const float*)d_in[8];
  const float* g2   = (const float*)d_in[9];
  const float* be2  = (const float*)d_in[10];
  float* out = (float*)d_out;
  char* w = (char*)d_ws;

  // ---- workspace map (bytes); regions time-multiplexed, peak ~145 MB ----
  float* qkv  = (float*)(w + 0);          // 50.33M  steps 3-4
  float* Pp   = (float*)(w + 0);          // 33.55M  steps 6-7 (over qkv dead)
  float* Msb  = (float*)(w + 33554432);   // 0.52M   steps 6-7
  float* Lsb  = (float*)(w + 34078720);   // 0.52M   steps 6-7
  u16*   h1b  = (u16*)  (w + 0);          // 33.55M  steps 9-11
  u16*   W1T  = (u16*)  (w + 35651584);   // 8.39M   steps 8-9
  u16*   W2T  = (u16*)  (w + 44040192);   // 8.39M   steps 10-11
  u16*   xh   = (u16*)  (w + 52428800);   // 8.39M   steps 1-3
  u16*   xl   = (u16*)  (w + 60817408);   // 8.39M   steps 1-3
  u16*   Qh   = (u16*)  (w + 52428800);   // 8.39M   steps 4-6 (over xh)
  u16*   Ql   = (u16*)  (w + 60817408);   // 8.39M   steps 4-6 (over xl)
  u16*   WqTh = (u16*)  (w + 69206016);   // 6.29M   steps 2-3
  u16*   WqTl = (u16*)  (w + 75497472);   // 6.29M   steps 2-3
  u16*   Khb  = (u16*)  (w + 69206016);   // 8.39M   steps 4-6 (over WqT*)
  u16*   Klb  = (u16*)  (w + 77594624);   // 8.39M   steps 4-6
  u16*   Vbb  = (u16*)  (w + 85983232);   // 8.39M   steps 4-5
  u16*   VTb  = (u16*)  (w + 94371840);   // 8.39M   steps 5-6
  float* pAB  = (float*)(w + 52428800);   // 33.55M  steps 11-12 (over Q/K dead)
  float* ln1  = (float*)(w + 119537664);  // 16.78M  steps 7-12
  u16*   ln1b = (u16*)  (w + 136314880);  // 8.39M   steps 7-9

  // 1. split x -> bf16 hi/lo
  split_hl<<<4096, 256, 0, stream>>>(x, xh, xl);
  // 2. Wqkv^T hi/lo bf16
  transpose_bf16<1><<<dim3(48, 16), 256, 0, stream>>>(Wqkv, WqTh, WqTl, H, 3*H);
  // 3. qkv = (x @ Wqkv) * bqkv  [split MFMA, 2-phase; V-col Bl staging skipped]
  mfma_gemm<1,0,0,1,0,0><<<24 * 32, 256, 0, stream>>>(xh, xl, WqTh, WqTl, bqkv,
                                                      qkv, nullptr, M_TOK, 3*H, H);
  // 4. repack heads -> scaled/split bf16 Q,K + bf16 V
  repack_qkv<<<M_TOK, 256, 0, stream>>>(qkv, Qh, Ql, Khb, Klb, Vbb);
  // 5. V transpose
  vtrans<<<dim3(T/64, B*NH), 256, 0, stream>>>(Vbb, VTb);
  // 6. attention (MFMA, swapped-operand, XCD-clustered, 8wx32r, split-KV=2)
  flash_attn_mfma<<<dim3(256, 2), 512, 0, stream>>>(Qh, Ql, Khb, Klb, VTb,
                                                    Pp, Msb, Lsb);
  // 7. ln1 = LN(x + merge(attn partials)) (+ bf16 copy)
  ln_residual_att<<<M_TOK, 256, 0, stream>>>(x, Pp, Msb, Lsb, g1, be1, ln1, ln1b);
  // 8. W1^T bf16
  transpose_bf16<0><<<dim3(64, 16), 256, 0, stream>>>(W1, W1T, nullptr, H, FF);
  // 9. h1 = relu((ln1 @ W1) * b1) -> bf16  [XCD-chunked, 3-deep]
  mfma_gemm<0,1,1,0,1,0><<<32 * 32, 256, 0, stream>>>(ln1b, nullptr, W1T, nullptr, b1,
                                                      nullptr, h1b, M_TOK, FF, H);
  // 10. W2^T bf16
  transpose_bf16<0><<<dim3(16, 64), 256, 0, stream>>>(W2, W2T, nullptr, FF, H);
  // 11. ffn partials = h1 @ W2 (split-K=2, raw fp32)  [XCD-chunked, 3-deep]
  mfma_gemm<0,0,0,0,1,1><<<dim3(8 * 32, 2), 256, 0, stream>>>(h1b, nullptr, W2T, nullptr, nullptr,
                                                              pAB, nullptr, M_TOK, H, FF);
  // 12. out = LN(ln1 + (pA+pB)*b2)
  ln_residual_sk<<<M_TOK, 256, 0, stream>>>(ln1, pAB, pAB + 4194304, b2, g2, be2, out);
}

// Round 4
// 319.745 us; speedup vs baseline: 1.1220x; 1.1220x over previous
//
#include <hip/hip_runtime.h>
#include <math.h>

// Sizes (fixed for this problem)
#define B 2
#define T 2048
#define H 1024
#define NH 16
#define HD 64
#define FF 4096
#define M_TOK (B*T)          // 4096 token rows
#define LOG2E 1.4426950408889634f

typedef unsigned short u16;
typedef __attribute__((ext_vector_type(8))) short bf16x8;
typedef __attribute__((ext_vector_type(4))) float f32x4;

// counted-vmcnt barrier: wait until only N of this wave's vmem ops remain,
// then workgroup barrier. Single asm with "memory" clobber so no memory op
// (gload_lds / ds_read) is reordered across it.
// NOTE (r8-r10 lesson): counted-vmcnt pipelines are only safe when EVERY
// LDS buffer is >=3 slots deep (overwrite target >=2 iterations stale).
// NOTE (R2 lesson): direct-to-register global V loads regress badly — the
// strided fragment pattern (rows T apart) turns each wave load into 16
// scattered L1 lines; keep V in LDS.
// NOTE (R3 lesson): split-KV partials must merge ON-CHIP. Global fp32
// partials (16B granules @ 256B stride) write-amplified ~6x and evicted
// the K/V working set from L2 (FETCH 20->195MB). Never again.
#define WAITBAR3  asm volatile("s_waitcnt vmcnt(3)\n\ts_barrier" ::: "memory")
#define WAITBAR4  asm volatile("s_waitcnt vmcnt(4)\n\ts_barrier" ::: "memory")
#define WAITBAR0  asm volatile("s_waitcnt vmcnt(0)\n\ts_barrier" ::: "memory")

__device__ __forceinline__ u16 f2bf(float f) {
  union { float f; unsigned u; } v; v.f = f;
  const unsigned r = (v.u + 0x7FFFu + ((v.u >> 16) & 1u)) >> 16;
  return (u16)r;
}
__device__ __forceinline__ float bf2f(u16 h) {
  union { unsigned u; float f; } v; v.u = ((unsigned)h) << 16;
  return v.f;
}
__device__ __forceinline__ unsigned cvt_pk_bf16(float lo, float hi) {
  unsigned r;
  asm("v_cvt_pk_bf16_f32 %0, %1, %2" : "=v"(r) : "v"(lo), "v"(hi));
  return r;
}
__device__ __forceinline__ float m3(float a, float b, float c) {
  return fmaxf(fmaxf(a, b), c);      // clang fuses to v_max3_f32
}
// async global->LDS, 16B per lane; dest = wave-uniform base + lane*16
__device__ __forceinline__ void gload16(const u16* g, u16* l) {
  __builtin_amdgcn_global_load_lds(
      (const __attribute__((address_space(1))) unsigned int*)g,
      (__attribute__((address_space(3))) unsigned int*)l, 16, 0, 0);
}

// ---------------------------------------------------------------------------
// split fp32 -> bf16 hi + bf16 lo (Dekker split; hi+lo ~ fp32 accurate)
// ---------------------------------------------------------------------------
__global__ __launch_bounds__(256) void split_hl(
    const float* __restrict__ in, u16* __restrict__ oh, u16* __restrict__ ol)
{
  const size_t i = ((size_t)blockIdx.x * 256 + threadIdx.x) * 4;
  const float4 v = *(const float4*)(in + i);
  union { u16 s[4]; uint2 u; } h, l;
  const float f[4] = {v.x, v.y, v.z, v.w};
#pragma unroll
  for (int j = 0; j < 4; ++j) {
    const u16 hb = f2bf(f[j]); h.s[j] = hb; l.s[j] = f2bf(f[j] - bf2f(hb));
  }
  *(uint2*)(oh + i) = h.u;
  *(uint2*)(ol + i) = l.u;
}

// ---------------------------------------------------------------------------
// transpose-convert: in [K][N] fp32 -> out [N][K] bf16 (hi, + lo if SPLIT)
// ---------------------------------------------------------------------------
template<int SPLIT>
__global__ __launch_bounds__(256) void transpose_bf16(
    const float* __restrict__ in, u16* __restrict__ oh, u16* __restrict__ ol,
    int K, int N)
{
  __shared__ float tile[64][69];
  const int k0 = blockIdx.y * 64, n0 = blockIdx.x * 64;
  const int tid = threadIdx.x;
  const int r = tid >> 4, c4 = (tid & 15) * 4;
#pragma unroll
  for (int i = 0; i < 4; ++i) {
    const float4 v = *(const float4*)(in + (size_t)(k0 + i*16 + r) * N + n0 + c4);
    tile[i*16+r][c4]   = v.x; tile[i*16+r][c4+1] = v.y;
    tile[i*16+r][c4+2] = v.z; tile[i*16+r][c4+3] = v.w;
  }
  __syncthreads();
  const int n = tid >> 2, kq = tid & 3;
  union { u16 s[8]; int4 v; } ph0, ph1, pl0, pl1;
#pragma unroll
  for (int j = 0; j < 8; ++j) {
    const float f0 = tile[kq*16 + j][n];
    const float f1 = tile[kq*16 + 8 + j][n];
    const u16 h0 = f2bf(f0), h1 = f2bf(f1);
    ph0.s[j] = h0; ph1.s[j] = h1;
    if (SPLIT) { pl0.s[j] = f2bf(f0 - bf2f(h0)); pl1.s[j] = f2bf(f1 - bf2f(h1)); }
  }
  u16* po = oh + (size_t)(n0 + n) * K + k0 + kq * 16;
  *(int4*)po = ph0.v; *(int4*)(po + 8) = ph1.v;
  if (SPLIT) {
    u16* pl = ol + (size_t)(n0 + n) * K + k0 + kq * 16;
    *(int4*)pl = pl0.v; *(int4*)(pl + 8) = pl1.v;
  }
}

// ---------------------------------------------------------------------------
// MFMA GEMM: C[M,N] = (A @ B^T) * bias[N]  (A [M][K] bf16, B [N][K] bf16)
// 128x128 tile, BK=32, global_load_lds staging, XCD-chunked 1-D grid.
// DEEP3 (non-split only): 3-slot LDS + counted vmcnt(4) barriers. 24KB.
// SPLIT: 2-phase double-buffered (__syncthreads drains vmcnt -> safe).
// PARTIAL: split-K=2 over blockIdx.y; raw fp32 partials (no bias/relu).
// QKV3: V fragments (qkv k-index 2) skip the hi/lo correction MFMAs, and
//       their Bl staging chunks are skipped entirely (never read).
// ---------------------------------------------------------------------------
__device__ __forceinline__ int swz(int r, int kq) {
  return r * 32 + ((kq ^ ((r >> 1) & 3)) * 8);
}

template<int SPLIT, int RELU, int OBF, int QKV3, int DEEP3, int PARTIAL>
__global__ __launch_bounds__(256) void mfma_gemm(
    const u16* __restrict__ Ah, const u16* __restrict__ Al,
    const u16* __restrict__ Bh, const u16* __restrict__ Bl,
    const float* __restrict__ bias,
    float* __restrict__ Cf, u16* __restrict__ Cb,
    int M, int N, int K)
{
  __shared__ u16 lds[DEEP3 ? 24576 : (SPLIT ? 32768 : 16384)];
  const int BUFSZ = SPLIT ? 16384 : 8192;
  const int tid = threadIdx.x;
  // XCD-chunked decode: xcd=bid&7 owns M-panels [4*xcd, 4*xcd+4)
  const int bid = blockIdx.x;
  const int xcd = bid & 7;
  const int idx = bid >> 3;
  const int row0 = (xcd * 4 + (idx & 3)) * 128;
  const int col0 = (idx >> 2) * 128;
  const int wv = tid >> 6, lane = tid & 63;
  const int wr = wv >> 1, wc = wv & 1;
  const int kq = lane >> 4, fr = lane & 15;

  int kb = 0, kE = K;
  if (PARTIAL) {
    const int khf = blockIdx.y;
    kb = khf * (K >> 1); kE = kb + (K >> 1);
    Cf += (size_t)khf * ((size_t)M * N);
  }

  f32x4 acc[4][4] = {};

  // stage one 128x32 bf16 array (8 chunks of 1KB); wave wv does chunks 2wv,2wv+1
#define GSTAGE(lbase, gb, rowbase, kk) do { \
    _Pragma("unroll") \
    for (int t_ = 0; t_ < 2; ++t_) { \
      const int c_ = wv * 2 + t_; \
      const int idx_ = c_ * 64 + lane; \
      const int r_ = idx_ >> 2; \
      const int kq_ = (idx_ & 3) ^ ((r_ >> 1) & 3); \
      gload16((gb) + (size_t)((rowbase) + r_) * K + (kk) + kq_ * 8, \
              &lds[(lbase) + c_ * 512]); \
    } } while (0)

  // Bl staging with V-group chunk skip (chunk c covers 16-col group
  // (col0>>4)+c; k-index %3==2 groups never read their b_l fragments).
#define BLSTAGE(lbase, kk) do { \
    _Pragma("unroll") \
    for (int t_ = 0; t_ < 2; ++t_) { \
      const int c_ = wv * 2 + t_; \
      if (!QKV3 || ((((col0 >> 4) + c_) % 3) != 2)) { \
        const int idx_ = c_ * 64 + lane; \
        const int r_ = idx_ >> 2; \
        const int kq_ = (idx_ & 3) ^ ((r_ >> 1) & 3); \
        gload16(Bl + (size_t)(col0 + r_) * K + (kk) + kq_ * 8, \
                &lds[(lbase) + c_ * 512]); \
      } } } while (0)

  if (DEEP3) {
    // ---- 3-deep counted-vmcnt pipeline (non-split only; all slots 3-deep,
    // overwrite target is 2 iterations stale -> no write-after-read hazard) ----
    const int nk = (kE - kb) >> 5;
    GSTAGE(0, Ah, row0, kb);            GSTAGE(4096, Bh, col0, kb);
    GSTAGE(8192, Ah, row0, kb + 32);    GSTAGE(8192 + 4096, Bh, col0, kb + 32);
    WAITBAR4;                            // stage 0 ready; stage 1 in flight
    int cslot = 0, islot = 2;
    for (int i = 0; i < nk; ++i) {
      if (i + 2 < nk) {
        const int kk = kb + (i + 2) * 32;
        GSTAGE(islot * 8192, Ah, row0, kk);
        GSTAGE(islot * 8192 + 4096, Bh, col0, kk);
        islot = (islot == 2) ? 0 : islot + 1;
      }
      const int rb = cslot * 8192;
      bf16x8 a_h[4];
#pragma unroll
      for (int m = 0; m < 4; ++m)
        a_h[m] = *(const bf16x8*)&lds[rb + swz(wr*64 + m*16 + fr, kq)];
#pragma unroll
      for (int n = 0; n < 4; ++n) {
        const bf16x8 b_h = *(const bf16x8*)&lds[rb + 4096 + swz(wc*64 + n*16 + fr, kq)];
#pragma unroll
        for (int m = 0; m < 4; ++m)
          acc[m][n] = __builtin_amdgcn_mfma_f32_16x16x32_bf16(a_h[m], b_h, acc[m][n], 0, 0, 0);
      }
      cslot = (cslot == 2) ? 0 : cslot + 1;
      if (i + 1 < nk) { if (i + 2 < nk) WAITBAR4; else WAITBAR0; }
    }
  } else {
    // ---- 2-phase double-buffered (__syncthreads drains all counters) ----
    GSTAGE(0, Ah, row0, kb);
    GSTAGE(4096, Bh, col0, kb);
    if (SPLIT) { GSTAGE(8192, Al, row0, kb); BLSTAGE(12288, kb); }
    __syncthreads();

    int cur = 0;
    for (int k0 = kb; k0 < kE; k0 += 32) {
      const int nxt = cur ^ 1;
      if (k0 + 32 < kE) {
        GSTAGE(nxt*BUFSZ, Ah, row0, k0 + 32);
        GSTAGE(nxt*BUFSZ + 4096, Bh, col0, k0 + 32);
        if (SPLIT) { GSTAGE(nxt*BUFSZ + 8192, Al, row0, k0 + 32);
                     BLSTAGE(nxt*BUFSZ + 12288, k0 + 32); }
      }
      const int rb = cur * BUFSZ;
      bf16x8 a_h[4], a_l[4];
#pragma unroll
      for (int m = 0; m < 4; ++m) {
        a_h[m] = *(const bf16x8*)&lds[rb + swz(wr*64 + m*16 + fr, kq)];
        if (SPLIT) a_l[m] = *(const bf16x8*)&lds[rb + 8192 + swz(wr*64 + m*16 + fr, kq)];
      }
#pragma unroll
      for (int n = 0; n < 4; ++n) {
        const bf16x8 b_h = *(const bf16x8*)&lds[rb + 4096 + swz(wc*64 + n*16 + fr, kq)];
#pragma unroll
        for (int m = 0; m < 4; ++m)
          acc[m][n] = __builtin_amdgcn_mfma_f32_16x16x32_bf16(a_h[m], b_h, acc[m][n], 0, 0, 0);
        if (SPLIT) {
          const bool dolo = !QKV3 || ((((col0 >> 4) + wc * 4 + n) % 3) != 2);
          if (dolo) {
            const bf16x8 b_l = *(const bf16x8*)&lds[rb + 12288 + swz(wc*64 + n*16 + fr, kq)];
#pragma unroll
            for (int m = 0; m < 4; ++m) {
              acc[m][n] = __builtin_amdgcn_mfma_f32_16x16x32_bf16(a_h[m], b_l, acc[m][n], 0, 0, 0);
              acc[m][n] = __builtin_amdgcn_mfma_f32_16x16x32_bf16(a_l[m], b_h, acc[m][n], 0, 0, 0);
            }
          }
        }
      }
      __syncthreads();
      cur = nxt;
    }
  }
#undef GSTAGE
#undef BLSTAGE

  const int orow0 = row0 + wr * 64, ocol0 = col0 + wc * 64;
#pragma unroll
  for (int n = 0; n < 4; ++n) {
    const int col = ocol0 + n * 16 + fr;
    const float bs = PARTIAL ? 1.0f : bias[col];
#pragma unroll
    for (int m = 0; m < 4; ++m) {
      const int rbase = orow0 + m * 16 + (lane >> 4) * 4;
#pragma unroll
      for (int j = 0; j < 4; ++j) {
        float v = acc[m][n][j] * bs;
        if (RELU) v = fmaxf(v, 0.0f);
        const size_t off = (size_t)(rbase + j) * N + col;
        if (OBF) Cb[off] = f2bf(v); else Cf[off] = v;
      }
    }
  }
}

// ---------------------------------------------------------------------------
// Repack qkv [B,T,3072] -> bf16 arrays: Qh/Ql (scaled by log2e/32, split),
// Kh/Kl (split), Vb (bf16), all [B*NH][T][HD]. Channel o = d*48 + k*16 + h.
// ---------------------------------------------------------------------------
__global__ __launch_bounds__(256) void repack_qkv(
    const float* __restrict__ qkv,
    u16* __restrict__ Qh, u16* __restrict__ Ql,
    u16* __restrict__ Kh, u16* __restrict__ Kl, u16* __restrict__ Vb)
{
  const int bt = blockIdx.x;
  const int b = bt >> 11, t = bt & (T - 1);
  const int tid = threadIdx.x;
  __shared__ float Ls[3 * H];
  const float* src = qkv + (size_t)bt * (3 * H);
#pragma unroll
  for (int i = 0; i < 3; ++i) {
    const int c4 = i * 256 + tid;
    *(float4*)&Ls[c4 * 4] = *(const float4*)(src + c4 * 4);
  }
  __syncthreads();
  const float qscale = LOG2E / 32.0f;
#pragma unroll
  for (int i = 0; i < 4; ++i) {
    const int j = i * 256 + tid;
    const int h = j >> 6, d = j & 63;
    const size_t dst = (((size_t)(b * NH + h)) * T + t) * HD + d;
    const float q = Ls[d * 48 + h] * qscale;
    const u16 qhb = f2bf(q);
    Qh[dst] = qhb; Ql[dst] = f2bf(q - bf2f(qhb));
    const float k = Ls[d * 48 + 16 + h];
    const u16 khb = f2bf(k);
    Kh[dst] = khb; Kl[dst] = f2bf(k - bf2f(khb));
    Vb[dst] = f2bf(Ls[d * 48 + 32 + h]);
  }
}

// ---------------------------------------------------------------------------
// Vb [bh][T][HD] bf16 -> VT [bh][HD][T] bf16 (64x64 tiles via LDS)
// ---------------------------------------------------------------------------
__global__ __launch_bounds__(256) void vtrans(
    const u16* __restrict__ Vb, u16* __restrict__ VT)
{
  __shared__ u16 Ls[64][72];
  const int bh = blockIdx.y, t0 = blockIdx.x * 64;
  const int tid = threadIdx.x;
  const int r = tid >> 2, c = (tid & 3) * 16;
  const size_t src = ((size_t)bh * T + t0 + r) * HD + c;
  *(int4*)&Ls[r][c]     = *(const int4*)(Vb + src);
  *(int4*)&Ls[r][c + 8] = *(const int4*)(Vb + src + 8);
  __syncthreads();
  const int d = tid >> 2, tc = (tid & 3) * 16;
  u16 buf[16];
#pragma unroll
  for (int i = 0; i < 16; ++i) buf[i] = Ls[tc + i][d];
  u16* dst = VT + ((size_t)bh * HD + d) * T + t0 + tc;
  *(int4*)dst       = *(int4*)&buf[0];
  *(int4*)(dst + 8) = *(int4*)&buf[8];
}

// ---------------------------------------------------------------------------
// sigma: LDS K-row r holds key sigma(r) so that the QK^T C-layout hands each
// lane exactly the 8-consecutive-key fragments PV's B-operand needs.
// For r<32 (KVBLK=32): sigma(r) = 8*kq-part + 4*n-part + jj — bijective on
// 0..31 (pure bit permutation), so the same formula serves 32-key tiles.
// ---------------------------------------------------------------------------
__device__ __forceinline__ int sigma_k(int r) {
  return ((r >> 5) << 5) | (((r >> 2) & 3) << 3) | (((r >> 4) & 1) << 2) | (r & 3);
}

// ---------------------------------------------------------------------------
// MFMA flash attention, swapped-operand, INTRA-BLOCK split-KV.
// 512 threads = 8 waves = 2 groups x 4 waves. Group g processes KV keys
// [g*1024, g*1024+1024) in 32 tiles of KVBLK=32; each wave owns 32 q-rows
// (2 q-frags), so K/V LDS reads amortize over 2x rows (R2 lesson) while the
// grid stays 512 -> 2 blocks/CU -> 16 waves/CU (R1's occupancy).
// LDS ring: 3 slots x 24KB PAIR (12KB per group tile: KH 4K | KL 4K | VT 4K),
// counted-vmcnt WAITBAR3 (3 gloads/wave/step, slots 3-deep -> safe).
// V tile rows are 64B (32 keys): XOR swizzle g^(r&3) on 16B granules.
// End: groups merge (m,l,O) through LDS (R3 lesson: merge on-chip, never
// via global partials). Group 0 writes the normalized output.
// ---------------------------------------------------------------------------
__global__ __launch_bounds__(512, 4) void flash_attn_mfma(
    const u16* __restrict__ Qh, const u16* __restrict__ Ql,
    const u16* __restrict__ Kh, const u16* __restrict__ Kl,
    const u16* __restrict__ VT, float* __restrict__ Out)
{
  __shared__ u16 sm[3 * 12288];  // 3 slots x (grp0 12KB | grp1 12KB)
  // XCD-clustered decode: xcd = i&7 owns heads 4*xcd..4*xcd+3
  const int i = blockIdx.x;
  const int slot = i >> 3;
  const int bh = (i & 7) * 4 + (slot >> 4);
  const int row0 = (slot & 15) * 128;
  const int b = bh >> 4, h = bh & 15;
  const int tid = threadIdx.x, wave = tid >> 6, lane = tid & 63;
  const int fr = lane & 15, kq = lane >> 4;
  const int u = wave & 3, grp = wave >> 2;

  // Q fragments (B-operand: col=q=fr, k=d=kq*8 within ks*32); wave owns
  // q-rows [row0 + u*32, +32), two 16-row frags qf=0,1. Both groups load
  // the same rows (same-u partner waves share q-rows).
  bf16x8 qh[2][2], ql[2][2];
#pragma unroll
  for (int qf = 0; qf < 2; ++qf) {
    const size_t qoff = ((size_t)bh * T + row0 + u*32 + qf*16 + fr) * HD + kq*8;
#pragma unroll
    for (int ks = 0; ks < 2; ++ks) {
      qh[qf][ks] = *(const bf16x8*)(Qh + qoff + ks*32);
      ql[qf][ks] = *(const bf16x8*)(Ql + qoff + ks*32);
    }
  }

  bf16x8 ones8;
#pragma unroll
  for (int z = 0; z < 8; ++z) ones8[z] = (short)0x3F80;

  f32x4 o[2][4] = {};
  f32x4 oex[2] = {};                       // lsum accumulators (all rows equal)
  float m_[2] = {-1e30f, -1e30f};

  // staging: group's 4 waves cover its 12 chunks (1KB each); wave u does
  // chunks u*3..u*3+2. sub<4: KH rows, 4..7: KL rows, 8..11: VT rows.
  const int kb0 = grp * (T / 2);
  const u16* sp0; const u16* sp1; const u16* sp2;
  int so0, so1, so2, st0, st1, st2;
#define MKCH(J, SP, SO, ST) do { \
    const int sub_ = u * 3 + (J); \
    if (sub_ < 8) { \
      const int r_ = (sub_ & 3) * 8 + (lane >> 3); \
      const int cd_ = (lane & 7) ^ (r_ & 7); \
      const u16* base_ = (sub_ < 4) ? Kh : Kl; \
      SP = base_ + ((size_t)bh * T + kb0 + sigma_k(r_)) * HD + cd_ * 8; \
      ST = 32 * HD; \
    } else { \
      const int r_ = (sub_ & 3) * 16 + (lane >> 2); \
      const int cd_ = (lane & 3) ^ (r_ & 3); \
      SP = VT + ((size_t)bh * HD + r_) * T + kb0 + cd_ * 8; \
      ST = 32; \
    } \
    SO = grp * 6144 + sub_ * 512; \
  } while (0)
  MKCH(0, sp0, so0, st0);
  MKCH(1, sp1, so1, st1);
  MKCH(2, sp2, so2, st2);
#undef MKCH

#define FSTAGE(sb) do { \
    gload16(sp0, &sm[(sb) + so0]); sp0 += st0; \
    gload16(sp1, &sm[(sb) + so1]); sp1 += st1; \
    gload16(sp2, &sm[(sb) + so2]); sp2 += st2; \
  } while (0)

  FSTAGE(0);
  FSTAGE(12288);
  WAITBAR3;                  // pair 0 ready (3 loads/wave); pair 1 in flight
  int cslot = 0, islot = 2;

  const int NT = 32;                       // 32 tiles of 32 keys per group
  for (int t = 0; t < NT; ++t) {
    if (t + 2 < NT) {
      FSTAGE(islot * 12288);
      islot = (islot == 2) ? 0 : islot + 1;
    }
    const u16* gb = &sm[cslot * 12288 + grp * 6144];

    // ---- QK^T (swapped): s[qf][n], keys sigma(16n+4kq+jj), q=fr; n=0,1
    f32x4 s[2][2] = {};
    __builtin_amdgcn_s_setprio(1);
#pragma unroll
    for (int ks = 0; ks < 2; ++ks) {
#pragma unroll
      for (int n = 0; n < 2; ++n) {
        const int kr = n * 16 + fr;
        const int sl = ((ks*4 + kq) ^ (kr & 7)) * 8;
        const bf16x8 kh_ = *(const bf16x8*)&gb[kr*64 + sl];
        const bf16x8 kl_ = *(const bf16x8*)&gb[2048 + kr*64 + sl];
        s[0][n] = __builtin_amdgcn_mfma_f32_16x16x32_bf16(kh_, qh[0][ks], s[0][n], 0, 0, 0);
        s[1][n] = __builtin_amdgcn_mfma_f32_16x16x32_bf16(kh_, qh[1][ks], s[1][n], 0, 0, 0);
        s[0][n] = __builtin_amdgcn_mfma_f32_16x16x32_bf16(kl_, qh[0][ks], s[0][n], 0, 0, 0);
        s[1][n] = __builtin_amdgcn_mfma_f32_16x16x32_bf16(kl_, qh[1][ks], s[1][n], 0, 0, 0);
        s[0][n] = __builtin_amdgcn_mfma_f32_16x16x32_bf16(kh_, ql[0][ks], s[0][n], 0, 0, 0);
        s[1][n] = __builtin_amdgcn_mfma_f32_16x16x32_bf16(kh_, ql[1][ks], s[1][n], 0, 0, 0);
      }
    }
    __builtin_amdgcn_s_setprio(0);

    // ---- hoist V^T fragments (shared by both q-frags); dn = d-block 0..3
    bf16x8 vf[4];
#pragma unroll
    for (int dn = 0; dn < 4; ++dn) {
      const int dr = dn * 16 + fr;
      vf[dn] = *(const bf16x8*)&gb[4096 + dr*32 + ((kq ^ (dr & 3)) * 8)];
    }

    // ---- per q-frag: defer-max softmax + in-reg P -> PV (+ lsum MFMA)
#pragma unroll
    for (int qf = 0; qf < 2; ++qf) {
      const float f1 = m3(s[qf][0][0], s[qf][0][1], s[qf][0][2]);
      const float f2 = m3(s[qf][0][3], s[qf][1][0], s[qf][1][1]);
      const float f3 = m3(s[qf][1][2], s[qf][1][3], f1);
      float mx = fmaxf(f2, f3);
      mx = fmaxf(mx, __shfl_xor(mx, 16));
      mx = fmaxf(mx, __shfl_xor(mx, 32));
      if (!__all(mx <= m_[qf] + 8.0f)) {      // record tile: rescale
        const float mn = fmaxf(m_[qf], mx);
        const float fsc = exp2f(m_[qf] - mn);
        m_[qf] = mn;
#pragma unroll
        for (int dn = 0; dn < 4; ++dn) {
          o[qf][dn][0] *= fsc; o[qf][dn][1] *= fsc;
          o[qf][dn][2] *= fsc; o[qf][dn][3] *= fsc;
        }
        oex[qf][0] *= fsc; oex[qf][1] *= fsc;
        oex[qf][2] *= fsc; oex[qf][3] *= fsc;
      }

      float p[2][4];
#pragma unroll
      for (int n = 0; n < 2; ++n)
#pragma unroll
        for (int jj = 0; jj < 4; ++jj)
          p[n][jj] = exp2f(s[qf][n][jj] - m_[qf]);

      union { unsigned pu[4]; bf16x8 v; } pb;
      pb.pu[0] = cvt_pk_bf16(p[0][0], p[0][1]);
      pb.pu[1] = cvt_pk_bf16(p[0][2], p[0][3]);
      pb.pu[2] = cvt_pk_bf16(p[1][0], p[1][1]);
      pb.pu[3] = cvt_pk_bf16(p[1][2], p[1][3]);

      __builtin_amdgcn_s_setprio(1);
#pragma unroll
      for (int dn = 0; dn < 4; ++dn)
        o[qf][dn] = __builtin_amdgcn_mfma_f32_16x16x32_bf16(vf[dn], pb.v, o[qf][dn], 0, 0, 0);
      oex[qf] = __builtin_amdgcn_mfma_f32_16x16x32_bf16(ones8, pb.v, oex[qf], 0, 0, 0);
      __builtin_amdgcn_s_setprio(0);
    }
    cslot = (cslot == 2) ? 0 : cslot + 1;
    if (t + 1 < NT) { if (t + 2 < NT) WAITBAR3; else WAITBAR0; }
  }
#undef FSTAGE

  // ---- on-chip split-KV merge: group1 -> LDS -> group0 combines + stores.
  // Region per partner-pair u: 2176 floats (8704B): o at [0,2048), stats
  // m at [2048+qf*16+fr], l at [2080+qf*16+fr]. 4 regions = 34816B <= 72KB.
  __syncthreads();                          // all tile-31 LDS reads done
  float* fm = (float*)sm;
  const int rb_ = u * 2176;
  if (grp == 1) {
#pragma unroll
    for (int qf = 0; qf < 2; ++qf) {
#pragma unroll
      for (int dn = 0; dn < 4; ++dn)
        *(f32x4*)&fm[rb_ + (qf*4 + dn)*256 + lane*4] = o[qf][dn];
      if (kq == 0) {
        fm[rb_ + 2048 + qf*16 + fr] = m_[qf];
        fm[rb_ + 2080 + qf*16 + fr] = oex[qf][0];
      }
    }
  }
  __syncthreads();
  if (grp == 0) {
#pragma unroll
    for (int qf = 0; qf < 2; ++qf) {
      const float mB = fm[rb_ + 2048 + qf*16 + fr];
      const float lB = fm[rb_ + 2080 + qf*16 + fr];
      const float M  = fmaxf(m_[qf], mB);
      const float wA = exp2f(m_[qf] - M);
      const float wB = exp2f(mB - M);
      const float inv = 1.0f / (oex[qf][0] * wA + lB * wB);
      const size_t qrow = (size_t)b * T + row0 + u*32 + qf*16 + fr;
#pragma unroll
      for (int dn = 0; dn < 4; ++dn) {
        const f32x4 ob = *(const f32x4*)&fm[rb_ + (qf*4 + dn)*256 + lane*4];
        float4 ov;
        ov.x = (o[qf][dn][0] * wA + ob[0] * wB) * inv;
        ov.y = (o[qf][dn][1] * wA + ob[1] * wB) * inv;
        ov.z = (o[qf][dn][2] * wA + ob[2] * wB) * inv;
        ov.w = (o[qf][dn][3] * wA + ob[3] * wB) * inv;
        *(float4*)(Out + qrow * H + h * HD + dn * 16 + kq * 4) = ov;
      }
    }
  }
}

// ---------------------------------------------------------------------------
// out = LN(a + b) * gamma + beta; ddof=1, eps on std. Optional bf16 copy.
// ---------------------------------------------------------------------------
__global__ __launch_bounds__(256) void ln_residual(
    const float* __restrict__ A, const float* __restrict__ Bz,
    const float* __restrict__ gamma, const float* __restrict__ beta,
    float* __restrict__ out, u16* __restrict__ obf)
{
  const int row = blockIdx.x, tid = threadIdx.x;
  const int wave = tid >> 6, lane = tid & 63;
  const size_t off = (size_t)row * H + tid * 4;
  const float4 av = *(const float4*)(A + off);
  const float4 bv = *(const float4*)(Bz + off);
  float4 y; y.x = av.x + bv.x; y.y = av.y + bv.y; y.z = av.z + bv.z; y.w = av.w + bv.w;
  float s  = y.x + y.y + y.z + y.w;
  float ss = y.x*y.x + y.y*y.y + y.z*y.z + y.w*y.w;
#pragma unroll
  for (int o = 32; o >= 1; o >>= 1) { s += __shfl_xor(s, o); ss += __shfl_xor(ss, o); }
  __shared__ float red[2][4];
  if (lane == 0) { red[0][wave] = s; red[1][wave] = ss; }
  __syncthreads();
  s  = red[0][0] + red[0][1] + red[0][2] + red[0][3];
  ss = red[1][0] + red[1][1] + red[1][2] + red[1][3];
  const float mean = s * (1.0f / (float)H);
  float var = (ss - (float)H * mean * mean) * (1.0f / (float)(H - 1));
  var = fmaxf(var, 0.0f);
  const float inv = 1.0f / (sqrtf(var) + 1e-6f);
  const float4 gv = *(const float4*)(gamma + tid * 4);
  const float4 be = *(const float4*)(beta + tid * 4);
  float4 o;
  o.x = gv.x * (y.x - mean) * inv + be.x;
  o.y = gv.y * (y.y - mean) * inv + be.y;
  o.z = gv.z * (y.z - mean) * inv + be.z;
  o.w = gv.w * (y.w - mean) * inv + be.w;
  *(float4*)(out + off) = o;
  if (obf) {
    union { u16 s[4]; uint2 u; } pk;
    pk.s[0] = f2bf(o.x); pk.s[1] = f2bf(o.y); pk.s[2] = f2bf(o.z); pk.s[3] = f2bf(o.w);
    *(uint2*)(obf + off) = pk.u;
  }
}

// ---------------------------------------------------------------------------
// split-K merge + LN: out = LN(a + (pA+pB)*bb) * gamma + beta
// ---------------------------------------------------------------------------
__global__ __launch_bounds__(256) void ln_residual_sk(
    const float* __restrict__ A, const float* __restrict__ PA,
    const float* __restrict__ PB, const float* __restrict__ bb,
    const float* __restrict__ gamma, const float* __restrict__ beta,
    float* __restrict__ out)
{
  const int row = blockIdx.x, tid = threadIdx.x;
  const int wave = tid >> 6, lane = tid & 63;
  const size_t off = (size_t)row * H + tid * 4;
  const float4 av = *(const float4*)(A + off);
  const float4 pa = *(const float4*)(PA + off);
  const float4 pb = *(const float4*)(PB + off);
  const float4 bw = *(const float4*)(bb + tid * 4);
  float4 y;
  y.x = av.x + (pa.x + pb.x) * bw.x;
  y.y = av.y + (pa.y + pb.y) * bw.y;
  y.z = av.z + (pa.z + pb.z) * bw.z;
  y.w = av.w + (pa.w + pb.w) * bw.w;
  float s  = y.x + y.y + y.z + y.w;
  float ss = y.x*y.x + y.y*y.y + y.z*y.z + y.w*y.w;
#pragma unroll
  for (int o = 32; o >= 1; o >>= 1) { s += __shfl_xor(s, o); ss += __shfl_xor(ss, o); }
  __shared__ float red[2][4];
  if (lane == 0) { red[0][wave] = s; red[1][wave] = ss; }
  __syncthreads();
  s  = red[0][0] + red[0][1] + red[0][2] + red[0][3];
  ss = red[1][0] + red[1][1] + red[1][2] + red[1][3];
  const float mean = s * (1.0f / (float)H);
  float var = (ss - (float)H * mean * mean) * (1.0f / (float)(H - 1));
  var = fmaxf(var, 0.0f);
  const float inv = 1.0f / (sqrtf(var) + 1e-6f);
  const float4 gv = *(const float4*)(gamma + tid * 4);
  const float4 be = *(const float4*)(beta + tid * 4);
  float4 o;
  o.x = gv.x * (y.x - mean) * inv + be.x;
  o.y = gv.y * (y.y - mean) * inv + be.y;
  o.z = gv.z * (y.z - mean) * inv + be.z;
  o.w = gv.w * (y.w - mean) * inv + be.w;
  *(float4*)(out + off) = o;
}

// ---------------------------------------------------------------------------
extern "C" void kernel_launch(void* const* d_in, const int* in_sizes, int n_in,
                              void* d_out, int out_size, void* d_ws, size_t ws_size,
                              hipStream_t stream)
{
  const float* x    = (const float*)d_in[0];
  const float* Wqkv = (const float*)d_in[1];
  const float* bqkv = (const float*)d_in[2];
  const float* W1   = (const float*)d_in[3];
  const float* b1   = (const float*)d_in[4];
  const float* W2   = (const float*)d_in[5];
  const float* b2   = (const float*)d_in[6];
  const float* g1   = (const float*)d_in[7];
  const float* be1  = (const float*)d_in[8];
  const float* g2   = (const float*)d_in[9];
  const float* be2  = (const float*)d_in[10];
  float* out = (float*)d_out;
  char* w = (char*)d_ws;

  // ---- workspace map (bytes); regions time-multiplexed, peak ~145 MB ----
  float* qkv  = (float*)(w + 0);          // 50.33M  steps 3-4
  u16*   h1b  = (u16*)  (w + 0);          // 33.55M  steps 9-11
  u16*   W1T  = (u16*)  (w + 35651584);   // 8.39M   steps 8-9
  u16*   W2T  = (u16*)  (w + 44040192);   // 8.39M   steps 10-11
  u16*   xh   = (u16*)  (w + 52428800);   // 8.39M   steps 1-3
  u16*   xl   = (u16*)  (w + 60817408);   // 8.39M   steps 1-3
  u16*   Qh   = (u16*)  (w + 52428800);   // 8.39M   steps 4-6 (over xh)
  u16*   Ql   = (u16*)  (w + 60817408);   // 8.39M   steps 4-6 (over xl)
  u16*   WqTh = (u16*)  (w + 69206016);   // 6.29M   steps 2-3
  u16*   WqTl = (u16*)  (w + 75497472);   // 6.29M   steps 2-3
  u16*   Khb  = (u16*)  (w + 69206016);   // 8.39M   steps 4-6 (over WqT*)
  u16*   Klb  = (u16*)  (w + 77594624);   // 8.39M   steps 4-6
  u16*   Vbb  = (u16*)  (w + 85983232);   // 8.39M   steps 4-5
  u16*   VTb  = (u16*)  (w + 94371840);   // 8.39M   steps 5-6
  float* pAB  = (float*)(w + 52428800);   // 33.55M  steps 11-12 (over Q/K dead)
  float* attn = (float*)(w + 102760448);  // 16.78M  steps 6-7
  float* ln1  = (float*)(w + 119537664);  // 16.78M  steps 7-12
  u16*   ln1b = (u16*)  (w + 136314880);  // 8.39M   steps 7-9

  // 1. split x -> bf16 hi/lo
  split_hl<<<4096, 256, 0, stream>>>(x, xh, xl);
  // 2. Wqkv^T hi/lo bf16
  transpose_bf16<1><<<dim3(48, 16), 256, 0, stream>>>(Wqkv, WqTh, WqTl, H, 3*H);
  // 3. qkv = (x @ Wqkv) * bqkv  [split MFMA, 2-phase; V-col Bl staging skipped]
  mfma_gemm<1,0,0,1,0,0><<<24 * 32, 256, 0, stream>>>(xh, xl, WqTh, WqTl, bqkv,
                                                      qkv, nullptr, M_TOK, 3*H, H);
  // 4. repack heads -> scaled/split bf16 Q,K + bf16 V
  repack_qkv<<<M_TOK, 256, 0, stream>>>(qkv, Qh, Ql, Khb, Klb, Vbb);
  // 5. V transpose
  vtrans<<<dim3(T/64, B*NH), 256, 0, stream>>>(Vbb, VTb);
  // 6. attention (MFMA, swapped-operand, intra-block split-KV, 8w x 32r)
  flash_attn_mfma<<<512, 512, 0, stream>>>(Qh, Ql, Khb, Klb, VTb, attn);
  // 7. ln1 = LN(x + attn) (+ bf16 copy)
  ln_residual<<<M_TOK, 256, 0, stream>>>(x, attn, g1, be1, ln1, ln1b);
  // 8. W1^T bf16
  transpose_bf16<0><<<dim3(64, 16), 256, 0, stream>>>(W1, W1T, nullptr, H, FF);
  // 9. h1 = relu((ln1 @ W1) * b1) -> bf16  [XCD-chunked, 3-deep]
  mfma_gemm<0,1,1,0,1,0><<<32 * 32, 256, 0, stream>>>(ln1b, nullptr, W1T, nullptr, b1,
                                                      nullptr, h1b, M_TOK, FF, H);
  // 10. W2^T bf16
  transpose_bf16<0><<<dim3(16, 64), 256, 0, stream>>>(W2, W2T, nullptr, FF, H);
  // 11. ffn partials = h1 @ W2 (split-K=2, raw fp32)  [XCD-chunked, 3-deep]
  mfma_gemm<0,0,0,0,1,1><<<dim3(8 * 32, 2), 256, 0, stream>>>(h1b, nullptr, W2T, nullptr, nullptr,
                                                              pAB, nullptr, M_TOK, H, FF);
  // 12. out = LN(ln1 + (pA+pB)*b2)
  ln_residual_sk<<<M_TOK, 256, 0, stream>>>(ln1, pAB, pAB + 4194304, b2, g2, be2, out);
}

// Round 5
// 302.943 us; speedup vs baseline: 1.1842x; 1.0555x over previous
//
#include <hip/hip_runtime.h>
#include <math.h>

// Sizes (fixed for this problem)
#define B 2
#define T 2048
#define H 1024
#define NH 16
#define HD 64
#define FF 4096
#define M_TOK (B*T)          // 4096 token rows
#define LOG2E 1.4426950408889634f

typedef unsigned short u16;
typedef __attribute__((ext_vector_type(8))) short bf16x8;
typedef __attribute__((ext_vector_type(4))) float f32x4;

// counted-vmcnt barrier: wait until only N of this wave's vmem ops remain,
// then workgroup barrier. Single asm with "memory" clobber so no memory op
// (gload_lds / ds_read) is reordered across it.
// NOTE (r8-r10 lesson): counted-vmcnt pipelines are only safe when EVERY
// LDS buffer is >=3 slots deep (overwrite target >=2 iterations stale).
// NOTE (R2 lesson): direct-to-register global V loads regress badly — the
// strided fragment pattern (rows T apart) turns each wave load into 16
// scattered L1 lines; keep V in LDS.
// NOTE (R3 lesson): split-KV partials must merge ON-CHIP. Global fp32
// partials (16B granules @ 256B stride) write-amplified ~6x and evicted
// the K/V working set from L2 (FETCH 20->195MB).
// NOTE (R4 lesson): 32-key KV tiles break the V bank-swizzle (64B rows ≡
// 16 mod 32 banks -> 4-way conflicts, 2.1M counted) and double per-tile
// softmax fixed costs. The R1 shape (8 waves x 16 rows, 64-key tiles,
// K hi/lo + V in LDS, 72KB, 3-deep ring) is the verified local optimum:
// LDS ~66% / VALU ~53% / MFMA ~33%; all three restructures regressed.
#define WAITBAR3  asm volatile("s_waitcnt vmcnt(3)\n\ts_barrier" ::: "memory")
#define WAITBAR4  asm volatile("s_waitcnt vmcnt(4)\n\ts_barrier" ::: "memory")
#define WAITBAR0  asm volatile("s_waitcnt vmcnt(0)\n\ts_barrier" ::: "memory")

__device__ __forceinline__ u16 f2bf(float f) {
  union { float f; unsigned u; } v; v.f = f;
  const unsigned r = (v.u + 0x7FFFu + ((v.u >> 16) & 1u)) >> 16;
  return (u16)r;
}
__device__ __forceinline__ float bf2f(u16 h) {
  union { unsigned u; float f; } v; v.u = ((unsigned)h) << 16;
  return v.f;
}
__device__ __forceinline__ unsigned cvt_pk_bf16(float lo, float hi) {
  unsigned r;
  asm("v_cvt_pk_bf16_f32 %0, %1, %2" : "=v"(r) : "v"(lo), "v"(hi));
  return r;
}
__device__ __forceinline__ float m3(float a, float b, float c) {
  return fmaxf(fmaxf(a, b), c);      // clang fuses to v_max3_f32
}
// async global->LDS, 16B per lane; dest = wave-uniform base + lane*16
__device__ __forceinline__ void gload16(const u16* g, u16* l) {
  __builtin_amdgcn_global_load_lds(
      (const __attribute__((address_space(1))) unsigned int*)g,
      (__attribute__((address_space(3))) unsigned int*)l, 16, 0, 0);
}

// ---------------------------------------------------------------------------
// split fp32 -> bf16 hi + bf16 lo (Dekker split; hi+lo ~ fp32 accurate)
// ---------------------------------------------------------------------------
__global__ __launch_bounds__(256) void split_hl(
    const float* __restrict__ in, u16* __restrict__ oh, u16* __restrict__ ol)
{
  const size_t i = ((size_t)blockIdx.x * 256 + threadIdx.x) * 4;
  const float4 v = *(const float4*)(in + i);
  union { u16 s[4]; uint2 u; } h, l;
  const float f[4] = {v.x, v.y, v.z, v.w};
#pragma unroll
  for (int j = 0; j < 4; ++j) {
    const u16 hb = f2bf(f[j]); h.s[j] = hb; l.s[j] = f2bf(f[j] - bf2f(hb));
  }
  *(uint2*)(oh + i) = h.u;
  *(uint2*)(ol + i) = l.u;
}

// ---------------------------------------------------------------------------
// transpose-convert: in [K][N] fp32 -> out [N][K] bf16 (hi, + lo if SPLIT)
// ---------------------------------------------------------------------------
template<int SPLIT>
__global__ __launch_bounds__(256) void transpose_bf16(
    const float* __restrict__ in, u16* __restrict__ oh, u16* __restrict__ ol,
    int K, int N)
{
  __shared__ float tile[64][69];
  const int k0 = blockIdx.y * 64, n0 = blockIdx.x * 64;
  const int tid = threadIdx.x;
  const int r = tid >> 4, c4 = (tid & 15) * 4;
#pragma unroll
  for (int i = 0; i < 4; ++i) {
    const float4 v = *(const float4*)(in + (size_t)(k0 + i*16 + r) * N + n0 + c4);
    tile[i*16+r][c4]   = v.x; tile[i*16+r][c4+1] = v.y;
    tile[i*16+r][c4+2] = v.z; tile[i*16+r][c4+3] = v.w;
  }
  __syncthreads();
  const int n = tid >> 2, kq = tid & 3;
  union { u16 s[8]; int4 v; } ph0, ph1, pl0, pl1;
#pragma unroll
  for (int j = 0; j < 8; ++j) {
    const float f0 = tile[kq*16 + j][n];
    const float f1 = tile[kq*16 + 8 + j][n];
    const u16 h0 = f2bf(f0), h1 = f2bf(f1);
    ph0.s[j] = h0; ph1.s[j] = h1;
    if (SPLIT) { pl0.s[j] = f2bf(f0 - bf2f(h0)); pl1.s[j] = f2bf(f1 - bf2f(h1)); }
  }
  u16* po = oh + (size_t)(n0 + n) * K + k0 + kq * 16;
  *(int4*)po = ph0.v; *(int4*)(po + 8) = ph1.v;
  if (SPLIT) {
    u16* pl = ol + (size_t)(n0 + n) * K + k0 + kq * 16;
    *(int4*)pl = pl0.v; *(int4*)(pl + 8) = pl1.v;
  }
}

// ---------------------------------------------------------------------------
// batched W1^T + W2^T transpose in ONE launch (independent inputs, identical
// body; saves a dispatch). bid<1024 -> W1 [H][FF]; else W2 [FF][H].
// ---------------------------------------------------------------------------
__global__ __launch_bounds__(256) void transpose_w12(
    const float* __restrict__ W1_, u16* __restrict__ W1T_,
    const float* __restrict__ W2_, u16* __restrict__ W2T_)
{
  __shared__ float tile[64][69];
  int bid = blockIdx.x;
  const float* in; u16* oh; int K, N, bx, by;
  if (bid < 1024) { in = W1_; oh = W1T_; K = H;  N = FF; bx = bid & 63; by = bid >> 6; }
  else { bid -= 1024; in = W2_; oh = W2T_; K = FF; N = H;  bx = bid & 15; by = bid >> 4; }
  const int k0 = by * 64, n0 = bx * 64;
  const int tid = threadIdx.x;
  const int r = tid >> 4, c4 = (tid & 15) * 4;
#pragma unroll
  for (int i = 0; i < 4; ++i) {
    const float4 v = *(const float4*)(in + (size_t)(k0 + i*16 + r) * N + n0 + c4);
    tile[i*16+r][c4]   = v.x; tile[i*16+r][c4+1] = v.y;
    tile[i*16+r][c4+2] = v.z; tile[i*16+r][c4+3] = v.w;
  }
  __syncthreads();
  const int n = tid >> 2, kq = tid & 3;
  union { u16 s[8]; int4 v; } ph0, ph1;
#pragma unroll
  for (int j = 0; j < 8; ++j) {
    ph0.s[j] = f2bf(tile[kq*16 + j][n]);
    ph1.s[j] = f2bf(tile[kq*16 + 8 + j][n]);
  }
  u16* po = oh + (size_t)(n0 + n) * K + k0 + kq * 16;
  *(int4*)po = ph0.v; *(int4*)(po + 8) = ph1.v;
}

// ---------------------------------------------------------------------------
// MFMA GEMM: C[M,N] = (A @ B^T) * bias[N]  (A [M][K] bf16, B [N][K] bf16)
// 128x128 tile, BK=32, global_load_lds staging, XCD-chunked 1-D grid.
// DEEP3 (non-split only): 3-slot LDS + counted vmcnt(4) barriers. 24KB.
// SPLIT: 2-phase double-buffered (__syncthreads drains vmcnt -> safe).
// PARTIAL: split-K=2 over blockIdx.y; raw fp32 partials (no bias/relu).
// QKV3: V fragments (qkv k-index 2) skip the hi/lo correction MFMAs, and
//       their Bl staging chunks are skipped entirely (never read).
// ---------------------------------------------------------------------------
__device__ __forceinline__ int swz(int r, int kq) {
  return r * 32 + ((kq ^ ((r >> 1) & 3)) * 8);
}

template<int SPLIT, int RELU, int OBF, int QKV3, int DEEP3, int PARTIAL>
__global__ __launch_bounds__(256) void mfma_gemm(
    const u16* __restrict__ Ah, const u16* __restrict__ Al,
    const u16* __restrict__ Bh, const u16* __restrict__ Bl,
    const float* __restrict__ bias,
    float* __restrict__ Cf, u16* __restrict__ Cb,
    int M, int N, int K)
{
  __shared__ u16 lds[DEEP3 ? 24576 : (SPLIT ? 32768 : 16384)];
  const int BUFSZ = SPLIT ? 16384 : 8192;
  const int tid = threadIdx.x;
  // XCD-chunked decode: xcd=bid&7 owns M-panels [4*xcd, 4*xcd+4)
  const int bid = blockIdx.x;
  const int xcd = bid & 7;
  const int idx = bid >> 3;
  const int row0 = (xcd * 4 + (idx & 3)) * 128;
  const int col0 = (idx >> 2) * 128;
  const int wv = tid >> 6, lane = tid & 63;
  const int wr = wv >> 1, wc = wv & 1;
  const int kq = lane >> 4, fr = lane & 15;

  int kb = 0, kE = K;
  if (PARTIAL) {
    const int khf = blockIdx.y;
    kb = khf * (K >> 1); kE = kb + (K >> 1);
    Cf += (size_t)khf * ((size_t)M * N);
  }

  f32x4 acc[4][4] = {};

  // stage one 128x32 bf16 array (8 chunks of 1KB); wave wv does chunks 2wv,2wv+1
#define GSTAGE(lbase, gb, rowbase, kk) do { \
    _Pragma("unroll") \
    for (int t_ = 0; t_ < 2; ++t_) { \
      const int c_ = wv * 2 + t_; \
      const int idx_ = c_ * 64 + lane; \
      const int r_ = idx_ >> 2; \
      const int kq_ = (idx_ & 3) ^ ((r_ >> 1) & 3); \
      gload16((gb) + (size_t)((rowbase) + r_) * K + (kk) + kq_ * 8, \
              &lds[(lbase) + c_ * 512]); \
    } } while (0)

  // Bl staging with V-group chunk skip (chunk c covers 16-col group
  // (col0>>4)+c; k-index %3==2 groups never read their b_l fragments).
#define BLSTAGE(lbase, kk) do { \
    _Pragma("unroll") \
    for (int t_ = 0; t_ < 2; ++t_) { \
      const int c_ = wv * 2 + t_; \
      if (!QKV3 || ((((col0 >> 4) + c_) % 3) != 2)) { \
        const int idx_ = c_ * 64 + lane; \
        const int r_ = idx_ >> 2; \
        const int kq_ = (idx_ & 3) ^ ((r_ >> 1) & 3); \
        gload16(Bl + (size_t)(col0 + r_) * K + (kk) + kq_ * 8, \
                &lds[(lbase) + c_ * 512]); \
      } } } while (0)

  if (DEEP3) {
    // ---- 3-deep counted-vmcnt pipeline (non-split only; all slots 3-deep,
    // overwrite target is 2 iterations stale -> no write-after-read hazard) ----
    const int nk = (kE - kb) >> 5;
    GSTAGE(0, Ah, row0, kb);            GSTAGE(4096, Bh, col0, kb);
    GSTAGE(8192, Ah, row0, kb + 32);    GSTAGE(8192 + 4096, Bh, col0, kb + 32);
    WAITBAR4;                            // stage 0 ready; stage 1 in flight
    int cslot = 0, islot = 2;
    for (int i = 0; i < nk; ++i) {
      if (i + 2 < nk) {
        const int kk = kb + (i + 2) * 32;
        GSTAGE(islot * 8192, Ah, row0, kk);
        GSTAGE(islot * 8192 + 4096, Bh, col0, kk);
        islot = (islot == 2) ? 0 : islot + 1;
      }
      const int rb = cslot * 8192;
      bf16x8 a_h[4];
#pragma unroll
      for (int m = 0; m < 4; ++m)
        a_h[m] = *(const bf16x8*)&lds[rb + swz(wr*64 + m*16 + fr, kq)];
#pragma unroll
      for (int n = 0; n < 4; ++n) {
        const bf16x8 b_h = *(const bf16x8*)&lds[rb + 4096 + swz(wc*64 + n*16 + fr, kq)];
#pragma unroll
        for (int m = 0; m < 4; ++m)
          acc[m][n] = __builtin_amdgcn_mfma_f32_16x16x32_bf16(a_h[m], b_h, acc[m][n], 0, 0, 0);
      }
      cslot = (cslot == 2) ? 0 : cslot + 1;
      if (i + 1 < nk) { if (i + 2 < nk) WAITBAR4; else WAITBAR0; }
    }
  } else {
    // ---- 2-phase double-buffered (__syncthreads drains all counters) ----
    GSTAGE(0, Ah, row0, kb);
    GSTAGE(4096, Bh, col0, kb);
    if (SPLIT) { GSTAGE(8192, Al, row0, kb); BLSTAGE(12288, kb); }
    __syncthreads();

    int cur = 0;
    for (int k0 = kb; k0 < kE; k0 += 32) {
      const int nxt = cur ^ 1;
      if (k0 + 32 < kE) {
        GSTAGE(nxt*BUFSZ, Ah, row0, k0 + 32);
        GSTAGE(nxt*BUFSZ + 4096, Bh, col0, k0 + 32);
        if (SPLIT) { GSTAGE(nxt*BUFSZ + 8192, Al, row0, k0 + 32);
                     BLSTAGE(nxt*BUFSZ + 12288, k0 + 32); }
      }
      const int rb = cur * BUFSZ;
      bf16x8 a_h[4], a_l[4];
#pragma unroll
      for (int m = 0; m < 4; ++m) {
        a_h[m] = *(const bf16x8*)&lds[rb + swz(wr*64 + m*16 + fr, kq)];
        if (SPLIT) a_l[m] = *(const bf16x8*)&lds[rb + 8192 + swz(wr*64 + m*16 + fr, kq)];
      }
#pragma unroll
      for (int n = 0; n < 4; ++n) {
        const bf16x8 b_h = *(const bf16x8*)&lds[rb + 4096 + swz(wc*64 + n*16 + fr, kq)];
#pragma unroll
        for (int m = 0; m < 4; ++m)
          acc[m][n] = __builtin_amdgcn_mfma_f32_16x16x32_bf16(a_h[m], b_h, acc[m][n], 0, 0, 0);
        if (SPLIT) {
          const bool dolo = !QKV3 || ((((col0 >> 4) + wc * 4 + n) % 3) != 2);
          if (dolo) {
            const bf16x8 b_l = *(const bf16x8*)&lds[rb + 12288 + swz(wc*64 + n*16 + fr, kq)];
#pragma unroll
            for (int m = 0; m < 4; ++m) {
              acc[m][n] = __builtin_amdgcn_mfma_f32_16x16x32_bf16(a_h[m], b_l, acc[m][n], 0, 0, 0);
              acc[m][n] = __builtin_amdgcn_mfma_f32_16x16x32_bf16(a_l[m], b_h, acc[m][n], 0, 0, 0);
            }
          }
        }
      }
      __syncthreads();
      cur = nxt;
    }
  }
#undef GSTAGE
#undef BLSTAGE

  const int orow0 = row0 + wr * 64, ocol0 = col0 + wc * 64;
#pragma unroll
  for (int n = 0; n < 4; ++n) {
    const int col = ocol0 + n * 16 + fr;
    const float bs = PARTIAL ? 1.0f : bias[col];
#pragma unroll
    for (int m = 0; m < 4; ++m) {
      const int rbase = orow0 + m * 16 + (lane >> 4) * 4;
#pragma unroll
      for (int j = 0; j < 4; ++j) {
        float v = acc[m][n][j] * bs;
        if (RELU) v = fmaxf(v, 0.0f);
        const size_t off = (size_t)(rbase + j) * N + col;
        if (OBF) Cb[off] = f2bf(v); else Cf[off] = v;
      }
    }
  }
}

// ---------------------------------------------------------------------------
// Repack qkv [B,T,3072] -> bf16 arrays: Qh/Ql (scaled by log2e/32, split),
// Kh/Kl (split), Vb (bf16), all [B*NH][T][HD]. Channel o = d*48 + k*16 + h.
// ---------------------------------------------------------------------------
__global__ __launch_bounds__(256) void repack_qkv(
    const float* __restrict__ qkv,
    u16* __restrict__ Qh, u16* __restrict__ Ql,
    u16* __restrict__ Kh, u16* __restrict__ Kl, u16* __restrict__ Vb)
{
  const int bt = blockIdx.x;
  const int b = bt >> 11, t = bt & (T - 1);
  const int tid = threadIdx.x;
  __shared__ float Ls[3 * H];
  const float* src = qkv + (size_t)bt * (3 * H);
#pragma unroll
  for (int i = 0; i < 3; ++i) {
    const int c4 = i * 256 + tid;
    *(float4*)&Ls[c4 * 4] = *(const float4*)(src + c4 * 4);
  }
  __syncthreads();
  const float qscale = LOG2E / 32.0f;
#pragma unroll
  for (int i = 0; i < 4; ++i) {
    const int j = i * 256 + tid;
    const int h = j >> 6, d = j & 63;
    const size_t dst = (((size_t)(b * NH + h)) * T + t) * HD + d;
    const float q = Ls[d * 48 + h] * qscale;
    const u16 qhb = f2bf(q);
    Qh[dst] = qhb; Ql[dst] = f2bf(q - bf2f(qhb));
    const float k = Ls[d * 48 + 16 + h];
    const u16 khb = f2bf(k);
    Kh[dst] = khb; Kl[dst] = f2bf(k - bf2f(khb));
    Vb[dst] = f2bf(Ls[d * 48 + 32 + h]);
  }
}

// ---------------------------------------------------------------------------
// Vb [bh][T][HD] bf16 -> VT [bh][HD][T] bf16 (64x64 tiles via LDS)
// ---------------------------------------------------------------------------
__global__ __launch_bounds__(256) void vtrans(
    const u16* __restrict__ Vb, u16* __restrict__ VT)
{
  __shared__ u16 Ls[64][72];
  const int bh = blockIdx.y, t0 = blockIdx.x * 64;
  const int tid = threadIdx.x;
  const int r = tid >> 2, c = (tid & 3) * 16;
  const size_t src = ((size_t)bh * T + t0 + r) * HD + c;
  *(int4*)&Ls[r][c]     = *(const int4*)(Vb + src);
  *(int4*)&Ls[r][c + 8] = *(const int4*)(Vb + src + 8);
  __syncthreads();
  const int d = tid >> 2, tc = (tid & 3) * 16;
  u16 buf[16];
#pragma unroll
  for (int i = 0; i < 16; ++i) buf[i] = Ls[tc + i][d];
  u16* dst = VT + ((size_t)bh * HD + d) * T + t0 + tc;
  *(int4*)dst       = *(int4*)&buf[0];
  *(int4*)(dst + 8) = *(int4*)&buf[8];
}

// ---------------------------------------------------------------------------
// sigma: LDS K-row r holds key sigma(r) so that the QK^T C-layout hands each
// lane exactly the 8-consecutive-key fragments PV's B-operand needs.
// ---------------------------------------------------------------------------
__device__ __forceinline__ int sigma_k(int r) {
  return ((r >> 5) << 5) | (((r >> 2) & 3) << 3) | (((r >> 4) & 1) << 2) | (r & 3);
}

// ---------------------------------------------------------------------------
// MFMA flash attention, swapped-operand. 8 waves x 16 q-rows (512 threads),
// KV tile 64. K hi/lo + VT staged in LDS, 3-deep counted-vmcnt pipeline
// (12KB/slot, 36KB... 3x12288 u16 = 72KB total). XCD-clustered grid;
// defer-max (THR=8); lsum via ones-A MFMA; setprio around MFMA clusters.
// 72KB LDS x 2 blocks/CU = 144KB <= 160KB -> 16 waves/CU (4/SIMD).
// This is the VERIFIED 93us configuration (R1) — see R2/R3/R4 notes above
// for the three restructures that regressed from it.
// ---------------------------------------------------------------------------
__global__ __launch_bounds__(512, 4) void flash_attn_mfma(
    const u16* __restrict__ Qh, const u16* __restrict__ Ql,
    const u16* __restrict__ Kh, const u16* __restrict__ Kl,
    const u16* __restrict__ VT, float* __restrict__ Out)
{
  __shared__ u16 sm[3 * 12288];  // slot: KH [0,4K) | KL [4K,8K) | VT [8K,12K) u16
  // XCD-clustered decode: xcd = i&7 owns heads 4*xcd..4*xcd+3
  const int i = blockIdx.x;
  const int slot = i >> 3;
  const int bh = (i & 7) * 4 + (slot >> 4);
  const int row0 = (slot & 15) * 128;
  const int b = bh >> 4, h = bh & 15;
  const int tid = threadIdx.x, wave = tid >> 6, lane = tid & 63;
  const int fr = lane & 15, kq = lane >> 4;

  // Q fragments (B-operand: col=q=fr, k=d=kq*8 within ks*32); wave owns
  // q-rows [row0 + wave*16, +16)
  bf16x8 qh[2], ql[2];
  const size_t qoff = ((size_t)bh * T + row0 + wave*16 + fr) * HD + kq*8;
#pragma unroll
  for (int ks = 0; ks < 2; ++ks) {
    qh[ks] = *(const bf16x8*)(Qh + qoff + ks*32);
    ql[ks] = *(const bf16x8*)(Ql + qoff + ks*32);
  }

  bf16x8 ones8;
#pragma unroll
  for (int z = 0; z < 8; ++z) ones8[z] = (short)0x3F80;

  f32x4 o[4] = {};
  f32x4 oex = {};                      // lsum accumulator (all 4 rows equal)
  float m_ = -1e30f;

  // staging: wave w stages chunk w (1KB) of each of the 3 arrays (8 waves
  // cover the 8 chunks). Global pointers advance by a constant per KV tile.
  const int c_ = wave;
  const int r0_ = c_ * 8 + (lane >> 3), s_ = lane & 7;
  const int cd0 = s_ ^ (r0_ & 7);
  const int k0_ = sigma_k(r0_);
  const u16* pKh0 = Kh + ((size_t)bh*T + k0_)*HD + cd0*8;
  const u16* pKl0 = Kl + ((size_t)bh*T + k0_)*HD + cd0*8;
  const u16* pV0  = VT + ((size_t)bh*HD + r0_)*T + cd0*8;

#define FSTAGE(sb) do { \
    gload16(pKh0, &sm[(sb) + c_*512]); \
    gload16(pKl0, &sm[(sb) + 4096 + c_*512]); \
    gload16(pV0,  &sm[(sb) + 8192 + c_*512]); \
    pKh0 += 64*HD; pKl0 += 64*HD; pV0 += 64; \
  } while (0)

  FSTAGE(0);
  FSTAGE(12288);
  WAITBAR3;                  // tile 0 ready (3 loads/wave); tile 1 in flight
  int cslot = 0, islot = 2;

  const int NT = T / 64;
  for (int t = 0; t < NT; ++t) {
    if (t + 2 < NT) {
      FSTAGE(islot * 12288);
      islot = (islot == 2) ? 0 : islot + 1;
    }
    const u16* smb = &sm[cslot * 12288];

    // ---- QK^T (swapped): s[n], keys sigma(16n+4kq+jj), q=fr
    f32x4 s[4] = {};
    __builtin_amdgcn_s_setprio(1);
#pragma unroll
    for (int ks = 0; ks < 2; ++ks) {
#pragma unroll
      for (int n = 0; n < 4; ++n) {
        const int kr = n * 16 + fr;
        const int sl = ((ks*4 + kq) ^ (kr & 7)) * 8;
        const bf16x8 kh_ = *(const bf16x8*)&smb[kr*64 + sl];
        const bf16x8 kl_ = *(const bf16x8*)&smb[4096 + kr*64 + sl];
        s[n] = __builtin_amdgcn_mfma_f32_16x16x32_bf16(kh_, qh[ks], s[n], 0, 0, 0);
        s[n] = __builtin_amdgcn_mfma_f32_16x16x32_bf16(kl_, qh[ks], s[n], 0, 0, 0);
        s[n] = __builtin_amdgcn_mfma_f32_16x16x32_bf16(kh_, ql[ks], s[n], 0, 0, 0);
      }
    }
    __builtin_amdgcn_s_setprio(0);

    // ---- defer-max softmax (THR=8)
    const float g0 = m3(s[0][0], s[0][1], s[0][2]);
    const float g1 = m3(s[0][3], s[1][0], s[1][1]);
    const float g2 = m3(s[1][2], s[1][3], s[2][0]);
    const float g3 = m3(s[2][1], s[2][2], s[2][3]);
    const float g4 = m3(s[3][0], s[3][1], s[3][2]);
    float mx = fmaxf(m3(g0, g1, g2), m3(g3, g4, s[3][3]));
    mx = fmaxf(mx, __shfl_xor(mx, 16));
    mx = fmaxf(mx, __shfl_xor(mx, 32));
    if (!__all(mx <= m_ + 8.0f)) {      // record tile (~10%): rescale
      const float mn = fmaxf(m_, mx);
      const float fsc = exp2f(m_ - mn);
      m_ = mn;
#pragma unroll
      for (int n = 0; n < 4; ++n) {
        o[n][0] *= fsc; o[n][1] *= fsc;
        o[n][2] *= fsc; o[n][3] *= fsc;
      }
      oex[0] *= fsc; oex[1] *= fsc; oex[2] *= fsc; oex[3] *= fsc;
    }

    float p[4][4];
#pragma unroll
    for (int n = 0; n < 4; ++n)
#pragma unroll
      for (int jj = 0; jj < 4; ++jj)
        p[n][jj] = exp2f(s[n][jj] - m_);

    unsigned pk[4][2];
#pragma unroll
    for (int n = 0; n < 4; ++n) {
      pk[n][0] = cvt_pk_bf16(p[n][0], p[n][1]);
      pk[n][1] = cvt_pk_bf16(p[n][2], p[n][3]);
    }

    // ---- in-reg P -> PV (+ lsum MFMA); V^T fragments from LDS
    __builtin_amdgcn_s_setprio(1);
#pragma unroll
    for (int ks = 0; ks < 2; ++ks) {
      union { unsigned u[4]; bf16x8 v; } pb;
      pb.u[0] = pk[2*ks][0];   pb.u[1] = pk[2*ks][1];
      pb.u[2] = pk[2*ks+1][0]; pb.u[3] = pk[2*ks+1][1];
#pragma unroll
      for (int n = 0; n < 4; ++n) {
        const int dr = n * 16 + fr;
        const bf16x8 vf = *(const bf16x8*)&smb[8192 + dr*64 + (((ks*4 + kq) ^ (dr & 7)) * 8)];
        o[n] = __builtin_amdgcn_mfma_f32_16x16x32_bf16(vf, pb.v, o[n], 0, 0, 0);
      }
      oex = __builtin_amdgcn_mfma_f32_16x16x32_bf16(ones8, pb.v, oex, 0, 0, 0);
    }
    __builtin_amdgcn_s_setprio(0);

    cslot = (cslot == 2) ? 0 : cslot + 1;
    if (t + 1 < NT) { if (t + 2 < NT) WAITBAR3; else WAITBAR0; }
  }
#undef FSTAGE

  // ---- epilogue: O^T frag has q=fr, d = 16n + 4kq + jj (jj contiguous)
  {
    const float inv = 1.0f / oex[0];
    const size_t qrow = (size_t)b * T + row0 + wave*16 + fr;
#pragma unroll
    for (int n = 0; n < 4; ++n) {
      float4 ov;
      ov.x = o[n][0] * inv; ov.y = o[n][1] * inv;
      ov.z = o[n][2] * inv; ov.w = o[n][3] * inv;
      *(float4*)(Out + qrow * H + h * HD + n * 16 + kq * 4) = ov;
    }
  }
}

// ---------------------------------------------------------------------------
// out = LN(a + b) * gamma + beta; ddof=1, eps on std. Optional bf16 copy.
// ---------------------------------------------------------------------------
__global__ __launch_bounds__(256) void ln_residual(
    const float* __restrict__ A, const float* __restrict__ Bz,
    const float* __restrict__ gamma, const float* __restrict__ beta,
    float* __restrict__ out, u16* __restrict__ obf)
{
  const int row = blockIdx.x, tid = threadIdx.x;
  const int wave = tid >> 6, lane = tid & 63;
  const size_t off = (size_t)row * H + tid * 4;
  const float4 av = *(const float4*)(A + off);
  const float4 bv = *(const float4*)(Bz + off);
  float4 y; y.x = av.x + bv.x; y.y = av.y + bv.y; y.z = av.z + bv.z; y.w = av.w + bv.w;
  float s  = y.x + y.y + y.z + y.w;
  float ss = y.x*y.x + y.y*y.y + y.z*y.z + y.w*y.w;
#pragma unroll
  for (int o = 32; o >= 1; o >>= 1) { s += __shfl_xor(s, o); ss += __shfl_xor(ss, o); }
  __shared__ float red[2][4];
  if (lane == 0) { red[0][wave] = s; red[1][wave] = ss; }
  __syncthreads();
  s  = red[0][0] + red[0][1] + red[0][2] + red[0][3];
  ss = red[1][0] + red[1][1] + red[1][2] + red[1][3];
  const float mean = s * (1.0f / (float)H);
  float var = (ss - (float)H * mean * mean) * (1.0f / (float)(H - 1));
  var = fmaxf(var, 0.0f);
  const float inv = 1.0f / (sqrtf(var) + 1e-6f);
  const float4 gv = *(const float4*)(gamma + tid * 4);
  const float4 be = *(const float4*)(beta + tid * 4);
  float4 o;
  o.x = gv.x * (y.x - mean) * inv + be.x;
  o.y = gv.y * (y.y - mean) * inv + be.y;
  o.z = gv.z * (y.z - mean) * inv + be.z;
  o.w = gv.w * (y.w - mean) * inv + be.w;
  *(float4*)(out + off) = o;
  if (obf) {
    union { u16 s[4]; uint2 u; } pk;
    pk.s[0] = f2bf(o.x); pk.s[1] = f2bf(o.y); pk.s[2] = f2bf(o.z); pk.s[3] = f2bf(o.w);
    *(uint2*)(obf + off) = pk.u;
  }
}

// ---------------------------------------------------------------------------
// split-K merge + LN: out = LN(a + (pA+pB)*bb) * gamma + beta
// ---------------------------------------------------------------------------
__global__ __launch_bounds__(256) void ln_residual_sk(
    const float* __restrict__ A, const float* __restrict__ PA,
    const float* __restrict__ PB, const float* __restrict__ bb,
    const float* __restrict__ gamma, const float* __restrict__ beta,
    float* __restrict__ out)
{
  const int row = blockIdx.x, tid = threadIdx.x;
  const int wave = tid >> 6, lane = tid & 63;
  const size_t off = (size_t)row * H + tid * 4;
  const float4 av = *(const float4*)(A + off);
  const float4 pa = *(const float4*)(PA + off);
  const float4 pb = *(const float4*)(PB + off);
  const float4 bw = *(const float4*)(bb + tid * 4);
  float4 y;
  y.x = av.x + (pa.x + pb.x) * bw.x;
  y.y = av.y + (pa.y + pb.y) * bw.y;
  y.z = av.z + (pa.z + pb.z) * bw.z;
  y.w = av.w + (pa.w + pb.w) * bw.w;
  float s  = y.x + y.y + y.z + y.w;
  float ss = y.x*y.x + y.y*y.y + y.z*y.z + y.w*y.w;
#pragma unroll
  for (int o = 32; o >= 1; o >>= 1) { s += __shfl_xor(s, o); ss += __shfl_xor(ss, o); }
  __shared__ float red[2][4];
  if (lane == 0) { red[0][wave] = s; red[1][wave] = ss; }
  __syncthreads();
  s  = red[0][0] + red[0][1] + red[0][2] + red[0][3];
  ss = red[1][0] + red[1][1] + red[1][2] + red[1][3];
  const float mean = s * (1.0f / (float)H);
  float var = (ss - (float)H * mean * mean) * (1.0f / (float)(H - 1));
  var = fmaxf(var, 0.0f);
  const float inv = 1.0f / (sqrtf(var) + 1e-6f);
  const float4 gv = *(const float4*)(gamma + tid * 4);
  const float4 be = *(const float4*)(beta + tid * 4);
  float4 o;
  o.x = gv.x * (y.x - mean) * inv + be.x;
  o.y = gv.y * (y.y - mean) * inv + be.y;
  o.z = gv.z * (y.z - mean) * inv + be.z;
  o.w = gv.w * (y.w - mean) * inv + be.w;
  *(float4*)(out + off) = o;
}

// ---------------------------------------------------------------------------
extern "C" void kernel_launch(void* const* d_in, const int* in_sizes, int n_in,
                              void* d_out, int out_size, void* d_ws, size_t ws_size,
                              hipStream_t stream)
{
  const float* x    = (const float*)d_in[0];
  const float* Wqkv = (const float*)d_in[1];
  const float* bqkv = (const float*)d_in[2];
  const float* W1   = (const float*)d_in[3];
  const float* b1   = (const float*)d_in[4];
  const float* W2   = (const float*)d_in[5];
  const float* b2   = (const float*)d_in[6];
  const float* g1   = (const float*)d_in[7];
  const float* be1  = (const float*)d_in[8];
  const float* g2   = (const float*)d_in[9];
  const float* be2  = (const float*)d_in[10];
  float* out = (float*)d_out;
  char* w = (char*)d_ws;

  // ---- workspace map (bytes); regions time-multiplexed, peak ~145 MB ----
  float* qkv  = (float*)(w + 0);          // 50.33M  steps 3-4
  u16*   h1b  = (u16*)  (w + 0);          // 33.55M  steps 9-11
  u16*   W1T  = (u16*)  (w + 35651584);   // 8.39M   steps 8-9
  u16*   W2T  = (u16*)  (w + 44040192);   // 8.39M   steps 8-11
  u16*   xh   = (u16*)  (w + 52428800);   // 8.39M   steps 1-3
  u16*   xl   = (u16*)  (w + 60817408);   // 8.39M   steps 1-3
  u16*   Qh   = (u16*)  (w + 52428800);   // 8.39M   steps 4-6 (over xh)
  u16*   Ql   = (u16*)  (w + 60817408);   // 8.39M   steps 4-6 (over xl)
  u16*   WqTh = (u16*)  (w + 69206016);   // 6.29M   steps 2-3
  u16*   WqTl = (u16*)  (w + 75497472);   // 6.29M   steps 2-3
  u16*   Khb  = (u16*)  (w + 69206016);   // 8.39M   steps 4-6 (over WqT*)
  u16*   Klb  = (u16*)  (w + 77594624);   // 8.39M   steps 4-6
  u16*   Vbb  = (u16*)  (w + 85983232);   // 8.39M   steps 4-5
  u16*   VTb  = (u16*)  (w + 94371840);   // 8.39M   steps 5-6
  float* pAB  = (float*)(w + 52428800);   // 33.55M  steps 11-12 (over Q/K dead)
  float* attn = (float*)(w + 102760448);  // 16.78M  steps 6-7
  float* ln1  = (float*)(w + 119537664);  // 16.78M  steps 7-12
  u16*   ln1b = (u16*)  (w + 136314880);  // 8.39M   steps 7-9

  // 1. split x -> bf16 hi/lo
  split_hl<<<4096, 256, 0, stream>>>(x, xh, xl);
  // 2. Wqkv^T hi/lo bf16
  transpose_bf16<1><<<dim3(48, 16), 256, 0, stream>>>(Wqkv, WqTh, WqTl, H, 3*H);
  // 3. qkv = (x @ Wqkv) * bqkv  [split MFMA, 2-phase; V-col Bl staging skipped]
  mfma_gemm<1,0,0,1,0,0><<<24 * 32, 256, 0, stream>>>(xh, xl, WqTh, WqTl, bqkv,
                                                      qkv, nullptr, M_TOK, 3*H, H);
  // 4. repack heads -> scaled/split bf16 Q,K + bf16 V
  repack_qkv<<<M_TOK, 256, 0, stream>>>(qkv, Qh, Ql, Khb, Klb, Vbb);
  // 5. V transpose
  vtrans<<<dim3(T/64, B*NH), 256, 0, stream>>>(Vbb, VTb);
  // 6. attention (MFMA, swapped-operand, XCD-clustered, 8-wave, 3-deep) — R1
  flash_attn_mfma<<<512, 512, 0, stream>>>(Qh, Ql, Khb, Klb, VTb, attn);
  // 7. ln1 = LN(x + attn) (+ bf16 copy)
  ln_residual<<<M_TOK, 256, 0, stream>>>(x, attn, g1, be1, ln1, ln1b);
  // 8. W1^T + W2^T bf16 in one batched launch
  transpose_w12<<<2048, 256, 0, stream>>>(W1, W1T, W2, W2T);
  // 9. h1 = relu((ln1 @ W1) * b1) -> bf16  [XCD-chunked, 3-deep]
  mfma_gemm<0,1,1,0,1,0><<<32 * 32, 256, 0, stream>>>(ln1b, nullptr, W1T, nullptr, b1,
                                                      nullptr, h1b, M_TOK, FF, H);
  // 11. ffn partials = h1 @ W2 (split-K=2, raw fp32)  [XCD-chunked, 3-deep]
  mfma_gemm<0,0,0,0,1,1><<<dim3(8 * 32, 2), 256, 0, stream>>>(h1b, nullptr, W2T, nullptr, nullptr,
                                                              pAB, nullptr, M_TOK, H, FF);
  // 12. out = LN(ln1 + (pA+pB)*b2)
  ln_residual_sk<<<M_TOK, 256, 0, stream>>>(ln1, pAB, pAB + 4194304, b2, g2, be2, out);
}

// Round 7
// 296.560 us; speedup vs baseline: 1.2097x; 1.0215x over previous
//
#include <hip/hip_runtime.h>
#include <math.h>

// Sizes (fixed for this problem)
#define B 2
#define T 2048
#define H 1024
#define NH 16
#define HD 64
#define FF 4096
#define M_TOK (B*T)          // 4096 token rows
#define LOG2E 1.4426950408889634f

typedef unsigned short u16;
typedef __attribute__((ext_vector_type(8))) short bf16x8;
typedef __attribute__((ext_vector_type(4))) float f32x4;

// counted-vmcnt barrier: wait until only N of this wave's vmem ops remain,
// then workgroup barrier. Single asm with "memory" clobber so no memory op
// (gload_lds / ds_read) is reordered across it.
// NOTE (r8-r10 lesson): counted-vmcnt pipelines are only safe when EVERY
// LDS buffer is >=3 slots deep (overwrite target >=2 iterations stale).
// NOTE (R2 lesson): direct-to-register global V loads regress badly — the
// strided fragment pattern (rows T apart) turns each wave load into 16
// scattered L1 lines; keep V in LDS.
// NOTE (R3 lesson): split-KV partials must merge ON-CHIP. Global fp32
// partials (16B granules @ 256B stride) write-amplified ~6x and evicted
// the K/V working set from L2 (FETCH 20->195MB).
// NOTE (R4 lesson): 32-key KV tiles break the V bank-swizzle (64B rows ≡
// 16 mod 32 banks -> 4-way conflicts) and double per-tile softmax costs.
// The R1 shape (8 waves x 16 rows, 64-key tiles, 72KB, 3-deep ring) is the
// verified local optimum; all three restructures regressed.
// NOTE (R6 lesson): WORKSPACE LIFETIME AUDIT before moving any launch.
// Moving W1T/W2T transposes to step 1 while leaving them inside the qkv
// region (0..50.3MB) let step 2 overwrite them -> NaN. Offsets now in the
// region freed by the dropped fp32 ln1 buffer.
#define WAITBAR3  asm volatile("s_waitcnt vmcnt(3)\n\ts_barrier" ::: "memory")
#define WAITBAR4  asm volatile("s_waitcnt vmcnt(4)\n\ts_barrier" ::: "memory")
#define WAITBAR0  asm volatile("s_waitcnt vmcnt(0)\n\ts_barrier" ::: "memory")

__device__ __forceinline__ u16 f2bf(float f) {
  union { float f; unsigned u; } v; v.f = f;
  const unsigned r = (v.u + 0x7FFFu + ((v.u >> 16) & 1u)) >> 16;
  return (u16)r;
}
__device__ __forceinline__ float bf2f(u16 h) {
  union { unsigned u; float f; } v; v.u = ((unsigned)h) << 16;
  return v.f;
}
__device__ __forceinline__ unsigned cvt_pk_bf16(float lo, float hi) {
  unsigned r;
  asm("v_cvt_pk_bf16_f32 %0, %1, %2" : "=v"(r) : "v"(lo), "v"(hi));
  return r;
}
__device__ __forceinline__ float m3(float a, float b, float c) {
  return fmaxf(fmaxf(a, b), c);      // clang fuses to v_max3_f32
}
// async global->LDS, 16B per lane; dest = wave-uniform base + lane*16
__device__ __forceinline__ void gload16(const u16* g, u16* l) {
  __builtin_amdgcn_global_load_lds(
      (const __attribute__((address_space(1))) unsigned int*)g,
      (__attribute__((address_space(3))) unsigned int*)l, 16, 0, 0);
}

// ---------------------------------------------------------------------------
// preprocess — ONE launch for all input-only work:
//   bid <  4096 : split x -> bf16 hi/lo (Dekker split)
//   bid <  4864 : Wqkv^T hi/lo bf16 (48x16 tiles of 64x64)
//   bid <  5888 : W1^T bf16 (64x16)
//   else        : W2^T bf16 (16x64)
// ---------------------------------------------------------------------------
__global__ __launch_bounds__(256) void preprocess(
    const float* __restrict__ x, u16* __restrict__ xh, u16* __restrict__ xl,
    const float* __restrict__ Wqkv, u16* __restrict__ WqTh, u16* __restrict__ WqTl,
    const float* __restrict__ W1_, u16* __restrict__ W1T_,
    const float* __restrict__ W2_, u16* __restrict__ W2T_)
{
  const int bid = blockIdx.x;
  const int tid = threadIdx.x;
  if (bid < 4096) {                       // ---- split_hl ----
    const size_t i = ((size_t)bid * 256 + tid) * 4;
    const float4 v = *(const float4*)(x + i);
    union { u16 s[4]; uint2 u; } h, l;
    const float f[4] = {v.x, v.y, v.z, v.w};
#pragma unroll
    for (int j = 0; j < 4; ++j) {
      const u16 hb = f2bf(f[j]); h.s[j] = hb; l.s[j] = f2bf(f[j] - bf2f(hb));
    }
    *(uint2*)(xh + i) = h.u;
    *(uint2*)(xl + i) = l.u;
    return;
  }
  // ---- transpose-convert paths (uniform per block) ----
  __shared__ float tile[64][69];
  const float* in; u16* oh; u16* ol = nullptr; int K, N, k0, n0, split = 0;
  if (bid < 4864) {
    const int tb = bid - 4096;
    in = Wqkv; oh = WqTh; ol = WqTl; K = H; N = 3*H; split = 1;
    n0 = (tb % 48) * 64; k0 = (tb / 48) * 64;
  } else if (bid < 5888) {
    const int tb = bid - 4864;
    in = W1_; oh = W1T_; K = H; N = FF;
    n0 = (tb & 63) * 64; k0 = (tb >> 6) * 64;
  } else {
    const int tb = bid - 5888;
    in = W2_; oh = W2T_; K = FF; N = H;
    n0 = (tb & 15) * 64; k0 = (tb >> 4) * 64;
  }
  const int r = tid >> 4, c4 = (tid & 15) * 4;
#pragma unroll
  for (int i = 0; i < 4; ++i) {
    const float4 v = *(const float4*)(in + (size_t)(k0 + i*16 + r) * N + n0 + c4);
    tile[i*16+r][c4]   = v.x; tile[i*16+r][c4+1] = v.y;
    tile[i*16+r][c4+2] = v.z; tile[i*16+r][c4+3] = v.w;
  }
  __syncthreads();
  const int n = tid >> 2, kq = tid & 3;
  union { u16 s[8]; int4 v; } ph0, ph1, pl0, pl1;
#pragma unroll
  for (int j = 0; j < 8; ++j) {
    const float f0 = tile[kq*16 + j][n];
    const float f1 = tile[kq*16 + 8 + j][n];
    const u16 h0 = f2bf(f0), h1 = f2bf(f1);
    ph0.s[j] = h0; ph1.s[j] = h1;
    if (split) { pl0.s[j] = f2bf(f0 - bf2f(h0)); pl1.s[j] = f2bf(f1 - bf2f(h1)); }
  }
  u16* po = oh + (size_t)(n0 + n) * K + k0 + kq * 16;
  *(int4*)po = ph0.v; *(int4*)(po + 8) = ph1.v;
  if (split) {
    u16* pl = ol + (size_t)(n0 + n) * K + k0 + kq * 16;
    *(int4*)pl = pl0.v; *(int4*)(pl + 8) = pl1.v;
  }
}

// ---------------------------------------------------------------------------
// MFMA GEMM: C[M,N] = (A @ B^T) * bias[N]  (A [M][K] bf16, B [N][K] bf16)
// 128x128 tile, BK=32, global_load_lds staging, XCD-chunked 1-D grid.
// DEEP3 (non-split only): 3-slot LDS + counted vmcnt(4) barriers. 24KB.
// SPLIT: 2-phase double-buffered (__syncthreads drains vmcnt -> safe).
// PARTIAL: split-K=2 over blockIdx.y; raw fp32 partials (no bias/relu).
// QKV3: V fragments (qkv k-index 2) skip the hi/lo correction MFMAs, and
//       their Bl staging chunks are skipped entirely (never read).
// ---------------------------------------------------------------------------
__device__ __forceinline__ int swz(int r, int kq) {
  return r * 32 + ((kq ^ ((r >> 1) & 3)) * 8);
}

template<int SPLIT, int RELU, int OBF, int QKV3, int DEEP3, int PARTIAL>
__global__ __launch_bounds__(256) void mfma_gemm(
    const u16* __restrict__ Ah, const u16* __restrict__ Al,
    const u16* __restrict__ Bh, const u16* __restrict__ Bl,
    const float* __restrict__ bias,
    float* __restrict__ Cf, u16* __restrict__ Cb,
    int M, int N, int K)
{
  __shared__ u16 lds[DEEP3 ? 24576 : (SPLIT ? 32768 : 16384)];
  const int BUFSZ = SPLIT ? 16384 : 8192;
  const int tid = threadIdx.x;
  // XCD-chunked decode: xcd=bid&7 owns M-panels [4*xcd, 4*xcd+4)
  const int bid = blockIdx.x;
  const int xcd = bid & 7;
  const int idx = bid >> 3;
  const int row0 = (xcd * 4 + (idx & 3)) * 128;
  const int col0 = (idx >> 2) * 128;
  const int wv = tid >> 6, lane = tid & 63;
  const int wr = wv >> 1, wc = wv & 1;
  const int kq = lane >> 4, fr = lane & 15;

  int kb = 0, kE = K;
  if (PARTIAL) {
    const int khf = blockIdx.y;
    kb = khf * (K >> 1); kE = kb + (K >> 1);
    Cf += (size_t)khf * ((size_t)M * N);
  }

  f32x4 acc[4][4] = {};

  // stage one 128x32 bf16 array (8 chunks of 1KB); wave wv does chunks 2wv,2wv+1
#define GSTAGE(lbase, gb, rowbase, kk) do { \
    _Pragma("unroll") \
    for (int t_ = 0; t_ < 2; ++t_) { \
      const int c_ = wv * 2 + t_; \
      const int idx_ = c_ * 64 + lane; \
      const int r_ = idx_ >> 2; \
      const int kq_ = (idx_ & 3) ^ ((r_ >> 1) & 3); \
      gload16((gb) + (size_t)((rowbase) + r_) * K + (kk) + kq_ * 8, \
              &lds[(lbase) + c_ * 512]); \
    } } while (0)

  // Bl staging with V-group chunk skip (chunk c covers 16-col group
  // (col0>>4)+c; k-index %3==2 groups never read their b_l fragments).
#define BLSTAGE(lbase, kk) do { \
    _Pragma("unroll") \
    for (int t_ = 0; t_ < 2; ++t_) { \
      const int c_ = wv * 2 + t_; \
      if (!QKV3 || ((((col0 >> 4) + c_) % 3) != 2)) { \
        const int idx_ = c_ * 64 + lane; \
        const int r_ = idx_ >> 2; \
        const int kq_ = (idx_ & 3) ^ ((r_ >> 1) & 3); \
        gload16(Bl + (size_t)(col0 + r_) * K + (kk) + kq_ * 8, \
                &lds[(lbase) + c_ * 512]); \
      } } } while (0)

  if (DEEP3) {
    // ---- 3-deep counted-vmcnt pipeline (non-split only; all slots 3-deep,
    // overwrite target is 2 iterations stale -> no write-after-read hazard) ----
    const int nk = (kE - kb) >> 5;
    GSTAGE(0, Ah, row0, kb);            GSTAGE(4096, Bh, col0, kb);
    GSTAGE(8192, Ah, row0, kb + 32);    GSTAGE(8192 + 4096, Bh, col0, kb + 32);
    WAITBAR4;                            // stage 0 ready; stage 1 in flight
    int cslot = 0, islot = 2;
    for (int i = 0; i < nk; ++i) {
      if (i + 2 < nk) {
        const int kk = kb + (i + 2) * 32;
        GSTAGE(islot * 8192, Ah, row0, kk);
        GSTAGE(islot * 8192 + 4096, Bh, col0, kk);
        islot = (islot == 2) ? 0 : islot + 1;
      }
      const int rb = cslot * 8192;
      bf16x8 a_h[4];
#pragma unroll
      for (int m = 0; m < 4; ++m)
        a_h[m] = *(const bf16x8*)&lds[rb + swz(wr*64 + m*16 + fr, kq)];
#pragma unroll
      for (int n = 0; n < 4; ++n) {
        const bf16x8 b_h = *(const bf16x8*)&lds[rb + 4096 + swz(wc*64 + n*16 + fr, kq)];
#pragma unroll
        for (int m = 0; m < 4; ++m)
          acc[m][n] = __builtin_amdgcn_mfma_f32_16x16x32_bf16(a_h[m], b_h, acc[m][n], 0, 0, 0);
      }
      cslot = (cslot == 2) ? 0 : cslot + 1;
      if (i + 1 < nk) { if (i + 2 < nk) WAITBAR4; else WAITBAR0; }
    }
  } else {
    // ---- 2-phase double-buffered (__syncthreads drains all counters) ----
    GSTAGE(0, Ah, row0, kb);
    GSTAGE(4096, Bh, col0, kb);
    if (SPLIT) { GSTAGE(8192, Al, row0, kb); BLSTAGE(12288, kb); }
    __syncthreads();

    int cur = 0;
    for (int k0 = kb; k0 < kE; k0 += 32) {
      const int nxt = cur ^ 1;
      if (k0 + 32 < kE) {
        GSTAGE(nxt*BUFSZ, Ah, row0, k0 + 32);
        GSTAGE(nxt*BUFSZ + 4096, Bh, col0, k0 + 32);
        if (SPLIT) { GSTAGE(nxt*BUFSZ + 8192, Al, row0, k0 + 32);
                     BLSTAGE(nxt*BUFSZ + 12288, k0 + 32); }
      }
      const int rb = cur * BUFSZ;
      bf16x8 a_h[4], a_l[4];
#pragma unroll
      for (int m = 0; m < 4; ++m) {
        a_h[m] = *(const bf16x8*)&lds[rb + swz(wr*64 + m*16 + fr, kq)];
        if (SPLIT) a_l[m] = *(const bf16x8*)&lds[rb + 8192 + swz(wr*64 + m*16 + fr, kq)];
      }
#pragma unroll
      for (int n = 0; n < 4; ++n) {
        const bf16x8 b_h = *(const bf16x8*)&lds[rb + 4096 + swz(wc*64 + n*16 + fr, kq)];
#pragma unroll
        for (int m = 0; m < 4; ++m)
          acc[m][n] = __builtin_amdgcn_mfma_f32_16x16x32_bf16(a_h[m], b_h, acc[m][n], 0, 0, 0);
        if (SPLIT) {
          const bool dolo = !QKV3 || ((((col0 >> 4) + wc * 4 + n) % 3) != 2);
          if (dolo) {
            const bf16x8 b_l = *(const bf16x8*)&lds[rb + 12288 + swz(wc*64 + n*16 + fr, kq)];
#pragma unroll
            for (int m = 0; m < 4; ++m) {
              acc[m][n] = __builtin_amdgcn_mfma_f32_16x16x32_bf16(a_h[m], b_l, acc[m][n], 0, 0, 0);
              acc[m][n] = __builtin_amdgcn_mfma_f32_16x16x32_bf16(a_l[m], b_h, acc[m][n], 0, 0, 0);
            }
          }
        }
      }
      __syncthreads();
      cur = nxt;
    }
  }
#undef GSTAGE
#undef BLSTAGE

  const int orow0 = row0 + wr * 64, ocol0 = col0 + wc * 64;
#pragma unroll
  for (int n = 0; n < 4; ++n) {
    const int col = ocol0 + n * 16 + fr;
    const float bs = PARTIAL ? 1.0f : bias[col];
#pragma unroll
    for (int m = 0; m < 4; ++m) {
      const int rbase = orow0 + m * 16 + (lane >> 4) * 4;
#pragma unroll
      for (int j = 0; j < 4; ++j) {
        float v = acc[m][n][j] * bs;
        if (RELU) v = fmaxf(v, 0.0f);
        const size_t off = (size_t)(rbase + j) * N + col;
        if (OBF) Cb[off] = f2bf(v); else Cf[off] = v;
      }
    }
  }
}

// ---------------------------------------------------------------------------
// Repack qkv [B,T,3072] -> bf16 arrays: Qh/Ql (scaled by log2e/32, split),
// Kh/Kl (split), Vb (bf16), all [B*NH][T][HD]. Channel o = d*48 + k*16 + h.
// ---------------------------------------------------------------------------
__global__ __launch_bounds__(256) void repack_qkv(
    const float* __restrict__ qkv,
    u16* __restrict__ Qh, u16* __restrict__ Ql,
    u16* __restrict__ Kh, u16* __restrict__ Kl, u16* __restrict__ Vb)
{
  const int bt = blockIdx.x;
  const int b = bt >> 11, t = bt & (T - 1);
  const int tid = threadIdx.x;
  __shared__ float Ls[3 * H];
  const float* src = qkv + (size_t)bt * (3 * H);
#pragma unroll
  for (int i = 0; i < 3; ++i) {
    const int c4 = i * 256 + tid;
    *(float4*)&Ls[c4 * 4] = *(const float4*)(src + c4 * 4);
  }
  __syncthreads();
  const float qscale = LOG2E / 32.0f;
#pragma unroll
  for (int i = 0; i < 4; ++i) {
    const int j = i * 256 + tid;
    const int h = j >> 6, d = j & 63;
    const size_t dst = (((size_t)(b * NH + h)) * T + t) * HD + d;
    const float q = Ls[d * 48 + h] * qscale;
    const u16 qhb = f2bf(q);
    Qh[dst] = qhb; Ql[dst] = f2bf(q - bf2f(qhb));
    const float k = Ls[d * 48 + 16 + h];
    const u16 khb = f2bf(k);
    Kh[dst] = khb; Kl[dst] = f2bf(k - bf2f(khb));
    Vb[dst] = f2bf(Ls[d * 48 + 32 + h]);
  }
}

// ---------------------------------------------------------------------------
// Vb [bh][T][HD] bf16 -> VT [bh][HD][T] bf16 (64x64 tiles via LDS)
// ---------------------------------------------------------------------------
__global__ __launch_bounds__(256) void vtrans(
    const u16* __restrict__ Vb, u16* __restrict__ VT)
{
  __shared__ u16 Ls[64][72];
  const int bh = blockIdx.y, t0 = blockIdx.x * 64;
  const int tid = threadIdx.x;
  const int r = tid >> 2, c = (tid & 3) * 16;
  const size_t src = ((size_t)bh * T + t0 + r) * HD + c;
  *(int4*)&Ls[r][c]     = *(const int4*)(Vb + src);
  *(int4*)&Ls[r][c + 8] = *(const int4*)(Vb + src + 8);
  __syncthreads();
  const int d = tid >> 2, tc = (tid & 3) * 16;
  u16 buf[16];
#pragma unroll
  for (int i = 0; i < 16; ++i) buf[i] = Ls[tc + i][d];
  u16* dst = VT + ((size_t)bh * HD + d) * T + t0 + tc;
  *(int4*)dst       = *(int4*)&buf[0];
  *(int4*)(dst + 8) = *(int4*)&buf[8];
}

// ---------------------------------------------------------------------------
// sigma: LDS K-row r holds key sigma(r) so that the QK^T C-layout hands each
// lane exactly the 8-consecutive-key fragments PV's B-operand needs.
// ---------------------------------------------------------------------------
__device__ __forceinline__ int sigma_k(int r) {
  return ((r >> 5) << 5) | (((r >> 2) & 3) << 3) | (((r >> 4) & 1) << 2) | (r & 3);
}

// ---------------------------------------------------------------------------
// MFMA flash attention, swapped-operand. 8 waves x 16 q-rows (512 threads),
// KV tile 64. K hi/lo + VT staged in LDS, 3-deep counted-vmcnt pipeline
// (24KB/slot, 72KB total). XCD-clustered grid; defer-max (THR=8); lsum via
// ones-A MFMA; setprio around MFMA clusters.
// 72KB LDS x 2 blocks/CU = 144KB <= 160KB -> 16 waves/CU (4/SIMD).
// VERIFIED 93us configuration (R1/R5).
// ---------------------------------------------------------------------------
__global__ __launch_bounds__(512, 4) void flash_attn_mfma(
    const u16* __restrict__ Qh, const u16* __restrict__ Ql,
    const u16* __restrict__ Kh, const u16* __restrict__ Kl,
    const u16* __restrict__ VT, float* __restrict__ Out)
{
  __shared__ u16 sm[3 * 12288];  // slot: KH [0,4K) | KL [4K,8K) | VT [8K,12K) u16
  // XCD-clustered decode: xcd = i&7 owns heads 4*xcd..4*xcd+3
  const int i = blockIdx.x;
  const int slot = i >> 3;
  const int bh = (i & 7) * 4 + (slot >> 4);
  const int row0 = (slot & 15) * 128;
  const int b = bh >> 4, h = bh & 15;
  const int tid = threadIdx.x, wave = tid >> 6, lane = tid & 63;
  const int fr = lane & 15, kq = lane >> 4;

  // Q fragments (B-operand: col=q=fr, k=d=kq*8 within ks*32); wave owns
  // q-rows [row0 + wave*16, +16)
  bf16x8 qh[2], ql[2];
  const size_t qoff = ((size_t)bh * T + row0 + wave*16 + fr) * HD + kq*8;
#pragma unroll
  for (int ks = 0; ks < 2; ++ks) {
    qh[ks] = *(const bf16x8*)(Qh + qoff + ks*32);
    ql[ks] = *(const bf16x8*)(Ql + qoff + ks*32);
  }

  bf16x8 ones8;
#pragma unroll
  for (int z = 0; z < 8; ++z) ones8[z] = (short)0x3F80;

  f32x4 o[4] = {};
  f32x4 oex = {};                      // lsum accumulator (all 4 rows equal)
  float m_ = -1e30f;

  // staging: wave w stages chunk w (1KB) of each of the 3 arrays (8 waves
  // cover the 8 chunks). Global pointers advance by a constant per KV tile.
  const int c_ = wave;
  const int r0_ = c_ * 8 + (lane >> 3), s_ = lane & 7;
  const int cd0 = s_ ^ (r0_ & 7);
  const int k0_ = sigma_k(r0_);
  const u16* pKh0 = Kh + ((size_t)bh*T + k0_)*HD + cd0*8;
  const u16* pKl0 = Kl + ((size_t)bh*T + k0_)*HD + cd0*8;
  const u16* pV0  = VT + ((size_t)bh*HD + r0_)*T + cd0*8;

#define FSTAGE(sb) do { \
    gload16(pKh0, &sm[(sb) + c_*512]); \
    gload16(pKl0, &sm[(sb) + 4096 + c_*512]); \
    gload16(pV0,  &sm[(sb) + 8192 + c_*512]); \
    pKh0 += 64*HD; pKl0 += 64*HD; pV0 += 64; \
  } while (0)

  FSTAGE(0);
  FSTAGE(12288);
  WAITBAR3;                  // tile 0 ready (3 loads/wave); tile 1 in flight
  int cslot = 0, islot = 2;

  const int NT = T / 64;
  for (int t = 0; t < NT; ++t) {
    if (t + 2 < NT) {
      FSTAGE(islot * 12288);
      islot = (islot == 2) ? 0 : islot + 1;
    }
    const u16* smb = &sm[cslot * 12288];

    // ---- QK^T (swapped): s[n], keys sigma(16n+4kq+jj), q=fr
    f32x4 s[4] = {};
    __builtin_amdgcn_s_setprio(1);
#pragma unroll
    for (int ks = 0; ks < 2; ++ks) {
#pragma unroll
      for (int n = 0; n < 4; ++n) {
        const int kr = n * 16 + fr;
        const int sl = ((ks*4 + kq) ^ (kr & 7)) * 8;
        const bf16x8 kh_ = *(const bf16x8*)&smb[kr*64 + sl];
        const bf16x8 kl_ = *(const bf16x8*)&smb[4096 + kr*64 + sl];
        s[n] = __builtin_amdgcn_mfma_f32_16x16x32_bf16(kh_, qh[ks], s[n], 0, 0, 0);
        s[n] = __builtin_amdgcn_mfma_f32_16x16x32_bf16(kl_, qh[ks], s[n], 0, 0, 0);
        s[n] = __builtin_amdgcn_mfma_f32_16x16x32_bf16(kh_, ql[ks], s[n], 0, 0, 0);
      }
    }
    __builtin_amdgcn_s_setprio(0);

    // ---- defer-max softmax (THR=8)
    const float g0 = m3(s[0][0], s[0][1], s[0][2]);
    const float g1 = m3(s[0][3], s[1][0], s[1][1]);
    const float g2 = m3(s[1][2], s[1][3], s[2][0]);
    const float g3 = m3(s[2][1], s[2][2], s[2][3]);
    const float g4 = m3(s[3][0], s[3][1], s[3][2]);
    float mx = fmaxf(m3(g0, g1, g2), m3(g3, g4, s[3][3]));
    mx = fmaxf(mx, __shfl_xor(mx, 16));
    mx = fmaxf(mx, __shfl_xor(mx, 32));
    if (!__all(mx <= m_ + 8.0f)) {      // record tile (~10%): rescale
      const float mn = fmaxf(m_, mx);
      const float fsc = exp2f(m_ - mn);
      m_ = mn;
#pragma unroll
      for (int n = 0; n < 4; ++n) {
        o[n][0] *= fsc; o[n][1] *= fsc;
        o[n][2] *= fsc; o[n][3] *= fsc;
      }
      oex[0] *= fsc; oex[1] *= fsc; oex[2] *= fsc; oex[3] *= fsc;
    }

    float p[4][4];
#pragma unroll
    for (int n = 0; n < 4; ++n)
#pragma unroll
      for (int jj = 0; jj < 4; ++jj)
        p[n][jj] = exp2f(s[n][jj] - m_);

    unsigned pk[4][2];
#pragma unroll
    for (int n = 0; n < 4; ++n) {
      pk[n][0] = cvt_pk_bf16(p[n][0], p[n][1]);
      pk[n][1] = cvt_pk_bf16(p[n][2], p[n][3]);
    }

    // ---- in-reg P -> PV (+ lsum MFMA); V^T fragments from LDS
    __builtin_amdgcn_s_setprio(1);
#pragma unroll
    for (int ks = 0; ks < 2; ++ks) {
      union { unsigned u[4]; bf16x8 v; } pb;
      pb.u[0] = pk[2*ks][0];   pb.u[1] = pk[2*ks][1];
      pb.u[2] = pk[2*ks+1][0]; pb.u[3] = pk[2*ks+1][1];
#pragma unroll
      for (int n = 0; n < 4; ++n) {
        const int dr = n * 16 + fr;
        const bf16x8 vf = *(const bf16x8*)&smb[8192 + dr*64 + (((ks*4 + kq) ^ (dr & 7)) * 8)];
        o[n] = __builtin_amdgcn_mfma_f32_16x16x32_bf16(vf, pb.v, o[n], 0, 0, 0);
      }
      oex = __builtin_amdgcn_mfma_f32_16x16x32_bf16(ones8, pb.v, oex, 0, 0, 0);
    }
    __builtin_amdgcn_s_setprio(0);

    cslot = (cslot == 2) ? 0 : cslot + 1;
    if (t + 1 < NT) { if (t + 2 < NT) WAITBAR3; else WAITBAR0; }
  }
#undef FSTAGE

  // ---- epilogue: O^T frag has q=fr, d = 16n + 4kq + jj (jj contiguous)
  {
    const float inv = 1.0f / oex[0];
    const size_t qrow = (size_t)b * T + row0 + wave*16 + fr;
#pragma unroll
    for (int n = 0; n < 4; ++n) {
      float4 ov;
      ov.x = o[n][0] * inv; ov.y = o[n][1] * inv;
      ov.z = o[n][2] * inv; ov.w = o[n][3] * inv;
      *(float4*)(Out + qrow * H + h * HD + n * 16 + kq * 4) = ov;
    }
  }
}

// ---------------------------------------------------------------------------
// out_bf16 = LN(a + b) * gamma + beta; ddof=1, eps on std.
// fp32 output dropped — the downstream residual (ln_residual_sk) is
// ffn-dominated (|ffn|~1e3 vs |ln1|~3), so the bf16 rounding perturbs the
// final LN by ~1e-5. Saves 16.7MB write + 8.3MB read.
// ---------------------------------------------------------------------------
__global__ __launch_bounds__(256) void ln_residual(
    const float* __restrict__ A, const float* __restrict__ Bz,
    const float* __restrict__ gamma, const float* __restrict__ beta,
    u16* __restrict__ obf)
{
  const int row = blockIdx.x, tid = threadIdx.x;
  const int wave = tid >> 6, lane = tid & 63;
  const size_t off = (size_t)row * H + tid * 4;
  const float4 av = *(const float4*)(A + off);
  const float4 bv = *(const float4*)(Bz + off);
  float4 y; y.x = av.x + bv.x; y.y = av.y + bv.y; y.z = av.z + bv.z; y.w = av.w + bv.w;
  float s  = y.x + y.y + y.z + y.w;
  float ss = y.x*y.x + y.y*y.y + y.z*y.z + y.w*y.w;
#pragma unroll
  for (int o = 32; o >= 1; o >>= 1) { s += __shfl_xor(s, o); ss += __shfl_xor(ss, o); }
  __shared__ float red[2][4];
  if (lane == 0) { red[0][wave] = s; red[1][wave] = ss; }
  __syncthreads();
  s  = red[0][0] + red[0][1] + red[0][2] + red[0][3];
  ss = red[1][0] + red[1][1] + red[1][2] + red[1][3];
  const float mean = s * (1.0f / (float)H);
  float var = (ss - (float)H * mean * mean) * (1.0f / (float)(H - 1));
  var = fmaxf(var, 0.0f);
  const float inv = 1.0f / (sqrtf(var) + 1e-6f);
  const float4 gv = *(const float4*)(gamma + tid * 4);
  const float4 be = *(const float4*)(beta + tid * 4);
  float4 o;
  o.x = gv.x * (y.x - mean) * inv + be.x;
  o.y = gv.y * (y.y - mean) * inv + be.y;
  o.z = gv.z * (y.z - mean) * inv + be.z;
  o.w = gv.w * (y.w - mean) * inv + be.w;
  union { u16 s[4]; uint2 u; } pk;
  pk.s[0] = f2bf(o.x); pk.s[1] = f2bf(o.y); pk.s[2] = f2bf(o.z); pk.s[3] = f2bf(o.w);
  *(uint2*)(obf + off) = pk.u;
}

// ---------------------------------------------------------------------------
// split-K merge + LN: out = LN(a + (pA+pB)*bb) * gamma + beta
// a is the bf16 ln1 copy (see ln_residual note).
// ---------------------------------------------------------------------------
__global__ __launch_bounds__(256) void ln_residual_sk(
    const u16* __restrict__ Ab, const float* __restrict__ PA,
    const float* __restrict__ PB, const float* __restrict__ bb,
    const float* __restrict__ gamma, const float* __restrict__ beta,
    float* __restrict__ out)
{
  const int row = blockIdx.x, tid = threadIdx.x;
  const int wave = tid >> 6, lane = tid & 63;
  const size_t off = (size_t)row * H + tid * 4;
  union { uint2 u; u16 s[4]; } au;
  au.u = *(const uint2*)(Ab + off);
  const float4 pa = *(const float4*)(PA + off);
  const float4 pb = *(const float4*)(PB + off);
  const float4 bw = *(const float4*)(bb + tid * 4);
  float4 y;
  y.x = bf2f(au.s[0]) + (pa.x + pb.x) * bw.x;
  y.y = bf2f(au.s[1]) + (pa.y + pb.y) * bw.y;
  y.z = bf2f(au.s[2]) + (pa.z + pb.z) * bw.z;
  y.w = bf2f(au.s[3]) + (pa.w + pb.w) * bw.w;
  float s  = y.x + y.y + y.z + y.w;
  float ss = y.x*y.x + y.y*y.y + y.z*y.z + y.w*y.w;
#pragma unroll
  for (int o = 32; o >= 1; o >>= 1) { s += __shfl_xor(s, o); ss += __shfl_xor(ss, o); }
  __shared__ float red[2][4];
  if (lane == 0) { red[0][wave] = s; red[1][wave] = ss; }
  __syncthreads();
  s  = red[0][0] + red[0][1] + red[0][2] + red[0][3];
  ss = red[1][0] + red[1][1] + red[1][2] + red[1][3];
  const float mean = s * (1.0f / (float)H);
  float var = (ss - (float)H * mean * mean) * (1.0f / (float)(H - 1));
  var = fmaxf(var, 0.0f);
  const float inv = 1.0f / (sqrtf(var) + 1e-6f);
  const float4 gv = *(const float4*)(gamma + tid * 4);
  const float4 be = *(const float4*)(beta + tid * 4);
  float4 o;
  o.x = gv.x * (y.x - mean) * inv + be.x;
  o.y = gv.y * (y.y - mean) * inv + be.y;
  o.z = gv.z * (y.z - mean) * inv + be.z;
  o.w = gv.w * (y.w - mean) * inv + be.w;
  *(float4*)(out + off) = o;
}

// ---------------------------------------------------------------------------
extern "C" void kernel_launch(void* const* d_in, const int* in_sizes, int n_in,
                              void* d_out, int out_size, void* d_ws, size_t ws_size,
                              hipStream_t stream)
{
  const float* x    = (const float*)d_in[0];
  const float* Wqkv = (const float*)d_in[1];
  const float* bqkv = (const float*)d_in[2];
  const float* W1   = (const float*)d_in[3];
  const float* b1   = (const float*)d_in[4];
  const float* W2   = (const float*)d_in[5];
  const float* b2   = (const float*)d_in[6];
  const float* g1   = (const float*)d_in[7];
  const float* be1  = (const float*)d_in[8];
  const float* g2   = (const float*)d_in[9];
  const float* be2  = (const float*)d_in[10];
  float* out = (float*)d_out;
  char* w = (char*)d_ws;

  // ---- workspace map (bytes); lifetime-audited (R6 lesson) ----
  // region              offset     size    live steps
  // qkv   fp32          0          50.33M  2-3
  // h1b   bf16          0          33.55M  7-8
  // xh/Qh bf16          52428800   8.39M   1-2 / 3-5
  // xl/Ql bf16          60817408   8.39M   1-2 / 3-5
  // WqTh/Khb bf16       69206016   6.29/8.39M  1-2 / 3-5
  // WqTl bf16           75497472   6.29M   1-2
  // Klb   bf16          77594624   8.39M   3-5
  // Vbb   bf16          85983232   8.39M   3-4
  // VTb   bf16          94371840   8.39M   4-5
  // pAB   fp32          52428800   33.55M  8-9 (over Q/K/V dead)
  // attn  fp32          102760448  16.78M  5-6
  // W1T   bf16          119537664  8.39M   1-7  (freed fp32-ln1 region)
  // W2T   bf16          127926272  8.39M   1-8
  // ln1b  bf16          136314880  8.39M   6-9
  float* qkv  = (float*)(w + 0);
  u16*   h1b  = (u16*)  (w + 0);
  u16*   xh   = (u16*)  (w + 52428800);
  u16*   xl   = (u16*)  (w + 60817408);
  u16*   Qh   = (u16*)  (w + 52428800);
  u16*   Ql   = (u16*)  (w + 60817408);
  u16*   WqTh = (u16*)  (w + 69206016);
  u16*   WqTl = (u16*)  (w + 75497472);
  u16*   Khb  = (u16*)  (w + 69206016);
  u16*   Klb  = (u16*)  (w + 77594624);
  u16*   Vbb  = (u16*)  (w + 85983232);
  u16*   VTb  = (u16*)  (w + 94371840);
  float* pAB  = (float*)(w + 52428800);
  float* attn = (float*)(w + 102760448);
  u16*   W1T  = (u16*)  (w + 119537664);
  u16*   W2T  = (u16*)  (w + 127926272);
  u16*   ln1b = (u16*)  (w + 136314880);

  // 1. preprocess: split x hi/lo + Wqkv^T hi/lo + W1^T + W2^T (one launch)
  preprocess<<<6912, 256, 0, stream>>>(x, xh, xl, Wqkv, WqTh, WqTl,
                                       W1, W1T, W2, W2T);
  // 2. qkv = (x @ Wqkv) * bqkv  [split MFMA, 2-phase; V-col Bl staging skipped]
  mfma_gemm<1,0,0,1,0,0><<<24 * 32, 256, 0, stream>>>(xh, xl, WqTh, WqTl, bqkv,
                                                      qkv, nullptr, M_TOK, 3*H, H);
  // 3. repack heads -> scaled/split bf16 Q,K + bf16 V
  repack_qkv<<<M_TOK, 256, 0, stream>>>(qkv, Qh, Ql, Khb, Klb, Vbb);
  // 4. V transpose
  vtrans<<<dim3(T/64, B*NH), 256, 0, stream>>>(Vbb, VTb);
  // 5. attention (MFMA, swapped-operand, XCD-clustered, 8-wave, 3-deep) — R1
  flash_attn_mfma<<<512, 512, 0, stream>>>(Qh, Ql, Khb, Klb, VTb, attn);
  // 6. ln1 = LN(x + attn) -> bf16 only
  ln_residual<<<M_TOK, 256, 0, stream>>>(x, attn, g1, be1, ln1b);
  // 7. h1 = relu((ln1 @ W1) * b1) -> bf16  [XCD-chunked, 3-deep]
  mfma_gemm<0,1,1,0,1,0><<<32 * 32, 256, 0, stream>>>(ln1b, nullptr, W1T, nullptr, b1,
                                                      nullptr, h1b, M_TOK, FF, H);
  // 8. ffn partials = h1 @ W2 (split-K=2, raw fp32)  [XCD-chunked, 3-deep]
  mfma_gemm<0,0,0,0,1,1><<<dim3(8 * 32, 2), 256, 0, stream>>>(h1b, nullptr, W2T, nullptr, nullptr,
                                                              pAB, nullptr, M_TOK, H, FF);
  // 9. out = LN(ln1 + (pA+pB)*b2)
  ln_residual_sk<<<M_TOK, 256, 0, stream>>>(ln1b, pAB, pAB + 4194304, b2, g2, be2, out);
}

// Round 8
// 292.170 us; speedup vs baseline: 1.2279x; 1.0150x over previous
//
#include <hip/hip_runtime.h>
#include <math.h>

// Sizes (fixed for this problem)
#define B 2
#define T 2048
#define H 1024
#define NH 16
#define HD 64
#define FF 4096
#define M_TOK (B*T)          // 4096 token rows
#define LOG2E 1.4426950408889634f

typedef unsigned short u16;
typedef __attribute__((ext_vector_type(8))) short bf16x8;
typedef __attribute__((ext_vector_type(4))) float f32x4;

// counted-vmcnt barrier: wait until only N of this wave's vmem ops remain,
// then workgroup barrier. Single asm with "memory" clobber so no memory op
// (gload_lds / ds_read) is reordered across it.
// NOTE (r8-r10 lesson): counted-vmcnt pipelines are only safe when EVERY
// LDS buffer is >=3 slots deep (overwrite target >=2 iterations stale).
// NOTE (R2 lesson): direct-to-register global V loads regress badly — the
// strided fragment pattern (rows T apart) turns each wave load into 16
// scattered L1 lines; keep V in LDS.
// NOTE (R3 lesson): split-KV/split-K partials must merge ON-CHIP. Global
// fp32 partials write-amplified ~6x and evicted L2 (FETCH 20->195MB).
// NOTE (R4 lesson): 32-key KV tiles break the V bank-swizzle and double
// per-tile softmax costs. The R1 attention shape (8 waves x 16 rows,
// 64-key tiles, 72KB, 3-deep ring) is the verified local optimum.
// NOTE (R6 lesson): WORKSPACE LIFETIME AUDIT before moving any launch.
// NOTE (R8): repack_qkv's Ls[d*48+h] reads were a 32-way bank conflict
// (stride 48 ≡ 16 mod 32 -> 2 banks per wave); fixed with +4-per-64 pad.
#define WAITBAR3  asm volatile("s_waitcnt vmcnt(3)\n\ts_barrier" ::: "memory")
#define WAITBAR4  asm volatile("s_waitcnt vmcnt(4)\n\ts_barrier" ::: "memory")
#define WAITBAR0  asm volatile("s_waitcnt vmcnt(0)\n\ts_barrier" ::: "memory")

__device__ __forceinline__ u16 f2bf(float f) {
  union { float f; unsigned u; } v; v.f = f;
  const unsigned r = (v.u + 0x7FFFu + ((v.u >> 16) & 1u)) >> 16;
  return (u16)r;
}
__device__ __forceinline__ float bf2f(u16 h) {
  union { unsigned u; float f; } v; v.u = ((unsigned)h) << 16;
  return v.f;
}
__device__ __forceinline__ unsigned cvt_pk_bf16(float lo, float hi) {
  unsigned r;
  asm("v_cvt_pk_bf16_f32 %0, %1, %2" : "=v"(r) : "v"(lo), "v"(hi));
  return r;
}
__device__ __forceinline__ float m3(float a, float b, float c) {
  return fmaxf(fmaxf(a, b), c);      // clang fuses to v_max3_f32
}
// async global->LDS, 16B per lane; dest = wave-uniform base + lane*16
__device__ __forceinline__ void gload16(const u16* g, u16* l) {
  __builtin_amdgcn_global_load_lds(
      (const __attribute__((address_space(1))) unsigned int*)g,
      (__attribute__((address_space(3))) unsigned int*)l, 16, 0, 0);
}

// ---------------------------------------------------------------------------
// preprocess — ONE launch for all input-only work:
//   bid <  4096 : split x -> bf16 hi/lo (Dekker split)
//   bid <  4864 : Wqkv^T hi/lo bf16 (48x16 tiles of 64x64)
//   bid <  5888 : W1^T bf16 (64x16)
//   else        : W2^T bf16 (16x64)
// ---------------------------------------------------------------------------
__global__ __launch_bounds__(256) void preprocess(
    const float* __restrict__ x, u16* __restrict__ xh, u16* __restrict__ xl,
    const float* __restrict__ Wqkv, u16* __restrict__ WqTh, u16* __restrict__ WqTl,
    const float* __restrict__ W1_, u16* __restrict__ W1T_,
    const float* __restrict__ W2_, u16* __restrict__ W2T_)
{
  const int bid = blockIdx.x;
  const int tid = threadIdx.x;
  if (bid < 4096) {                       // ---- split_hl ----
    const size_t i = ((size_t)bid * 256 + tid) * 4;
    const float4 v = *(const float4*)(x + i);
    union { u16 s[4]; uint2 u; } h, l;
    const float f[4] = {v.x, v.y, v.z, v.w};
#pragma unroll
    for (int j = 0; j < 4; ++j) {
      const u16 hb = f2bf(f[j]); h.s[j] = hb; l.s[j] = f2bf(f[j] - bf2f(hb));
    }
    *(uint2*)(xh + i) = h.u;
    *(uint2*)(xl + i) = l.u;
    return;
  }
  // ---- transpose-convert paths (uniform per block) ----
  __shared__ float tile[64][69];
  const float* in; u16* oh; u16* ol = nullptr; int K, N, k0, n0, split = 0;
  if (bid < 4864) {
    const int tb = bid - 4096;
    in = Wqkv; oh = WqTh; ol = WqTl; K = H; N = 3*H; split = 1;
    n0 = (tb % 48) * 64; k0 = (tb / 48) * 64;
  } else if (bid < 5888) {
    const int tb = bid - 4864;
    in = W1_; oh = W1T_; K = H; N = FF;
    n0 = (tb & 63) * 64; k0 = (tb >> 6) * 64;
  } else {
    const int tb = bid - 5888;
    in = W2_; oh = W2T_; K = FF; N = H;
    n0 = (tb & 15) * 64; k0 = (tb >> 4) * 64;
  }
  const int r = tid >> 4, c4 = (tid & 15) * 4;
#pragma unroll
  for (int i = 0; i < 4; ++i) {
    const float4 v = *(const float4*)(in + (size_t)(k0 + i*16 + r) * N + n0 + c4);
    tile[i*16+r][c4]   = v.x; tile[i*16+r][c4+1] = v.y;
    tile[i*16+r][c4+2] = v.z; tile[i*16+r][c4+3] = v.w;
  }
  __syncthreads();
  const int n = tid >> 2, kq = tid & 3;
  union { u16 s[8]; int4 v; } ph0, ph1, pl0, pl1;
#pragma unroll
  for (int j = 0; j < 8; ++j) {
    const float f0 = tile[kq*16 + j][n];
    const float f1 = tile[kq*16 + 8 + j][n];
    const u16 h0 = f2bf(f0), h1 = f2bf(f1);
    ph0.s[j] = h0; ph1.s[j] = h1;
    if (split) { pl0.s[j] = f2bf(f0 - bf2f(h0)); pl1.s[j] = f2bf(f1 - bf2f(h1)); }
  }
  u16* po = oh + (size_t)(n0 + n) * K + k0 + kq * 16;
  *(int4*)po = ph0.v; *(int4*)(po + 8) = ph1.v;
  if (split) {
    u16* pl = ol + (size_t)(n0 + n) * K + k0 + kq * 16;
    *(int4*)pl = pl0.v; *(int4*)(pl + 8) = pl1.v;
  }
}

// ---------------------------------------------------------------------------
// MFMA GEMM: C[M,N] = (A @ B^T) * bias[N]  (A [M][K] bf16, B [N][K] bf16)
// 128x128 tile, BK=32, global_load_lds staging, XCD-chunked 1-D grid.
// DEEP3 (non-split only): 3-slot LDS ring + counted vmcnt(4) barriers. 48KB.
// SPLIT: 2-phase double-buffered (__syncthreads drains vmcnt -> safe;
//        counted-vmcnt needs 3-deep which would be 96KB here).
// QKV3: V fragments (qkv k-index 2) skip the hi/lo correction MFMAs, and
//       their Bl staging chunks are skipped entirely (never read).
// ---------------------------------------------------------------------------
__device__ __forceinline__ int swz(int r, int kq) {
  return r * 32 + ((kq ^ ((r >> 1) & 3)) * 8);
}

template<int SPLIT, int RELU, int OBF, int QKV3, int DEEP3>
__global__ __launch_bounds__(256) void mfma_gemm(
    const u16* __restrict__ Ah, const u16* __restrict__ Al,
    const u16* __restrict__ Bh, const u16* __restrict__ Bl,
    const float* __restrict__ bias,
    float* __restrict__ Cf, u16* __restrict__ Cb,
    int M, int N, int K)
{
  __shared__ u16 lds[DEEP3 ? 24576 : (SPLIT ? 32768 : 16384)];
  const int BUFSZ = SPLIT ? 16384 : 8192;
  const int tid = threadIdx.x;
  // XCD-chunked decode: xcd=bid&7 owns M-panels [4*xcd, 4*xcd+4)
  const int bid = blockIdx.x;
  const int xcd = bid & 7;
  const int idx = bid >> 3;
  const int row0 = (xcd * 4 + (idx & 3)) * 128;
  const int col0 = (idx >> 2) * 128;
  const int wv = tid >> 6, lane = tid & 63;
  const int wr = wv >> 1, wc = wv & 1;
  const int kq = lane >> 4, fr = lane & 15;

  f32x4 acc[4][4] = {};

  // stage one 128x32 bf16 array (8 chunks of 1KB); wave wv does chunks 2wv,2wv+1
#define GSTAGE(lbase, gb, rowbase, kk) do { \
    _Pragma("unroll") \
    for (int t_ = 0; t_ < 2; ++t_) { \
      const int c_ = wv * 2 + t_; \
      const int idx_ = c_ * 64 + lane; \
      const int r_ = idx_ >> 2; \
      const int kq_ = (idx_ & 3) ^ ((r_ >> 1) & 3); \
      gload16((gb) + (size_t)((rowbase) + r_) * K + (kk) + kq_ * 8, \
              &lds[(lbase) + c_ * 512]); \
    } } while (0)

  // Bl staging with V-group chunk skip (chunk c covers 16-col group
  // (col0>>4)+c; k-index %3==2 groups never read their b_l fragments).
#define BLSTAGE(lbase, kk) do { \
    _Pragma("unroll") \
    for (int t_ = 0; t_ < 2; ++t_) { \
      const int c_ = wv * 2 + t_; \
      if (!QKV3 || ((((col0 >> 4) + c_) % 3) != 2)) { \
        const int idx_ = c_ * 64 + lane; \
        const int r_ = idx_ >> 2; \
        const int kq_ = (idx_ & 3) ^ ((r_ >> 1) & 3); \
        gload16(Bl + (size_t)(col0 + r_) * K + (kk) + kq_ * 8, \
                &lds[(lbase) + c_ * 512]); \
      } } } while (0)

  if (DEEP3) {
    // ---- 3-deep counted-vmcnt pipeline (non-split only) ----
    const int nk = K >> 5;
    GSTAGE(0, Ah, row0, 0);            GSTAGE(4096, Bh, col0, 0);
    GSTAGE(8192, Ah, row0, 32);        GSTAGE(8192 + 4096, Bh, col0, 32);
    WAITBAR4;                            // stage 0 ready; stage 1 in flight
    int cslot = 0, islot = 2;
    for (int i = 0; i < nk; ++i) {
      if (i + 2 < nk) {
        const int kk = (i + 2) * 32;
        GSTAGE(islot * 8192, Ah, row0, kk);
        GSTAGE(islot * 8192 + 4096, Bh, col0, kk);
        islot = (islot == 2) ? 0 : islot + 1;
      }
      const int rb = cslot * 8192;
      bf16x8 a_h[4];
#pragma unroll
      for (int m = 0; m < 4; ++m)
        a_h[m] = *(const bf16x8*)&lds[rb + swz(wr*64 + m*16 + fr, kq)];
#pragma unroll
      for (int n = 0; n < 4; ++n) {
        const bf16x8 b_h = *(const bf16x8*)&lds[rb + 4096 + swz(wc*64 + n*16 + fr, kq)];
#pragma unroll
        for (int m = 0; m < 4; ++m)
          acc[m][n] = __builtin_amdgcn_mfma_f32_16x16x32_bf16(a_h[m], b_h, acc[m][n], 0, 0, 0);
      }
      cslot = (cslot == 2) ? 0 : cslot + 1;
      if (i + 1 < nk) { if (i + 2 < nk) WAITBAR4; else WAITBAR0; }
    }
  } else {
    // ---- 2-phase double-buffered (__syncthreads drains all counters) ----
    GSTAGE(0, Ah, row0, 0);
    GSTAGE(4096, Bh, col0, 0);
    if (SPLIT) { GSTAGE(8192, Al, row0, 0); BLSTAGE(12288, 0); }
    __syncthreads();

    int cur = 0;
    for (int k0 = 0; k0 < K; k0 += 32) {
      const int nxt = cur ^ 1;
      if (k0 + 32 < K) {
        GSTAGE(nxt*BUFSZ, Ah, row0, k0 + 32);
        GSTAGE(nxt*BUFSZ + 4096, Bh, col0, k0 + 32);
        if (SPLIT) { GSTAGE(nxt*BUFSZ + 8192, Al, row0, k0 + 32);
                     BLSTAGE(nxt*BUFSZ + 12288, k0 + 32); }
      }
      const int rb = cur * BUFSZ;
      bf16x8 a_h[4], a_l[4];
#pragma unroll
      for (int m = 0; m < 4; ++m) {
        a_h[m] = *(const bf16x8*)&lds[rb + swz(wr*64 + m*16 + fr, kq)];
        if (SPLIT) a_l[m] = *(const bf16x8*)&lds[rb + 8192 + swz(wr*64 + m*16 + fr, kq)];
      }
#pragma unroll
      for (int n = 0; n < 4; ++n) {
        const bf16x8 b_h = *(const bf16x8*)&lds[rb + 4096 + swz(wc*64 + n*16 + fr, kq)];
#pragma unroll
        for (int m = 0; m < 4; ++m)
          acc[m][n] = __builtin_amdgcn_mfma_f32_16x16x32_bf16(a_h[m], b_h, acc[m][n], 0, 0, 0);
        if (SPLIT) {
          const bool dolo = !QKV3 || ((((col0 >> 4) + wc * 4 + n) % 3) != 2);
          if (dolo) {
            const bf16x8 b_l = *(const bf16x8*)&lds[rb + 12288 + swz(wc*64 + n*16 + fr, kq)];
#pragma unroll
            for (int m = 0; m < 4; ++m) {
              acc[m][n] = __builtin_amdgcn_mfma_f32_16x16x32_bf16(a_h[m], b_l, acc[m][n], 0, 0, 0);
              acc[m][n] = __builtin_amdgcn_mfma_f32_16x16x32_bf16(a_l[m], b_h, acc[m][n], 0, 0, 0);
            }
          }
        }
      }
      __syncthreads();
      cur = nxt;
    }
  }
#undef GSTAGE
#undef BLSTAGE

  const int orow0 = row0 + wr * 64, ocol0 = col0 + wc * 64;
#pragma unroll
  for (int n = 0; n < 4; ++n) {
    const int col = ocol0 + n * 16 + fr;
    const float bs = bias[col];
#pragma unroll
    for (int m = 0; m < 4; ++m) {
      const int rbase = orow0 + m * 16 + (lane >> 4) * 4;
#pragma unroll
      for (int j = 0; j < 4; ++j) {
        float v = acc[m][n][j] * bs;
        if (RELU) v = fmaxf(v, 0.0f);
        const size_t off = (size_t)(rbase + j) * N + col;
        if (OBF) Cb[off] = f2bf(v); else Cf[off] = v;
      }
    }
  }
}

// ---------------------------------------------------------------------------
// FFN2 with INTRA-BLOCK split-K (R8): y = ln1 + (h1 @ W2) * b2, fp32.
// 512 threads = 2 groups x 4 waves; group g runs the DEEP3 counted-vmcnt
// ring over K-half [g*2048, +2048) in its own 48KB LDS region (96KB total,
// 1 block/CU = 8 waves/CU, same wave count as the old grid-(256,2) version).
// Both groups execute identical trip counts and barrier sequences, so the
// shared s_barrier stays aligned. Merge: group1 dumps acc (64KB) to LDS,
// group0 adds (same fp32 order as the old ln_residual_sk), fuses the ln1
// residual + bias, writes y. Kills the 67MB pAB round-trip (R3 lesson:
// merge on-chip).
// ---------------------------------------------------------------------------
__global__ __launch_bounds__(512, 2) void mfma_ffn2(
    const u16* __restrict__ Ah, const u16* __restrict__ Bh,
    const u16* __restrict__ Res, const float* __restrict__ bias,
    float* __restrict__ Y)
{
  const int N = H, K = FF;
  __shared__ u16 lds[2 * 24576];        // 96KB: per-group 3-slot ring
  const int tid = threadIdx.x;
  const int bid = blockIdx.x;           // 256 blocks
  const int xcd = bid & 7;
  const int idx = bid >> 3;             // [0,32)
  const int row0 = (xcd * 4 + (idx & 3)) * 128;
  const int col0 = (idx >> 2) * 128;    // [0, 1024)
  const int wv8 = tid >> 6, lane = tid & 63;
  const int grp = wv8 >> 2, wv = wv8 & 3;
  const int wr = wv >> 1, wc = wv & 1;
  const int kq = lane >> 4, fr = lane & 15;
  const int kb = grp * (K >> 1);
  u16* gl = &lds[grp * 24576];

  f32x4 acc[4][4] = {};

#define GSTAGE2(lbase, gb, rowbase, kk) do { \
    _Pragma("unroll") \
    for (int t_ = 0; t_ < 2; ++t_) { \
      const int c_ = wv * 2 + t_; \
      const int idx_ = c_ * 64 + lane; \
      const int r_ = idx_ >> 2; \
      const int kq_ = (idx_ & 3) ^ ((r_ >> 1) & 3); \
      gload16((gb) + (size_t)((rowbase) + r_) * K + (kk) + kq_ * 8, \
              &gl[(lbase) + c_ * 512]); \
    } } while (0)

  const int nk = (K >> 1) >> 5;         // 64 steps per group
  GSTAGE2(0, Ah, row0, kb);            GSTAGE2(4096, Bh, col0, kb);
  GSTAGE2(8192, Ah, row0, kb + 32);    GSTAGE2(8192 + 4096, Bh, col0, kb + 32);
  WAITBAR4;
  int cslot = 0, islot = 2;
  for (int i = 0; i < nk; ++i) {
    if (i + 2 < nk) {
      const int kk = kb + (i + 2) * 32;
      GSTAGE2(islot * 8192, Ah, row0, kk);
      GSTAGE2(islot * 8192 + 4096, Bh, col0, kk);
      islot = (islot == 2) ? 0 : islot + 1;
    }
    const int rb = cslot * 8192;
    bf16x8 a_h[4];
#pragma unroll
    for (int m = 0; m < 4; ++m)
      a_h[m] = *(const bf16x8*)&gl[rb + swz(wr*64 + m*16 + fr, kq)];
#pragma unroll
    for (int n = 0; n < 4; ++n) {
      const bf16x8 b_h = *(const bf16x8*)&gl[rb + 4096 + swz(wc*64 + n*16 + fr, kq)];
#pragma unroll
      for (int m = 0; m < 4; ++m)
        acc[m][n] = __builtin_amdgcn_mfma_f32_16x16x32_bf16(a_h[m], b_h, acc[m][n], 0, 0, 0);
    }
    cslot = (cslot == 2) ? 0 : cslot + 1;
    if (i + 1 < nk) { if (i + 2 < nk) WAITBAR4; else WAITBAR0; }
  }
#undef GSTAGE2

  // ---- on-chip merge + fused residual epilogue ----
  __syncthreads();                      // all ring reads done (drains cnts)
  float* fm = (float*)lds;              // 24576 floats available
  const int base = wv * 4096;           // 16KB per wave-pair region
  if (grp == 1) {
#pragma unroll
    for (int m = 0; m < 4; ++m)
#pragma unroll
      for (int n = 0; n < 4; ++n)
        *(f32x4*)&fm[base + (m*4 + n)*256 + lane*4] = acc[m][n];
  }
  __syncthreads();
  if (grp == 0) {
    const int orow0 = row0 + wr * 64, ocol0 = col0 + wc * 64;
#pragma unroll
    for (int n = 0; n < 4; ++n) {
      const int col = ocol0 + n * 16 + fr;
      const float bs = bias[col];
#pragma unroll
      for (int m = 0; m < 4; ++m) {
        const f32x4 ob = *(const f32x4*)&fm[base + (m*4 + n)*256 + lane*4];
        const int rbase = orow0 + m * 16 + kq * 4;
#pragma unroll
        for (int j = 0; j < 4; ++j) {
          const size_t off = (size_t)(rbase + j) * N + col;
          Y[off] = bf2f(Res[off]) + (acc[m][n][j] + ob[j]) * bs;
        }
      }
    }
  }
}

// ---------------------------------------------------------------------------
// Repack qkv [B,T,3072] -> bf16 arrays: Qh/Ql (scaled by log2e/32, split),
// Kh/Kl (split), Vb (bf16), all [B*NH][T][HD]. Channel o = d*48 + k*16 + h.
// R8: LDS index padded +4 per 64 (the d-stride-48 reads were a 32-way bank
// conflict: 48 ≡ 16 mod 32 -> whole wave on 2 banks); stores vectorized
// (4 consecutive d per thread -> uint2) — 5 stores instead of 20.
// ---------------------------------------------------------------------------
__device__ __forceinline__ int padi(int o) { return o + 4 * (o >> 6); }

__global__ __launch_bounds__(256) void repack_qkv(
    const float* __restrict__ qkv,
    u16* __restrict__ Qh, u16* __restrict__ Ql,
    u16* __restrict__ Kh, u16* __restrict__ Kl, u16* __restrict__ Vb)
{
  const int bt = blockIdx.x;
  const int b = bt >> 11, t = bt & (T - 1);
  const int tid = threadIdx.x;
  __shared__ float Ls[3 * H + 192];
  const float* src = qkv + (size_t)bt * (3 * H);
#pragma unroll
  for (int i = 0; i < 3; ++i) {
    const int o = (i * 256 + tid) * 4;       // 4-aligned; pad keeps 16B align
    *(float4*)&Ls[padi(o)] = *(const float4*)(src + o);
  }
  __syncthreads();
  const float qscale = LOG2E / 32.0f;
  const int h = tid >> 4, d0 = (tid & 15) * 4;
  const size_t dst = (((size_t)(b * NH + h)) * T + t) * HD + d0;
  union { u16 s[4]; uint2 u; } qh_, ql_, kh_, kl_, vb_;
#pragma unroll
  for (int jj = 0; jj < 4; ++jj) {
    const int ob = (d0 + jj) * 48 + h;
    const float q = Ls[padi(ob)] * qscale;
    const float k = Ls[padi(ob + 16)];
    const float v = Ls[padi(ob + 32)];
    const u16 qhb = f2bf(q);
    qh_.s[jj] = qhb; ql_.s[jj] = f2bf(q - bf2f(qhb));
    const u16 khb = f2bf(k);
    kh_.s[jj] = khb; kl_.s[jj] = f2bf(k - bf2f(khb));
    vb_.s[jj] = f2bf(v);
  }
  *(uint2*)(Qh + dst) = qh_.u;
  *(uint2*)(Ql + dst) = ql_.u;
  *(uint2*)(Kh + dst) = kh_.u;
  *(uint2*)(Kl + dst) = kl_.u;
  *(uint2*)(Vb + dst) = vb_.u;
}

// ---------------------------------------------------------------------------
// Vb [bh][T][HD] bf16 -> VT [bh][HD][T] bf16 (64x64 tiles via LDS)
// ---------------------------------------------------------------------------
__global__ __launch_bounds__(256) void vtrans(
    const u16* __restrict__ Vb, u16* __restrict__ VT)
{
  __shared__ u16 Ls[64][72];
  const int bh = blockIdx.y, t0 = blockIdx.x * 64;
  const int tid = threadIdx.x;
  const int r = tid >> 2, c = (tid & 3) * 16;
  const size_t src = ((size_t)bh * T + t0 + r) * HD + c;
  *(int4*)&Ls[r][c]     = *(const int4*)(Vb + src);
  *(int4*)&Ls[r][c + 8] = *(const int4*)(Vb + src + 8);
  __syncthreads();
  const int d = tid >> 2, tc = (tid & 3) * 16;
  u16 buf[16];
#pragma unroll
  for (int i = 0; i < 16; ++i) buf[i] = Ls[tc + i][d];
  u16* dst = VT + ((size_t)bh * HD + d) * T + t0 + tc;
  *(int4*)dst       = *(int4*)&buf[0];
  *(int4*)(dst + 8) = *(int4*)&buf[8];
}

// ---------------------------------------------------------------------------
// sigma: LDS K-row r holds key sigma(r) so that the QK^T C-layout hands each
// lane exactly the 8-consecutive-key fragments PV's B-operand needs.
// ---------------------------------------------------------------------------
__device__ __forceinline__ int sigma_k(int r) {
  return ((r >> 5) << 5) | (((r >> 2) & 3) << 3) | (((r >> 4) & 1) << 2) | (r & 3);
}

// ---------------------------------------------------------------------------
// MFMA flash attention, swapped-operand. 8 waves x 16 q-rows (512 threads),
// KV tile 64. K hi/lo + VT staged in LDS, 3-deep counted-vmcnt pipeline
// (24KB/slot, 72KB total). XCD-clustered grid; defer-max (THR=8); lsum via
// ones-A MFMA; setprio around MFMA clusters.
// 72KB LDS x 2 blocks/CU = 144KB <= 160KB -> 16 waves/CU (4/SIMD).
// VERIFIED 93us configuration (R1/R5).
// ---------------------------------------------------------------------------
__global__ __launch_bounds__(512, 4) void flash_attn_mfma(
    const u16* __restrict__ Qh, const u16* __restrict__ Ql,
    const u16* __restrict__ Kh, const u16* __restrict__ Kl,
    const u16* __restrict__ VT, float* __restrict__ Out)
{
  __shared__ u16 sm[3 * 12288];  // slot: KH [0,4K) | KL [4K,8K) | VT [8K,12K) u16
  // XCD-clustered decode: xcd = i&7 owns heads 4*xcd..4*xcd+3
  const int i = blockIdx.x;
  const int slot = i >> 3;
  const int bh = (i & 7) * 4 + (slot >> 4);
  const int row0 = (slot & 15) * 128;
  const int b = bh >> 4, h = bh & 15;
  const int tid = threadIdx.x, wave = tid >> 6, lane = tid & 63;
  const int fr = lane & 15, kq = lane >> 4;

  // Q fragments (B-operand: col=q=fr, k=d=kq*8 within ks*32); wave owns
  // q-rows [row0 + wave*16, +16)
  bf16x8 qh[2], ql[2];
  const size_t qoff = ((size_t)bh * T + row0 + wave*16 + fr) * HD + kq*8;
#pragma unroll
  for (int ks = 0; ks < 2; ++ks) {
    qh[ks] = *(const bf16x8*)(Qh + qoff + ks*32);
    ql[ks] = *(const bf16x8*)(Ql + qoff + ks*32);
  }

  bf16x8 ones8;
#pragma unroll
  for (int z = 0; z < 8; ++z) ones8[z] = (short)0x3F80;

  f32x4 o[4] = {};
  f32x4 oex = {};                      // lsum accumulator (all 4 rows equal)
  float m_ = -1e30f;

  // staging: wave w stages chunk w (1KB) of each of the 3 arrays (8 waves
  // cover the 8 chunks). Global pointers advance by a constant per KV tile.
  const int c_ = wave;
  const int r0_ = c_ * 8 + (lane >> 3), s_ = lane & 7;
  const int cd0 = s_ ^ (r0_ & 7);
  const int k0_ = sigma_k(r0_);
  const u16* pKh0 = Kh + ((size_t)bh*T + k0_)*HD + cd0*8;
  const u16* pKl0 = Kl + ((size_t)bh*T + k0_)*HD + cd0*8;
  const u16* pV0  = VT + ((size_t)bh*HD + r0_)*T + cd0*8;

#define FSTAGE(sb) do { \
    gload16(pKh0, &sm[(sb) + c_*512]); \
    gload16(pKl0, &sm[(sb) + 4096 + c_*512]); \
    gload16(pV0,  &sm[(sb) + 8192 + c_*512]); \
    pKh0 += 64*HD; pKl0 += 64*HD; pV0 += 64; \
  } while (0)

  FSTAGE(0);
  FSTAGE(12288);
  WAITBAR3;                  // tile 0 ready (3 loads/wave); tile 1 in flight
  int cslot = 0, islot = 2;

  const int NT = T / 64;
  for (int t = 0; t < NT; ++t) {
    if (t + 2 < NT) {
      FSTAGE(islot * 12288);
      islot = (islot == 2) ? 0 : islot + 1;
    }
    const u16* smb = &sm[cslot * 12288];

    // ---- QK^T (swapped): s[n], keys sigma(16n+4kq+jj), q=fr
    f32x4 s[4] = {};
    __builtin_amdgcn_s_setprio(1);
#pragma unroll
    for (int ks = 0; ks < 2; ++ks) {
#pragma unroll
      for (int n = 0; n < 4; ++n) {
        const int kr = n * 16 + fr;
        const int sl = ((ks*4 + kq) ^ (kr & 7)) * 8;
        const bf16x8 kh_ = *(const bf16x8*)&smb[kr*64 + sl];
        const bf16x8 kl_ = *(const bf16x8*)&smb[4096 + kr*64 + sl];
        s[n] = __builtin_amdgcn_mfma_f32_16x16x32_bf16(kh_, qh[ks], s[n], 0, 0, 0);
        s[n] = __builtin_amdgcn_mfma_f32_16x16x32_bf16(kl_, qh[ks], s[n], 0, 0, 0);
        s[n] = __builtin_amdgcn_mfma_f32_16x16x32_bf16(kh_, ql[ks], s[n], 0, 0, 0);
      }
    }
    __builtin_amdgcn_s_setprio(0);

    // ---- defer-max softmax (THR=8)
    const float g0 = m3(s[0][0], s[0][1], s[0][2]);
    const float g1 = m3(s[0][3], s[1][0], s[1][1]);
    const float g2 = m3(s[1][2], s[1][3], s[2][0]);
    const float g3 = m3(s[2][1], s[2][2], s[2][3]);
    const float g4 = m3(s[3][0], s[3][1], s[3][2]);
    float mx = fmaxf(m3(g0, g1, g2), m3(g3, g4, s[3][3]));
    mx = fmaxf(mx, __shfl_xor(mx, 16));
    mx = fmaxf(mx, __shfl_xor(mx, 32));
    if (!__all(mx <= m_ + 8.0f)) {      // record tile (~10%): rescale
      const float mn = fmaxf(m_, mx);
      const float fsc = exp2f(m_ - mn);
      m_ = mn;
#pragma unroll
      for (int n = 0; n < 4; ++n) {
        o[n][0] *= fsc; o[n][1] *= fsc;
        o[n][2] *= fsc; o[n][3] *= fsc;
      }
      oex[0] *= fsc; oex[1] *= fsc; oex[2] *= fsc; oex[3] *= fsc;
    }

    float p[4][4];
#pragma unroll
    for (int n = 0; n < 4; ++n)
#pragma unroll
      for (int jj = 0; jj < 4; ++jj)
        p[n][jj] = exp2f(s[n][jj] - m_);

    unsigned pk[4][2];
#pragma unroll
    for (int n = 0; n < 4; ++n) {
      pk[n][0] = cvt_pk_bf16(p[n][0], p[n][1]);
      pk[n][1] = cvt_pk_bf16(p[n][2], p[n][3]);
    }

    // ---- in-reg P -> PV (+ lsum MFMA); V^T fragments from LDS
    __builtin_amdgcn_s_setprio(1);
#pragma unroll
    for (int ks = 0; ks < 2; ++ks) {
      union { unsigned u[4]; bf16x8 v; } pb;
      pb.u[0] = pk[2*ks][0];   pb.u[1] = pk[2*ks][1];
      pb.u[2] = pk[2*ks+1][0]; pb.u[3] = pk[2*ks+1][1];
#pragma unroll
      for (int n = 0; n < 4; ++n) {
        const int dr = n * 16 + fr;
        const bf16x8 vf = *(const bf16x8*)&smb[8192 + dr*64 + (((ks*4 + kq) ^ (dr & 7)) * 8)];
        o[n] = __builtin_amdgcn_mfma_f32_16x16x32_bf16(vf, pb.v, o[n], 0, 0, 0);
      }
      oex = __builtin_amdgcn_mfma_f32_16x16x32_bf16(ones8, pb.v, oex, 0, 0, 0);
    }
    __builtin_amdgcn_s_setprio(0);

    cslot = (cslot == 2) ? 0 : cslot + 1;
    if (t + 1 < NT) { if (t + 2 < NT) WAITBAR3; else WAITBAR0; }
  }
#undef FSTAGE

  // ---- epilogue: O^T frag has q=fr, d = 16n + 4kq + jj (jj contiguous)
  {
    const float inv = 1.0f / oex[0];
    const size_t qrow = (size_t)b * T + row0 + wave*16 + fr;
#pragma unroll
    for (int n = 0; n < 4; ++n) {
      float4 ov;
      ov.x = o[n][0] * inv; ov.y = o[n][1] * inv;
      ov.z = o[n][2] * inv; ov.w = o[n][3] * inv;
      *(float4*)(Out + qrow * H + h * HD + n * 16 + kq * 4) = ov;
    }
  }
}

// ---------------------------------------------------------------------------
// out_bf16 = LN(a + b) * gamma + beta; ddof=1, eps on std.
// fp32 output dropped — the downstream residual is ffn-dominated
// (|ffn|~1e3 vs |ln1|~3) so bf16 rounding perturbs the final LN ~1e-5.
// ---------------------------------------------------------------------------
__global__ __launch_bounds__(256) void ln_residual(
    const float* __restrict__ A, const float* __restrict__ Bz,
    const float* __restrict__ gamma, const float* __restrict__ beta,
    u16* __restrict__ obf)
{
  const int row = blockIdx.x, tid = threadIdx.x;
  const int wave = tid >> 6, lane = tid & 63;
  const size_t off = (size_t)row * H + tid * 4;
  const float4 av = *(const float4*)(A + off);
  const float4 bv = *(const float4*)(Bz + off);
  float4 y; y.x = av.x + bv.x; y.y = av.y + bv.y; y.z = av.z + bv.z; y.w = av.w + bv.w;
  float s  = y.x + y.y + y.z + y.w;
  float ss = y.x*y.x + y.y*y.y + y.z*y.z + y.w*y.w;
#pragma unroll
  for (int o = 32; o >= 1; o >>= 1) { s += __shfl_xor(s, o); ss += __shfl_xor(ss, o); }
  __shared__ float red[2][4];
  if (lane == 0) { red[0][wave] = s; red[1][wave] = ss; }
  __syncthreads();
  s  = red[0][0] + red[0][1] + red[0][2] + red[0][3];
  ss = red[1][0] + red[1][1] + red[1][2] + red[1][3];
  const float mean = s * (1.0f / (float)H);
  float var = (ss - (float)H * mean * mean) * (1.0f / (float)(H - 1));
  var = fmaxf(var, 0.0f);
  const float inv = 1.0f / (sqrtf(var) + 1e-6f);
  const float4 gv = *(const float4*)(gamma + tid * 4);
  const float4 be = *(const float4*)(beta + tid * 4);
  float4 o;
  o.x = gv.x * (y.x - mean) * inv + be.x;
  o.y = gv.y * (y.y - mean) * inv + be.y;
  o.z = gv.z * (y.z - mean) * inv + be.z;
  o.w = gv.w * (y.w - mean) * inv + be.w;
  union { u16 s[4]; uint2 u; } pk;
  pk.s[0] = f2bf(o.x); pk.s[1] = f2bf(o.y); pk.s[2] = f2bf(o.z); pk.s[3] = f2bf(o.w);
  *(uint2*)(obf + off) = pk.u;
}

// ---------------------------------------------------------------------------
// final LN only: out = LN(y) * gamma + beta (y already has residual+bias)
// ---------------------------------------------------------------------------
__global__ __launch_bounds__(256) void ln_only(
    const float* __restrict__ Yv,
    const float* __restrict__ gamma, const float* __restrict__ beta,
    float* __restrict__ out)
{
  const int row = blockIdx.x, tid = threadIdx.x;
  const int wave = tid >> 6, lane = tid & 63;
  const size_t off = (size_t)row * H + tid * 4;
  const float4 y = *(const float4*)(Yv + off);
  float s  = y.x + y.y + y.z + y.w;
  float ss = y.x*y.x + y.y*y.y + y.z*y.z + y.w*y.w;
#pragma unroll
  for (int o = 32; o >= 1; o >>= 1) { s += __shfl_xor(s, o); ss += __shfl_xor(ss, o); }
  __shared__ float red[2][4];
  if (lane == 0) { red[0][wave] = s; red[1][wave] = ss; }
  __syncthreads();
  s  = red[0][0] + red[0][1] + red[0][2] + red[0][3];
  ss = red[1][0] + red[1][1] + red[1][2] + red[1][3];
  const float mean = s * (1.0f / (float)H);
  float var = (ss - (float)H * mean * mean) * (1.0f / (float)(H - 1));
  var = fmaxf(var, 0.0f);
  const float inv = 1.0f / (sqrtf(var) + 1e-6f);
  const float4 gv = *(const float4*)(gamma + tid * 4);
  const float4 be = *(const float4*)(beta + tid * 4);
  float4 o;
  o.x = gv.x * (y.x - mean) * inv + be.x;
  o.y = gv.y * (y.y - mean) * inv + be.y;
  o.z = gv.z * (y.z - mean) * inv + be.z;
  o.w = gv.w * (y.w - mean) * inv + be.w;
  *(float4*)(out + off) = o;
}

// ---------------------------------------------------------------------------
extern "C" void kernel_launch(void* const* d_in, const int* in_sizes, int n_in,
                              void* d_out, int out_size, void* d_ws, size_t ws_size,
                              hipStream_t stream)
{
  const float* x    = (const float*)d_in[0];
  const float* Wqkv = (const float*)d_in[1];
  const float* bqkv = (const float*)d_in[2];
  const float* W1   = (const float*)d_in[3];
  const float* b1   = (const float*)d_in[4];
  const float* W2   = (const float*)d_in[5];
  const float* b2   = (const float*)d_in[6];
  const float* g1   = (const float*)d_in[7];
  const float* be1  = (const float*)d_in[8];
  const float* g2   = (const float*)d_in[9];
  const float* be2  = (const float*)d_in[10];
  float* out = (float*)d_out;
  char* w = (char*)d_ws;

  // ---- workspace map (bytes); lifetime-audited (R6 lesson) ----
  // region              offset     size    live steps
  // qkv   fp32          0          50.33M  2-3
  // h1b   bf16          0          33.55M  7-8
  // xh/Qh bf16          52428800   8.39M   1-2 / 3-5
  // xl/Ql bf16          60817408   8.39M   1-2 / 3-5
  // WqTh/Khb bf16       69206016   6.29/8.39M  1-2 / 3-5
  // WqTl bf16           75497472   6.29M   1-2
  // Klb   bf16          77594624   8.39M   3-5
  // Vbb   bf16          85983232   8.39M   3-4
  // VTb   bf16          94371840   8.39M   4-5
  // attn  fp32          102760448  16.78M  5-6
  // Y     fp32          102760448  16.78M  8-9 (over attn dead)
  // W1T   bf16          119537664  8.39M   1-7
  // W2T   bf16          127926272  8.39M   1-8
  // ln1b  bf16          136314880  8.39M   6-8
  float* qkv  = (float*)(w + 0);
  u16*   h1b  = (u16*)  (w + 0);
  u16*   xh   = (u16*)  (w + 52428800);
  u16*   xl   = (u16*)  (w + 60817408);
  u16*   Qh   = (u16*)  (w + 52428800);
  u16*   Ql   = (u16*)  (w + 60817408);
  u16*   WqTh = (u16*)  (w + 69206016);
  u16*   WqTl = (u16*)  (w + 75497472);
  u16*   Khb  = (u16*)  (w + 69206016);
  u16*   Klb  = (u16*)  (w + 77594624);
  u16*   Vbb  = (u16*)  (w + 85983232);
  u16*   VTb  = (u16*)  (w + 94371840);
  float* attn = (float*)(w + 102760448);
  float* Yb   = (float*)(w + 102760448);
  u16*   W1T  = (u16*)  (w + 119537664);
  u16*   W2T  = (u16*)  (w + 127926272);
  u16*   ln1b = (u16*)  (w + 136314880);

  // 1. preprocess: split x hi/lo + Wqkv^T hi/lo + W1^T + W2^T (one launch)
  preprocess<<<6912, 256, 0, stream>>>(x, xh, xl, Wqkv, WqTh, WqTl,
                                       W1, W1T, W2, W2T);
  // 2. qkv = (x @ Wqkv) * bqkv  [split MFMA, 2-phase; V-col Bl staging skipped]
  mfma_gemm<1,0,0,1,0><<<24 * 32, 256, 0, stream>>>(xh, xl, WqTh, WqTl, bqkv,
                                                    qkv, nullptr, M_TOK, 3*H, H);
  // 3. repack heads -> scaled/split bf16 Q,K + bf16 V (padded LDS, vec stores)
  repack_qkv<<<M_TOK, 256, 0, stream>>>(qkv, Qh, Ql, Khb, Klb, Vbb);
  // 4. V transpose
  vtrans<<<dim3(T/64, B*NH), 256, 0, stream>>>(Vbb, VTb);
  // 5. attention (MFMA, swapped-operand, XCD-clustered, 8-wave, 3-deep) — R1
  flash_attn_mfma<<<512, 512, 0, stream>>>(Qh, Ql, Khb, Klb, VTb, attn);
  // 6. ln1 = LN(x + attn) -> bf16 only
  ln_residual<<<M_TOK, 256, 0, stream>>>(x, attn, g1, be1, ln1b);
  // 7. h1 = relu((ln1 @ W1) * b1) -> bf16  [XCD-chunked, 3-deep]
  mfma_gemm<0,1,1,0,1><<<32 * 32, 256, 0, stream>>>(ln1b, nullptr, W1T, nullptr, b1,
                                                    nullptr, h1b, M_TOK, FF, H);
  // 8. y = ln1 + (h1 @ W2)*b2  [intra-block split-K, on-chip merge, fused res]
  mfma_ffn2<<<256, 512, 0, stream>>>(h1b, W2T, ln1b, b2, Yb);
  // 9. out = LN(y)
  ln_only<<<M_TOK, 256, 0, stream>>>(Yb, g2, be2, out);
}

// Round 9
// 268.254 us; speedup vs baseline: 1.3374x; 1.0892x over previous
//
#include <hip/hip_runtime.h>
#include <math.h>

// Sizes (fixed for this problem)
#define B 2
#define T 2048
#define H 1024
#define NH 16
#define HD 64
#define FF 4096
#define M_TOK (B*T)          // 4096 token rows
#define LOG2E 1.4426950408889634f

typedef unsigned short u16;
typedef __attribute__((ext_vector_type(8))) short bf16x8;
typedef __attribute__((ext_vector_type(4))) float f32x4;

// counted-vmcnt barrier: wait until only N of this wave's vmem ops remain,
// then workgroup barrier. Single asm with "memory" clobber so no memory op
// (gload_lds / ds_read) is reordered across it.
// NOTE (r8-r10 lesson): counted-vmcnt pipelines are only safe when EVERY
// LDS buffer is >=3 slots deep (overwrite target >=2 iterations stale).
// NOTE (R2 lesson): direct-to-register global V loads regress badly.
// NOTE (R3 lesson): split partials merge ON-CHIP; never 2-16B-granule
// scattered fp32 partials through global (write-amp + L2 eviction).
// NOTE (R4 lesson): 32-key KV tiles break the V bank-swizzle; R1 attention
// shape (8 waves x 16 rows, 64-key tiles, 72KB, 3-deep) is the optimum.
// NOTE (R6 lesson): WORKSPACE LIFETIME AUDIT before moving any launch.
// NOTE (R9): qkv GEMM columns PRE-PERMUTED to head-major (k*1024+h*64+d)
// via the WqT row permutation -> epilogue writes Q/K/V directly (fused
// repack, fp32 qkv intermediate + repack kernel deleted, ~100MB saved).
#define WAITBAR3  asm volatile("s_waitcnt vmcnt(3)\n\ts_barrier" ::: "memory")
#define WAITBAR4  asm volatile("s_waitcnt vmcnt(4)\n\ts_barrier" ::: "memory")
#define WAITBAR0  asm volatile("s_waitcnt vmcnt(0)\n\ts_barrier" ::: "memory")

__device__ __forceinline__ u16 f2bf(float f) {
  union { float f; unsigned u; } v; v.f = f;
  const unsigned r = (v.u + 0x7FFFu + ((v.u >> 16) & 1u)) >> 16;
  return (u16)r;
}
__device__ __forceinline__ float bf2f(u16 h) {
  union { unsigned u; float f; } v; v.u = ((unsigned)h) << 16;
  return v.f;
}
__device__ __forceinline__ unsigned cvt_pk_bf16(float lo, float hi) {
  unsigned r;
  asm("v_cvt_pk_bf16_f32 %0, %1, %2" : "=v"(r) : "v"(lo), "v"(hi));
  return r;
}
__device__ __forceinline__ float m3(float a, float b, float c) {
  return fmaxf(fmaxf(a, b), c);      // clang fuses to v_max3_f32
}
// async global->LDS, 16B per lane; dest = wave-uniform base + lane*16
__device__ __forceinline__ void gload16(const u16* g, u16* l) {
  __builtin_amdgcn_global_load_lds(
      (const __attribute__((address_space(1))) unsigned int*)g,
      (__attribute__((address_space(3))) unsigned int*)l, 16, 0, 0);
}

// head-major column permutation: orig col c (= d*48 + k*16 + h) ->
// col' = k*1024 + h*64 + d
__device__ __forceinline__ int colperm(int c) {
  const int d = c / 48;
  const int rem = c - d * 48;
  return ((rem >> 4) << 10) | ((rem & 15) << 6) | d;
}

// ---------------------------------------------------------------------------
// preprocess — ONE launch for all input-only work:
//   bid <  4096 : split x -> bf16 hi/lo (Dekker split)
//   bid <  4864 : Wqkv^T hi/lo bf16, output ROWS PERMUTED head-major (R9)
//   bid <  5888 : W1^T bf16 (64x16)
//   bid <  6912 : W2^T bf16 (16x64)
//   bid == 6912 : bqkv head-major permutation
// ---------------------------------------------------------------------------
__global__ __launch_bounds__(256) void preprocess(
    const float* __restrict__ x, u16* __restrict__ xh, u16* __restrict__ xl,
    const float* __restrict__ Wqkv, u16* __restrict__ WqTh, u16* __restrict__ WqTl,
    const float* __restrict__ W1_, u16* __restrict__ W1T_,
    const float* __restrict__ W2_, u16* __restrict__ W2T_,
    const float* __restrict__ bqkv, float* __restrict__ bqkvP)
{
  const int bid = blockIdx.x;
  const int tid = threadIdx.x;
  if (bid == 6912) {                      // ---- bias permute ----
#pragma unroll
    for (int it = 0; it < 12; ++it) {
      const int c = it * 256 + tid;
      bqkvP[colperm(c)] = bqkv[c];
    }
    return;
  }
  if (bid < 4096) {                       // ---- split_hl ----
    const size_t i = ((size_t)bid * 256 + tid) * 4;
    const float4 v = *(const float4*)(x + i);
    union { u16 s[4]; uint2 u; } h, l;
    const float f[4] = {v.x, v.y, v.z, v.w};
#pragma unroll
    for (int j = 0; j < 4; ++j) {
      const u16 hb = f2bf(f[j]); h.s[j] = hb; l.s[j] = f2bf(f[j] - bf2f(hb));
    }
    *(uint2*)(xh + i) = h.u;
    *(uint2*)(xl + i) = l.u;
    return;
  }
  // ---- transpose-convert paths (uniform per block) ----
  __shared__ float tile[64][69];
  const float* in; u16* oh; u16* ol = nullptr;
  int K, N, k0, n0, split = 0, permq = 0;
  if (bid < 4864) {
    const int tb = bid - 4096;
    in = Wqkv; oh = WqTh; ol = WqTl; K = H; N = 3*H; split = 1; permq = 1;
    n0 = (tb % 48) * 64; k0 = (tb / 48) * 64;
  } else if (bid < 5888) {
    const int tb = bid - 4864;
    in = W1_; oh = W1T_; K = H; N = FF;
    n0 = (tb & 63) * 64; k0 = (tb >> 6) * 64;
  } else {
    const int tb = bid - 5888;
    in = W2_; oh = W2T_; K = FF; N = H;
    n0 = (tb & 15) * 64; k0 = (tb >> 4) * 64;
  }
  const int r = tid >> 4, c4 = (tid & 15) * 4;
#pragma unroll
  for (int i = 0; i < 4; ++i) {
    const float4 v = *(const float4*)(in + (size_t)(k0 + i*16 + r) * N + n0 + c4);
    tile[i*16+r][c4]   = v.x; tile[i*16+r][c4+1] = v.y;
    tile[i*16+r][c4+2] = v.z; tile[i*16+r][c4+3] = v.w;
  }
  __syncthreads();
  const int n = tid >> 2, kq = tid & 3;
  union { u16 s[8]; int4 v; } ph0, ph1, pl0, pl1;
#pragma unroll
  for (int j = 0; j < 8; ++j) {
    const float f0 = tile[kq*16 + j][n];
    const float f1 = tile[kq*16 + 8 + j][n];
    const u16 h0 = f2bf(f0), h1 = f2bf(f1);
    ph0.s[j] = h0; ph1.s[j] = h1;
    if (split) { pl0.s[j] = f2bf(f0 - bf2f(h0)); pl1.s[j] = f2bf(f1 - bf2f(h1)); }
  }
  int orow = n0 + n;
  if (permq) orow = colperm(orow);        // head-major output row (R9)
  u16* po = oh + (size_t)orow * K + k0 + kq * 16;
  *(int4*)po = ph0.v; *(int4*)(po + 8) = ph1.v;
  if (split) {
    u16* pl = ol + (size_t)orow * K + k0 + kq * 16;
    *(int4*)pl = pl0.v; *(int4*)(pl + 8) = pl1.v;
  }
}

// ---------------------------------------------------------------------------
// MFMA GEMM (FFN1 use): C = relu((A @ B^T) * bias) -> bf16.
// 128x128 tile, BK=32, global_load_lds staging, XCD-chunked 1-D grid.
// DEEP3: 3-slot LDS ring + counted vmcnt(4) barriers. 48KB.
// ---------------------------------------------------------------------------
__device__ __forceinline__ int swz(int r, int kq) {
  return r * 32 + ((kq ^ ((r >> 1) & 3)) * 8);
}

template<int RELU, int OBF>
__global__ __launch_bounds__(256) void mfma_gemm(
    const u16* __restrict__ Ah, const u16* __restrict__ Bh,
    const float* __restrict__ bias,
    float* __restrict__ Cf, u16* __restrict__ Cb,
    int M, int N, int K)
{
  __shared__ u16 lds[24576];
  const int tid = threadIdx.x;
  const int bid = blockIdx.x;
  const int xcd = bid & 7;
  const int idx = bid >> 3;
  const int row0 = (xcd * 4 + (idx & 3)) * 128;
  const int col0 = (idx >> 2) * 128;
  const int wv = tid >> 6, lane = tid & 63;
  const int wr = wv >> 1, wc = wv & 1;
  const int kq = lane >> 4, fr = lane & 15;

  f32x4 acc[4][4] = {};

#define GSTAGE(lbase, gb, rowbase, kk) do { \
    _Pragma("unroll") \
    for (int t_ = 0; t_ < 2; ++t_) { \
      const int c_ = wv * 2 + t_; \
      const int idx_ = c_ * 64 + lane; \
      const int r_ = idx_ >> 2; \
      const int kq_ = (idx_ & 3) ^ ((r_ >> 1) & 3); \
      gload16((gb) + (size_t)((rowbase) + r_) * K + (kk) + kq_ * 8, \
              &lds[(lbase) + c_ * 512]); \
    } } while (0)

  const int nk = K >> 5;
  GSTAGE(0, Ah, row0, 0);            GSTAGE(4096, Bh, col0, 0);
  GSTAGE(8192, Ah, row0, 32);        GSTAGE(8192 + 4096, Bh, col0, 32);
  WAITBAR4;                            // stage 0 ready; stage 1 in flight
  int cslot = 0, islot = 2;
  for (int i = 0; i < nk; ++i) {
    if (i + 2 < nk) {
      const int kk = (i + 2) * 32;
      GSTAGE(islot * 8192, Ah, row0, kk);
      GSTAGE(islot * 8192 + 4096, Bh, col0, kk);
      islot = (islot == 2) ? 0 : islot + 1;
    }
    const int rb = cslot * 8192;
    bf16x8 a_h[4];
#pragma unroll
    for (int m = 0; m < 4; ++m)
      a_h[m] = *(const bf16x8*)&lds[rb + swz(wr*64 + m*16 + fr, kq)];
#pragma unroll
    for (int n = 0; n < 4; ++n) {
      const bf16x8 b_h = *(const bf16x8*)&lds[rb + 4096 + swz(wc*64 + n*16 + fr, kq)];
#pragma unroll
      for (int m = 0; m < 4; ++m)
        acc[m][n] = __builtin_amdgcn_mfma_f32_16x16x32_bf16(a_h[m], b_h, acc[m][n], 0, 0, 0);
    }
    cslot = (cslot == 2) ? 0 : cslot + 1;
    if (i + 1 < nk) { if (i + 2 < nk) WAITBAR4; else WAITBAR0; }
  }
#undef GSTAGE

  const int orow0 = row0 + wr * 64, ocol0 = col0 + wc * 64;
#pragma unroll
  for (int n = 0; n < 4; ++n) {
    const int col = ocol0 + n * 16 + fr;
    const float bs = bias[col];
#pragma unroll
    for (int m = 0; m < 4; ++m) {
      const int rbase = orow0 + m * 16 + kq * 4;
#pragma unroll
      for (int j = 0; j < 4; ++j) {
        float v = acc[m][n][j] * bs;
        if (RELU) v = fmaxf(v, 0.0f);
        const size_t off = (size_t)(rbase + j) * N + col;
        if (OBF) Cb[off] = f2bf(v); else Cf[off] = v;
      }
    }
  }
}

// ---------------------------------------------------------------------------
// QKV GEMM with FUSED REPACK (R9). Columns are head-major permuted
// (col' = k*1024 + h*64 + d via WqT row perm), so each 128-col block is
// pure Q, K or V. SPLIT hi/lo 3-term for Q/K blocks; V blocks are plain
// hi*hi and skip ALL lo staging. 2-phase double-buffer (64KB LDS,
// 2 blocks/CU). Epilogue applies bias (+qscale for Q), Dekker-splits, and
// writes Qh/Ql/Kh/Kl/Vb DIRECTLY in [bh][T][HD] layout — the fp32 qkv
// intermediate and the repack kernel are gone (~100MB HBM saved).
// Arithmetic order identical to old GEMM+repack -> bit-identical outputs.
// ---------------------------------------------------------------------------
__global__ __launch_bounds__(256) void mfma_qkv(
    const u16* __restrict__ Ah, const u16* __restrict__ Al,
    const u16* __restrict__ Bh, const u16* __restrict__ Bl,
    const float* __restrict__ biasP,
    u16* __restrict__ Qh, u16* __restrict__ Ql,
    u16* __restrict__ Kh, u16* __restrict__ Kl, u16* __restrict__ Vb)
{
  const int K = H;
  __shared__ u16 lds[32768];
  const int tid = threadIdx.x;
  const int bid = blockIdx.x;            // 768 = 8 xcd x 4 rowchunk x 24 col
  const int xcd = bid & 7;
  const int idx = bid >> 3;
  const int row0 = (xcd * 4 + (idx & 3)) * 128;
  const int col0 = (idx >> 2) * 128;     // col' base, [0, 3072)
  const int wv = tid >> 6, lane = tid & 63;
  const int wr = wv >> 1, wc = wv & 1;
  const int kq = lane >> 4, fr = lane & 15;
  const bool isV = (col0 >= 2048);       // block-uniform class (R9)

  f32x4 acc[4][4] = {};

#define QSTAGE(lbase, gb, rowbase, kk) do { \
    _Pragma("unroll") \
    for (int t_ = 0; t_ < 2; ++t_) { \
      const int c_ = wv * 2 + t_; \
      const int idx_ = c_ * 64 + lane; \
      const int r_ = idx_ >> 2; \
      const int kq_ = (idx_ & 3) ^ ((r_ >> 1) & 3); \
      gload16((gb) + (size_t)((rowbase) + r_) * K + (kk) + kq_ * 8, \
              &lds[(lbase) + c_ * 512]); \
    } } while (0)

  QSTAGE(0, Ah, row0, 0);
  QSTAGE(4096, Bh, col0, 0);
  if (!isV) { QSTAGE(8192, Al, row0, 0); QSTAGE(12288, Bl, col0, 0); }
  __syncthreads();

  int cur = 0;
  for (int k0 = 0; k0 < K; k0 += 32) {
    const int nxt = cur ^ 1;
    if (k0 + 32 < K) {
      QSTAGE(nxt*16384, Ah, row0, k0 + 32);
      QSTAGE(nxt*16384 + 4096, Bh, col0, k0 + 32);
      if (!isV) { QSTAGE(nxt*16384 + 8192, Al, row0, k0 + 32);
                  QSTAGE(nxt*16384 + 12288, Bl, col0, k0 + 32); }
    }
    const int rb = cur * 16384;
    bf16x8 a_h[4], a_l[4];
#pragma unroll
    for (int m = 0; m < 4; ++m) {
      a_h[m] = *(const bf16x8*)&lds[rb + swz(wr*64 + m*16 + fr, kq)];
      if (!isV) a_l[m] = *(const bf16x8*)&lds[rb + 8192 + swz(wr*64 + m*16 + fr, kq)];
    }
#pragma unroll
    for (int n = 0; n < 4; ++n) {
      const bf16x8 b_h = *(const bf16x8*)&lds[rb + 4096 + swz(wc*64 + n*16 + fr, kq)];
#pragma unroll
      for (int m = 0; m < 4; ++m)
        acc[m][n] = __builtin_amdgcn_mfma_f32_16x16x32_bf16(a_h[m], b_h, acc[m][n], 0, 0, 0);
      if (!isV) {
        const bf16x8 b_l = *(const bf16x8*)&lds[rb + 12288 + swz(wc*64 + n*16 + fr, kq)];
#pragma unroll
        for (int m = 0; m < 4; ++m) {
          acc[m][n] = __builtin_amdgcn_mfma_f32_16x16x32_bf16(a_h[m], b_l, acc[m][n], 0, 0, 0);
          acc[m][n] = __builtin_amdgcn_mfma_f32_16x16x32_bf16(a_l[m], b_h, acc[m][n], 0, 0, 0);
        }
      }
    }
    __syncthreads();
    cur = nxt;
  }
#undef QSTAGE

  // ---- fused repack epilogue: col' -> (k,h,d); write final head layout.
  // Lanes fr = 16 consecutive d -> 32B-contiguous stores per (n,m,j).
  const float qscale = LOG2E / 32.0f;
  const int orow0 = row0 + wr * 64, ocol0 = col0 + wc * 64;
  const int kcls = col0 >> 10;           // 0=Q, 1=K, 2=V (uniform)
#pragma unroll
  for (int n = 0; n < 4; ++n) {
    const int colp = ocol0 + n * 16 + fr;
    const int d = colp & 63, hh = (colp >> 6) & 15;
    const float bs = biasP[colp];
#pragma unroll
    for (int m = 0; m < 4; ++m) {
      const int rbase = orow0 + m * 16 + kq * 4;
#pragma unroll
      for (int j = 0; j < 4; ++j) {
        const int row = rbase + j;
        const int b = row >> 11, t = row & (T - 1);
        const size_t dst = (((size_t)(b * NH + hh)) * T + t) * HD + d;
        float v = acc[m][n][j] * bs;
        if (kcls == 0) {
          v *= qscale;
          const u16 hb = f2bf(v);
          Qh[dst] = hb; Ql[dst] = f2bf(v - bf2f(hb));
        } else if (kcls == 1) {
          const u16 hb = f2bf(v);
          Kh[dst] = hb; Kl[dst] = f2bf(v - bf2f(hb));
        } else {
          Vb[dst] = f2bf(v);
        }
      }
    }
  }
}

// ---------------------------------------------------------------------------
// FFN2 with INTRA-BLOCK split-K (R8): y = ln1 + (h1 @ W2) * b2, fp32.
// 512 threads = 2 groups x 4 waves; group g runs the DEEP3 counted-vmcnt
// ring over K-half in its own 48KB LDS region (96KB total, 1 block/CU).
// Merge: group1 dumps acc to LDS, group0 adds + fuses ln1 residual + bias.
// ---------------------------------------------------------------------------
__global__ __launch_bounds__(512, 2) void mfma_ffn2(
    const u16* __restrict__ Ah, const u16* __restrict__ Bh,
    const u16* __restrict__ Res, const float* __restrict__ bias,
    float* __restrict__ Y)
{
  const int N = H, K = FF;
  __shared__ u16 lds[2 * 24576];        // 96KB: per-group 3-slot ring
  const int tid = threadIdx.x;
  const int bid = blockIdx.x;           // 256 blocks
  const int xcd = bid & 7;
  const int idx = bid >> 3;             // [0,32)
  const int row0 = (xcd * 4 + (idx & 3)) * 128;
  const int col0 = (idx >> 2) * 128;    // [0, 1024)
  const int wv8 = tid >> 6, lane = tid & 63;
  const int grp = wv8 >> 2, wv = wv8 & 3;
  const int wr = wv >> 1, wc = wv & 1;
  const int kq = lane >> 4, fr = lane & 15;
  const int kb = grp * (K >> 1);
  u16* gl = &lds[grp * 24576];

  f32x4 acc[4][4] = {};

#define GSTAGE2(lbase, gb, rowbase, kk) do { \
    _Pragma("unroll") \
    for (int t_ = 0; t_ < 2; ++t_) { \
      const int c_ = wv * 2 + t_; \
      const int idx_ = c_ * 64 + lane; \
      const int r_ = idx_ >> 2; \
      const int kq_ = (idx_ & 3) ^ ((r_ >> 1) & 3); \
      gload16((gb) + (size_t)((rowbase) + r_) * K + (kk) + kq_ * 8, \
              &gl[(lbase) + c_ * 512]); \
    } } while (0)

  const int nk = (K >> 1) >> 5;         // 64 steps per group
  GSTAGE2(0, Ah, row0, kb);            GSTAGE2(4096, Bh, col0, kb);
  GSTAGE2(8192, Ah, row0, kb + 32);    GSTAGE2(8192 + 4096, Bh, col0, kb + 32);
  WAITBAR4;
  int cslot = 0, islot = 2;
  for (int i = 0; i < nk; ++i) {
    if (i + 2 < nk) {
      const int kk = kb + (i + 2) * 32;
      GSTAGE2(islot * 8192, Ah, row0, kk);
      GSTAGE2(islot * 8192 + 4096, Bh, col0, kk);
      islot = (islot == 2) ? 0 : islot + 1;
    }
    const int rb = cslot * 8192;
    bf16x8 a_h[4];
#pragma unroll
    for (int m = 0; m < 4; ++m)
      a_h[m] = *(const bf16x8*)&gl[rb + swz(wr*64 + m*16 + fr, kq)];
#pragma unroll
    for (int n = 0; n < 4; ++n) {
      const bf16x8 b_h = *(const bf16x8*)&gl[rb + 4096 + swz(wc*64 + n*16 + fr, kq)];
#pragma unroll
      for (int m = 0; m < 4; ++m)
        acc[m][n] = __builtin_amdgcn_mfma_f32_16x16x32_bf16(a_h[m], b_h, acc[m][n], 0, 0, 0);
    }
    cslot = (cslot == 2) ? 0 : cslot + 1;
    if (i + 1 < nk) { if (i + 2 < nk) WAITBAR4; else WAITBAR0; }
  }
#undef GSTAGE2

  // ---- on-chip merge + fused residual epilogue ----
  __syncthreads();                      // all ring reads done (drains cnts)
  float* fm = (float*)lds;              // 24576 floats available
  const int base = wv * 4096;           // 16KB per wave-pair region
  if (grp == 1) {
#pragma unroll
    for (int m = 0; m < 4; ++m)
#pragma unroll
      for (int n = 0; n < 4; ++n)
        *(f32x4*)&fm[base + (m*4 + n)*256 + lane*4] = acc[m][n];
  }
  __syncthreads();
  if (grp == 0) {
    const int orow0 = row0 + wr * 64, ocol0 = col0 + wc * 64;
#pragma unroll
    for (int n = 0; n < 4; ++n) {
      const int col = ocol0 + n * 16 + fr;
      const float bs = bias[col];
#pragma unroll
      for (int m = 0; m < 4; ++m) {
        const f32x4 ob = *(const f32x4*)&fm[base + (m*4 + n)*256 + lane*4];
        const int rbase = orow0 + m * 16 + kq * 4;
#pragma unroll
        for (int j = 0; j < 4; ++j) {
          const size_t off = (size_t)(rbase + j) * N + col;
          Y[off] = bf2f(Res[off]) + (acc[m][n][j] + ob[j]) * bs;
        }
      }
    }
  }
}

// ---------------------------------------------------------------------------
// Vb [bh][T][HD] bf16 -> VT [bh][HD][T] bf16 (64x64 tiles via LDS)
// ---------------------------------------------------------------------------
__global__ __launch_bounds__(256) void vtrans(
    const u16* __restrict__ Vb, u16* __restrict__ VT)
{
  __shared__ u16 Ls[64][72];
  const int bh = blockIdx.y, t0 = blockIdx.x * 64;
  const int tid = threadIdx.x;
  const int r = tid >> 2, c = (tid & 3) * 16;
  const size_t src = ((size_t)bh * T + t0 + r) * HD + c;
  *(int4*)&Ls[r][c]     = *(const int4*)(Vb + src);
  *(int4*)&Ls[r][c + 8] = *(const int4*)(Vb + src + 8);
  __syncthreads();
  const int d = tid >> 2, tc = (tid & 3) * 16;
  u16 buf[16];
#pragma unroll
  for (int i = 0; i < 16; ++i) buf[i] = Ls[tc + i][d];
  u16* dst = VT + ((size_t)bh * HD + d) * T + t0 + tc;
  *(int4*)dst       = *(int4*)&buf[0];
  *(int4*)(dst + 8) = *(int4*)&buf[8];
}

// ---------------------------------------------------------------------------
// sigma: LDS K-row r holds key sigma(r) so that the QK^T C-layout hands each
// lane exactly the 8-consecutive-key fragments PV's B-operand needs.
// ---------------------------------------------------------------------------
__device__ __forceinline__ int sigma_k(int r) {
  return ((r >> 5) << 5) | (((r >> 2) & 3) << 3) | (((r >> 4) & 1) << 2) | (r & 3);
}

// ---------------------------------------------------------------------------
// MFMA flash attention, swapped-operand. 8 waves x 16 q-rows (512 threads),
// KV tile 64. K hi/lo + VT staged in LDS, 3-deep counted-vmcnt pipeline
// (24KB/slot, 72KB total). XCD-clustered grid; defer-max (THR=8); lsum via
// ones-A MFMA; setprio around MFMA clusters.
// 72KB LDS x 2 blocks/CU = 144KB <= 160KB -> 16 waves/CU (4/SIMD).
// VERIFIED 93us configuration (R1/R5).
// ---------------------------------------------------------------------------
__global__ __launch_bounds__(512, 4) void flash_attn_mfma(
    const u16* __restrict__ Qh, const u16* __restrict__ Ql,
    const u16* __restrict__ Kh, const u16* __restrict__ Kl,
    const u16* __restrict__ VT, float* __restrict__ Out)
{
  __shared__ u16 sm[3 * 12288];  // slot: KH [0,4K) | KL [4K,8K) | VT [8K,12K) u16
  // XCD-clustered decode: xcd = i&7 owns heads 4*xcd..4*xcd+3
  const int i = blockIdx.x;
  const int slot = i >> 3;
  const int bh = (i & 7) * 4 + (slot >> 4);
  const int row0 = (slot & 15) * 128;
  const int b = bh >> 4, h = bh & 15;
  const int tid = threadIdx.x, wave = tid >> 6, lane = tid & 63;
  const int fr = lane & 15, kq = lane >> 4;

  // Q fragments (B-operand: col=q=fr, k=d=kq*8 within ks*32); wave owns
  // q-rows [row0 + wave*16, +16)
  bf16x8 qh[2], ql[2];
  const size_t qoff = ((size_t)bh * T + row0 + wave*16 + fr) * HD + kq*8;
#pragma unroll
  for (int ks = 0; ks < 2; ++ks) {
    qh[ks] = *(const bf16x8*)(Qh + qoff + ks*32);
    ql[ks] = *(const bf16x8*)(Ql + qoff + ks*32);
  }

  bf16x8 ones8;
#pragma unroll
  for (int z = 0; z < 8; ++z) ones8[z] = (short)0x3F80;

  f32x4 o[4] = {};
  f32x4 oex = {};                      // lsum accumulator (all 4 rows equal)
  float m_ = -1e30f;

  // staging: wave w stages chunk w (1KB) of each of the 3 arrays (8 waves
  // cover the 8 chunks). Global pointers advance by a constant per KV tile.
  const int c_ = wave;
  const int r0_ = c_ * 8 + (lane >> 3), s_ = lane & 7;
  const int cd0 = s_ ^ (r0_ & 7);
  const int k0_ = sigma_k(r0_);
  const u16* pKh0 = Kh + ((size_t)bh*T + k0_)*HD + cd0*8;
  const u16* pKl0 = Kl + ((size_t)bh*T + k0_)*HD + cd0*8;
  const u16* pV0  = VT + ((size_t)bh*HD + r0_)*T + cd0*8;

#define FSTAGE(sb) do { \
    gload16(pKh0, &sm[(sb) + c_*512]); \
    gload16(pKl0, &sm[(sb) + 4096 + c_*512]); \
    gload16(pV0,  &sm[(sb) + 8192 + c_*512]); \
    pKh0 += 64*HD; pKl0 += 64*HD; pV0 += 64; \
  } while (0)

  FSTAGE(0);
  FSTAGE(12288);
  WAITBAR3;                  // tile 0 ready (3 loads/wave); tile 1 in flight
  int cslot = 0, islot = 2;

  const int NT = T / 64;
  for (int t = 0; t < NT; ++t) {
    if (t + 2 < NT) {
      FSTAGE(islot * 12288);
      islot = (islot == 2) ? 0 : islot + 1;
    }
    const u16* smb = &sm[cslot * 12288];

    // ---- QK^T (swapped): s[n], keys sigma(16n+4kq+jj), q=fr
    f32x4 s[4] = {};
    __builtin_amdgcn_s_setprio(1);
#pragma unroll
    for (int ks = 0; ks < 2; ++ks) {
#pragma unroll
      for (int n = 0; n < 4; ++n) {
        const int kr = n * 16 + fr;
        const int sl = ((ks*4 + kq) ^ (kr & 7)) * 8;
        const bf16x8 kh_ = *(const bf16x8*)&smb[kr*64 + sl];
        const bf16x8 kl_ = *(const bf16x8*)&smb[4096 + kr*64 + sl];
        s[n] = __builtin_amdgcn_mfma_f32_16x16x32_bf16(kh_, qh[ks], s[n], 0, 0, 0);
        s[n] = __builtin_amdgcn_mfma_f32_16x16x32_bf16(kl_, qh[ks], s[n], 0, 0, 0);
        s[n] = __builtin_amdgcn_mfma_f32_16x16x32_bf16(kh_, ql[ks], s[n], 0, 0, 0);
      }
    }
    __builtin_amdgcn_s_setprio(0);

    // ---- defer-max softmax (THR=8)
    const float g0 = m3(s[0][0], s[0][1], s[0][2]);
    const float g1 = m3(s[0][3], s[1][0], s[1][1]);
    const float g2 = m3(s[1][2], s[1][3], s[2][0]);
    const float g3 = m3(s[2][1], s[2][2], s[2][3]);
    const float g4 = m3(s[3][0], s[3][1], s[3][2]);
    float mx = fmaxf(m3(g0, g1, g2), m3(g3, g4, s[3][3]));
    mx = fmaxf(mx, __shfl_xor(mx, 16));
    mx = fmaxf(mx, __shfl_xor(mx, 32));
    if (!__all(mx <= m_ + 8.0f)) {      // record tile (~10%): rescale
      const float mn = fmaxf(m_, mx);
      const float fsc = exp2f(m_ - mn);
      m_ = mn;
#pragma unroll
      for (int n = 0; n < 4; ++n) {
        o[n][0] *= fsc; o[n][1] *= fsc;
        o[n][2] *= fsc; o[n][3] *= fsc;
      }
      oex[0] *= fsc; oex[1] *= fsc; oex[2] *= fsc; oex[3] *= fsc;
    }

    float p[4][4];
#pragma unroll
    for (int n = 0; n < 4; ++n)
#pragma unroll
      for (int jj = 0; jj < 4; ++jj)
        p[n][jj] = exp2f(s[n][jj] - m_);

    unsigned pk[4][2];
#pragma unroll
    for (int n = 0; n < 4; ++n) {
      pk[n][0] = cvt_pk_bf16(p[n][0], p[n][1]);
      pk[n][1] = cvt_pk_bf16(p[n][2], p[n][3]);
    }

    // ---- in-reg P -> PV (+ lsum MFMA); V^T fragments from LDS
    __builtin_amdgcn_s_setprio(1);
#pragma unroll
    for (int ks = 0; ks < 2; ++ks) {
      union { unsigned u[4]; bf16x8 v; } pb;
      pb.u[0] = pk[2*ks][0];   pb.u[1] = pk[2*ks][1];
      pb.u[2] = pk[2*ks+1][0]; pb.u[3] = pk[2*ks+1][1];
#pragma unroll
      for (int n = 0; n < 4; ++n) {
        const int dr = n * 16 + fr;
        const bf16x8 vf = *(const bf16x8*)&smb[8192 + dr*64 + (((ks*4 + kq) ^ (dr & 7)) * 8)];
        o[n] = __builtin_amdgcn_mfma_f32_16x16x32_bf16(vf, pb.v, o[n], 0, 0, 0);
      }
      oex = __builtin_amdgcn_mfma_f32_16x16x32_bf16(ones8, pb.v, oex, 0, 0, 0);
    }
    __builtin_amdgcn_s_setprio(0);

    cslot = (cslot == 2) ? 0 : cslot + 1;
    if (t + 1 < NT) { if (t + 2 < NT) WAITBAR3; else WAITBAR0; }
  }
#undef FSTAGE

  // ---- epilogue: O^T frag has q=fr, d = 16n + 4kq + jj (jj contiguous)
  {
    const float inv = 1.0f / oex[0];
    const size_t qrow = (size_t)b * T + row0 + wave*16 + fr;
#pragma unroll
    for (int n = 0; n < 4; ++n) {
      float4 ov;
      ov.x = o[n][0] * inv; ov.y = o[n][1] * inv;
      ov.z = o[n][2] * inv; ov.w = o[n][3] * inv;
      *(float4*)(Out + qrow * H + h * HD + n * 16 + kq * 4) = ov;
    }
  }
}

// ---------------------------------------------------------------------------
// out_bf16 = LN(a + b) * gamma + beta; ddof=1, eps on std.
// fp32 output dropped — the downstream residual is ffn-dominated
// (|ffn|~1e3 vs |ln1|~3) so bf16 rounding perturbs the final LN ~1e-5.
// ---------------------------------------------------------------------------
__global__ __launch_bounds__(256) void ln_residual(
    const float* __restrict__ A, const float* __restrict__ Bz,
    const float* __restrict__ gamma, const float* __restrict__ beta,
    u16* __restrict__ obf)
{
  const int row = blockIdx.x, tid = threadIdx.x;
  const int wave = tid >> 6, lane = tid & 63;
  const size_t off = (size_t)row * H + tid * 4;
  const float4 av = *(const float4*)(A + off);
  const float4 bv = *(const float4*)(Bz + off);
  float4 y; y.x = av.x + bv.x; y.y = av.y + bv.y; y.z = av.z + bv.z; y.w = av.w + bv.w;
  float s  = y.x + y.y + y.z + y.w;
  float ss = y.x*y.x + y.y*y.y + y.z*y.z + y.w*y.w;
#pragma unroll
  for (int o = 32; o >= 1; o >>= 1) { s += __shfl_xor(s, o); ss += __shfl_xor(ss, o); }
  __shared__ float red[2][4];
  if (lane == 0) { red[0][wave] = s; red[1][wave] = ss; }
  __syncthreads();
  s  = red[0][0] + red[0][1] + red[0][2] + red[0][3];
  ss = red[1][0] + red[1][1] + red[1][2] + red[1][3];
  const float mean = s * (1.0f / (float)H);
  float var = (ss - (float)H * mean * mean) * (1.0f / (float)(H - 1));
  var = fmaxf(var, 0.0f);
  const float inv = 1.0f / (sqrtf(var) + 1e-6f);
  const float4 gv = *(const float4*)(gamma + tid * 4);
  const float4 be = *(const float4*)(beta + tid * 4);
  float4 o;
  o.x = gv.x * (y.x - mean) * inv + be.x;
  o.y = gv.y * (y.y - mean) * inv + be.y;
  o.z = gv.z * (y.z - mean) * inv + be.z;
  o.w = gv.w * (y.w - mean) * inv + be.w;
  union { u16 s[4]; uint2 u; } pk;
  pk.s[0] = f2bf(o.x); pk.s[1] = f2bf(o.y); pk.s[2] = f2bf(o.z); pk.s[3] = f2bf(o.w);
  *(uint2*)(obf + off) = pk.u;
}

// ---------------------------------------------------------------------------
// final LN only: out = LN(y) * gamma + beta (y already has residual+bias)
// ---------------------------------------------------------------------------
__global__ __launch_bounds__(256) void ln_only(
    const float* __restrict__ Yv,
    const float* __restrict__ gamma, const float* __restrict__ beta,
    float* __restrict__ out)
{
  const int row = blockIdx.x, tid = threadIdx.x;
  const int wave = tid >> 6, lane = tid & 63;
  const size_t off = (size_t)row * H + tid * 4;
  const float4 y = *(const float4*)(Yv + off);
  float s  = y.x + y.y + y.z + y.w;
  float ss = y.x*y.x + y.y*y.y + y.z*y.z + y.w*y.w;
#pragma unroll
  for (int o = 32; o >= 1; o >>= 1) { s += __shfl_xor(s, o); ss += __shfl_xor(ss, o); }
  __shared__ float red[2][4];
  if (lane == 0) { red[0][wave] = s; red[1][wave] = ss; }
  __syncthreads();
  s  = red[0][0] + red[0][1] + red[0][2] + red[0][3];
  ss = red[1][0] + red[1][1] + red[1][2] + red[1][3];
  const float mean = s * (1.0f / (float)H);
  float var = (ss - (float)H * mean * mean) * (1.0f / (float)(H - 1));
  var = fmaxf(var, 0.0f);
  const float inv = 1.0f / (sqrtf(var) + 1e-6f);
  const float4 gv = *(const float4*)(gamma + tid * 4);
  const float4 be = *(const float4*)(beta + tid * 4);
  float4 o;
  o.x = gv.x * (y.x - mean) * inv + be.x;
  o.y = gv.y * (y.y - mean) * inv + be.y;
  o.z = gv.z * (y.z - mean) * inv + be.z;
  o.w = gv.w * (y.w - mean) * inv + be.w;
  *(float4*)(out + off) = o;
}

// ---------------------------------------------------------------------------
extern "C" void kernel_launch(void* const* d_in, const int* in_sizes, int n_in,
                              void* d_out, int out_size, void* d_ws, size_t ws_size,
                              hipStream_t stream)
{
  const float* x    = (const float*)d_in[0];
  const float* Wqkv = (const float*)d_in[1];
  const float* bqkv = (const float*)d_in[2];
  const float* W1   = (const float*)d_in[3];
  const float* b1   = (const float*)d_in[4];
  const float* W2   = (const float*)d_in[5];
  const float* b2   = (const float*)d_in[6];
  const float* g1   = (const float*)d_in[7];
  const float* be1  = (const float*)d_in[8];
  const float* g2   = (const float*)d_in[9];
  const float* be2  = (const float*)d_in[10];
  float* out = (float*)d_out;
  char* w = (char*)d_ws;

  // ---- workspace map (bytes); lifetime-audited (R6 lesson; R9 re-audit) --
  // region              offset     size    live steps
  // Qh    bf16          0          8.39M   2-4
  // Ql    bf16          8388608    8.39M   2-4
  // Khb   bf16          16777216   8.39M   2-4
  // Klb   bf16          25165824   8.39M   2-4
  // Vbb   bf16          33554432   8.39M   2-3
  // VTb   bf16          41943040   8.39M   3-4
  // h1b   bf16          0          33.55M  6-7 (over Q/K/V dead)
  // xh    bf16          52428800   8.39M   1-2
  // xl    bf16          60817408   8.39M   1-2
  // WqTh  bf16          69206016   6.29M   1-2
  // WqTl  bf16          75497472   6.29M   1-2
  // attn  fp32          102760448  16.78M  4-5
  // Y     fp32          102760448  16.78M  7-8 (over attn dead)
  // W1T   bf16          119537664  8.39M   1-6
  // W2T   bf16          127926272  8.39M   1-7
  // ln1b  bf16          136314880  8.39M   5-8
  // bqkvP fp32          144703488  12KB    1-2
  u16*   Qh    = (u16*)  (w + 0);
  u16*   Ql    = (u16*)  (w + 8388608);
  u16*   Khb   = (u16*)  (w + 16777216);
  u16*   Klb   = (u16*)  (w + 25165824);
  u16*   Vbb   = (u16*)  (w + 33554432);
  u16*   VTb   = (u16*)  (w + 41943040);
  u16*   h1b   = (u16*)  (w + 0);
  u16*   xh    = (u16*)  (w + 52428800);
  u16*   xl    = (u16*)  (w + 60817408);
  u16*   WqTh  = (u16*)  (w + 69206016);
  u16*   WqTl  = (u16*)  (w + 75497472);
  float* attn  = (float*)(w + 102760448);
  float* Yb    = (float*)(w + 102760448);
  u16*   W1T   = (u16*)  (w + 119537664);
  u16*   W2T   = (u16*)  (w + 127926272);
  u16*   ln1b  = (u16*)  (w + 136314880);
  float* bqkvP = (float*)(w + 144703488);

  // 1. preprocess: split x hi/lo + Wqkv^T (head-major perm) + W1^T + W2^T
  //    + bqkv permutation — one launch
  preprocess<<<6913, 256, 0, stream>>>(x, xh, xl, Wqkv, WqTh, WqTl,
                                       W1, W1T, W2, W2T, bqkv, bqkvP);
  // 2. QKV GEMM with fused repack -> Qh/Ql/Kh/Kl/Vb directly
  mfma_qkv<<<24 * 32, 256, 0, stream>>>(xh, xl, WqTh, WqTl, bqkvP,
                                        Qh, Ql, Khb, Klb, Vbb);
  // 3. V transpose
  vtrans<<<dim3(T/64, B*NH), 256, 0, stream>>>(Vbb, VTb);
  // 4. attention (MFMA, swapped-operand, XCD-clustered, 8-wave, 3-deep) — R1
  flash_attn_mfma<<<512, 512, 0, stream>>>(Qh, Ql, Khb, Klb, VTb, attn);
  // 5. ln1 = LN(x + attn) -> bf16 only
  ln_residual<<<M_TOK, 256, 0, stream>>>(x, attn, g1, be1, ln1b);
  // 6. h1 = relu((ln1 @ W1) * b1) -> bf16  [XCD-chunked, 3-deep]
  mfma_gemm<1,1><<<32 * 32, 256, 0, stream>>>(ln1b, W1T, b1,
                                              nullptr, h1b, M_TOK, FF, H);
  // 7. y = ln1 + (h1 @ W2)*b2  [intra-block split-K, on-chip merge, fused res]
  mfma_ffn2<<<256, 512, 0, stream>>>(h1b, W2T, ln1b, b2, Yb);
  // 8. out = LN(y)
  ln_only<<<M_TOK, 256, 0, stream>>>(Yb, g2, be2, out);
}

// Round 10
// 260.858 us; speedup vs baseline: 1.3753x; 1.0284x over previous
//
#include <hip/hip_runtime.h>
#include <math.h>

// Sizes (fixed for this problem)
#define B 2
#define T 2048
#define H 1024
#define NH 16
#define HD 64
#define FF 4096
#define M_TOK (B*T)          // 4096 token rows
#define LOG2E 1.4426950408889634f

typedef unsigned short u16;
typedef __attribute__((ext_vector_type(8))) short bf16x8;
typedef __attribute__((ext_vector_type(4))) float f32x4;

// counted-vmcnt barrier: wait until only N of this wave's vmem ops remain,
// then workgroup barrier. Single asm with "memory" clobber so no memory op
// (gload_lds / ds_read) is reordered across it.
// NOTE (r8-r10 lesson): counted-vmcnt pipelines are only safe when EVERY
// LDS buffer is >=3 slots deep (overwrite target >=2 iterations stale).
// NOTE (R2 lesson): direct-to-register global V loads regress badly.
// NOTE (R3 lesson): split partials merge ON-CHIP; never small-granule
// scattered fp32 partials through global (write-amp + L2 eviction).
// NOTE (R4 lesson): 32-key KV tiles break the V bank-swizzle; R1 attention
// shape (8 waves x 16 rows, 64-key tiles, 72KB, 3-deep) is the optimum.
// NOTE (R6 lesson): WORKSPACE LIFETIME AUDIT before moving any launch.
// NOTE (R9): qkv GEMM columns PRE-PERMUTED to head-major (k*1024+h*64+d)
// via the WqT row permutation -> epilogue writes Q/K/V directly (fused
// repack, fp32 qkv intermediate + repack kernel deleted, ~100MB saved).
// NOTE (R10): V-class blocks transpose on-chip in the epilogue (staging
// LDS is free after the K-loop) and write VT directly -> vtrans kernel
// and Vb buffer deleted (−16.8MB round-trip, −1 launch).
#define WAITBAR3  asm volatile("s_waitcnt vmcnt(3)\n\ts_barrier" ::: "memory")
#define WAITBAR4  asm volatile("s_waitcnt vmcnt(4)\n\ts_barrier" ::: "memory")
#define WAITBAR0  asm volatile("s_waitcnt vmcnt(0)\n\ts_barrier" ::: "memory")

__device__ __forceinline__ u16 f2bf(float f) {
  union { float f; unsigned u; } v; v.f = f;
  const unsigned r = (v.u + 0x7FFFu + ((v.u >> 16) & 1u)) >> 16;
  return (u16)r;
}
__device__ __forceinline__ float bf2f(u16 h) {
  union { unsigned u; float f; } v; v.u = ((unsigned)h) << 16;
  return v.f;
}
__device__ __forceinline__ unsigned cvt_pk_bf16(float lo, float hi) {
  unsigned r;
  asm("v_cvt_pk_bf16_f32 %0, %1, %2" : "=v"(r) : "v"(lo), "v"(hi));
  return r;
}
__device__ __forceinline__ float m3(float a, float b, float c) {
  return fmaxf(fmaxf(a, b), c);      // clang fuses to v_max3_f32
}
// async global->LDS, 16B per lane; dest = wave-uniform base + lane*16
__device__ __forceinline__ void gload16(const u16* g, u16* l) {
  __builtin_amdgcn_global_load_lds(
      (const __attribute__((address_space(1))) unsigned int*)g,
      (__attribute__((address_space(3))) unsigned int*)l, 16, 0, 0);
}

// head-major column permutation: orig col c (= d*48 + k*16 + h) ->
// col' = k*1024 + h*64 + d
__device__ __forceinline__ int colperm(int c) {
  const int d = c / 48;
  const int rem = c - d * 48;
  return ((rem >> 4) << 10) | ((rem & 15) << 6) | d;
}

// ---------------------------------------------------------------------------
// preprocess — ONE launch for all input-only work:
//   bid <  4096 : split x -> bf16 hi/lo (Dekker split)
//   bid <  4864 : Wqkv^T hi/lo bf16, output ROWS PERMUTED head-major (R9)
//   bid <  5888 : W1^T bf16 (64x16)
//   bid <  6912 : W2^T bf16 (16x64)
//   bid == 6912 : bqkv head-major permutation
// ---------------------------------------------------------------------------
__global__ __launch_bounds__(256) void preprocess(
    const float* __restrict__ x, u16* __restrict__ xh, u16* __restrict__ xl,
    const float* __restrict__ Wqkv, u16* __restrict__ WqTh, u16* __restrict__ WqTl,
    const float* __restrict__ W1_, u16* __restrict__ W1T_,
    const float* __restrict__ W2_, u16* __restrict__ W2T_,
    const float* __restrict__ bqkv, float* __restrict__ bqkvP)
{
  const int bid = blockIdx.x;
  const int tid = threadIdx.x;
  if (bid == 6912) {                      // ---- bias permute ----
#pragma unroll
    for (int it = 0; it < 12; ++it) {
      const int c = it * 256 + tid;
      bqkvP[colperm(c)] = bqkv[c];
    }
    return;
  }
  if (bid < 4096) {                       // ---- split_hl ----
    const size_t i = ((size_t)bid * 256 + tid) * 4;
    const float4 v = *(const float4*)(x + i);
    union { u16 s[4]; uint2 u; } h, l;
    const float f[4] = {v.x, v.y, v.z, v.w};
#pragma unroll
    for (int j = 0; j < 4; ++j) {
      const u16 hb = f2bf(f[j]); h.s[j] = hb; l.s[j] = f2bf(f[j] - bf2f(hb));
    }
    *(uint2*)(xh + i) = h.u;
    *(uint2*)(xl + i) = l.u;
    return;
  }
  // ---- transpose-convert paths (uniform per block) ----
  __shared__ float tile[64][69];
  const float* in; u16* oh; u16* ol = nullptr;
  int K, N, k0, n0, split = 0, permq = 0;
  if (bid < 4864) {
    const int tb = bid - 4096;
    in = Wqkv; oh = WqTh; ol = WqTl; K = H; N = 3*H; split = 1; permq = 1;
    n0 = (tb % 48) * 64; k0 = (tb / 48) * 64;
  } else if (bid < 5888) {
    const int tb = bid - 4864;
    in = W1_; oh = W1T_; K = H; N = FF;
    n0 = (tb & 63) * 64; k0 = (tb >> 6) * 64;
  } else {
    const int tb = bid - 5888;
    in = W2_; oh = W2T_; K = FF; N = H;
    n0 = (tb & 15) * 64; k0 = (tb >> 4) * 64;
  }
  const int r = tid >> 4, c4 = (tid & 15) * 4;
#pragma unroll
  for (int i = 0; i < 4; ++i) {
    const float4 v = *(const float4*)(in + (size_t)(k0 + i*16 + r) * N + n0 + c4);
    tile[i*16+r][c4]   = v.x; tile[i*16+r][c4+1] = v.y;
    tile[i*16+r][c4+2] = v.z; tile[i*16+r][c4+3] = v.w;
  }
  __syncthreads();
  const int n = tid >> 2, kq = tid & 3;
  union { u16 s[8]; int4 v; } ph0, ph1, pl0, pl1;
#pragma unroll
  for (int j = 0; j < 8; ++j) {
    const float f0 = tile[kq*16 + j][n];
    const float f1 = tile[kq*16 + 8 + j][n];
    const u16 h0 = f2bf(f0), h1 = f2bf(f1);
    ph0.s[j] = h0; ph1.s[j] = h1;
    if (split) { pl0.s[j] = f2bf(f0 - bf2f(h0)); pl1.s[j] = f2bf(f1 - bf2f(h1)); }
  }
  int orow = n0 + n;
  if (permq) orow = colperm(orow);        // head-major output row (R9)
  u16* po = oh + (size_t)orow * K + k0 + kq * 16;
  *(int4*)po = ph0.v; *(int4*)(po + 8) = ph1.v;
  if (split) {
    u16* pl = ol + (size_t)orow * K + k0 + kq * 16;
    *(int4*)pl = pl0.v; *(int4*)(pl + 8) = pl1.v;
  }
}

// ---------------------------------------------------------------------------
// MFMA GEMM (FFN1 use): C = relu((A @ B^T) * bias) -> bf16.
// 128x128 tile, BK=32, global_load_lds staging, XCD-chunked 1-D grid.
// DEEP3: 3-slot LDS ring + counted vmcnt(4) barriers. 48KB.
// ---------------------------------------------------------------------------
__device__ __forceinline__ int swz(int r, int kq) {
  return r * 32 + ((kq ^ ((r >> 1) & 3)) * 8);
}

template<int RELU, int OBF>
__global__ __launch_bounds__(256) void mfma_gemm(
    const u16* __restrict__ Ah, const u16* __restrict__ Bh,
    const float* __restrict__ bias,
    float* __restrict__ Cf, u16* __restrict__ Cb,
    int M, int N, int K)
{
  __shared__ u16 lds[24576];
  const int tid = threadIdx.x;
  const int bid = blockIdx.x;
  const int xcd = bid & 7;
  const int idx = bid >> 3;
  const int row0 = (xcd * 4 + (idx & 3)) * 128;
  const int col0 = (idx >> 2) * 128;
  const int wv = tid >> 6, lane = tid & 63;
  const int wr = wv >> 1, wc = wv & 1;
  const int kq = lane >> 4, fr = lane & 15;

  f32x4 acc[4][4] = {};

#define GSTAGE(lbase, gb, rowbase, kk) do { \
    _Pragma("unroll") \
    for (int t_ = 0; t_ < 2; ++t_) { \
      const int c_ = wv * 2 + t_; \
      const int idx_ = c_ * 64 + lane; \
      const int r_ = idx_ >> 2; \
      const int kq_ = (idx_ & 3) ^ ((r_ >> 1) & 3); \
      gload16((gb) + (size_t)((rowbase) + r_) * K + (kk) + kq_ * 8, \
              &lds[(lbase) + c_ * 512]); \
    } } while (0)

  const int nk = K >> 5;
  GSTAGE(0, Ah, row0, 0);            GSTAGE(4096, Bh, col0, 0);
  GSTAGE(8192, Ah, row0, 32);        GSTAGE(8192 + 4096, Bh, col0, 32);
  WAITBAR4;                            // stage 0 ready; stage 1 in flight
  int cslot = 0, islot = 2;
  for (int i = 0; i < nk; ++i) {
    if (i + 2 < nk) {
      const int kk = (i + 2) * 32;
      GSTAGE(islot * 8192, Ah, row0, kk);
      GSTAGE(islot * 8192 + 4096, Bh, col0, kk);
      islot = (islot == 2) ? 0 : islot + 1;
    }
    const int rb = cslot * 8192;
    bf16x8 a_h[4];
#pragma unroll
    for (int m = 0; m < 4; ++m)
      a_h[m] = *(const bf16x8*)&lds[rb + swz(wr*64 + m*16 + fr, kq)];
#pragma unroll
    for (int n = 0; n < 4; ++n) {
      const bf16x8 b_h = *(const bf16x8*)&lds[rb + 4096 + swz(wc*64 + n*16 + fr, kq)];
#pragma unroll
      for (int m = 0; m < 4; ++m)
        acc[m][n] = __builtin_amdgcn_mfma_f32_16x16x32_bf16(a_h[m], b_h, acc[m][n], 0, 0, 0);
    }
    cslot = (cslot == 2) ? 0 : cslot + 1;
    if (i + 1 < nk) { if (i + 2 < nk) WAITBAR4; else WAITBAR0; }
  }
#undef GSTAGE

  const int orow0 = row0 + wr * 64, ocol0 = col0 + wc * 64;
#pragma unroll
  for (int n = 0; n < 4; ++n) {
    const int col = ocol0 + n * 16 + fr;
    const float bs = bias[col];
#pragma unroll
    for (int m = 0; m < 4; ++m) {
      const int rbase = orow0 + m * 16 + kq * 4;
#pragma unroll
      for (int j = 0; j < 4; ++j) {
        float v = acc[m][n][j] * bs;
        if (RELU) v = fmaxf(v, 0.0f);
        const size_t off = (size_t)(rbase + j) * N + col;
        if (OBF) Cb[off] = f2bf(v); else Cf[off] = v;
      }
    }
  }
}

// ---------------------------------------------------------------------------
// QKV GEMM with FUSED REPACK (R9) + FUSED V-TRANSPOSE (R10).
// Columns head-major permuted (col' = k*1024+h*64+d), so each 128-col block
// is pure Q, K or V. SPLIT hi/lo 3-term for Q/K; V blocks are plain hi*hi
// and skip ALL lo staging. 2-phase double-buffer (64KB LDS, 2 blocks/CU).
// Epilogue: Q/K apply bias (+qscale), Dekker-split, write [bh][T][HD].
// V: transpose on-chip (staging LDS reused, [128][132] u16 padded tile)
// and write VT [bh][HD][T] directly — each thread emits one full 128B line.
// Arithmetic order identical to old GEMM+repack -> bit-identical outputs.
// ---------------------------------------------------------------------------
__global__ __launch_bounds__(256) void mfma_qkv(
    const u16* __restrict__ Ah, const u16* __restrict__ Al,
    const u16* __restrict__ Bh, const u16* __restrict__ Bl,
    const float* __restrict__ biasP,
    u16* __restrict__ Qh, u16* __restrict__ Ql,
    u16* __restrict__ Kh, u16* __restrict__ Kl, u16* __restrict__ VT)
{
  const int K = H;
  __shared__ u16 lds[32768];
  const int tid = threadIdx.x;
  const int bid = blockIdx.x;            // 768 = 8 xcd x 4 rowchunk x 24 col
  const int xcd = bid & 7;
  const int idx = bid >> 3;
  const int row0 = (xcd * 4 + (idx & 3)) * 128;
  const int col0 = (idx >> 2) * 128;     // col' base, [0, 3072)
  const int wv = tid >> 6, lane = tid & 63;
  const int wr = wv >> 1, wc = wv & 1;
  const int kq = lane >> 4, fr = lane & 15;
  const bool isV = (col0 >= 2048);       // block-uniform class (R9)

  f32x4 acc[4][4] = {};

#define QSTAGE(lbase, gb, rowbase, kk) do { \
    _Pragma("unroll") \
    for (int t_ = 0; t_ < 2; ++t_) { \
      const int c_ = wv * 2 + t_; \
      const int idx_ = c_ * 64 + lane; \
      const int r_ = idx_ >> 2; \
      const int kq_ = (idx_ & 3) ^ ((r_ >> 1) & 3); \
      gload16((gb) + (size_t)((rowbase) + r_) * K + (kk) + kq_ * 8, \
              &lds[(lbase) + c_ * 512]); \
    } } while (0)

  QSTAGE(0, Ah, row0, 0);
  QSTAGE(4096, Bh, col0, 0);
  if (!isV) { QSTAGE(8192, Al, row0, 0); QSTAGE(12288, Bl, col0, 0); }
  __syncthreads();

  int cur = 0;
  for (int k0 = 0; k0 < K; k0 += 32) {
    const int nxt = cur ^ 1;
    if (k0 + 32 < K) {
      QSTAGE(nxt*16384, Ah, row0, k0 + 32);
      QSTAGE(nxt*16384 + 4096, Bh, col0, k0 + 32);
      if (!isV) { QSTAGE(nxt*16384 + 8192, Al, row0, k0 + 32);
                  QSTAGE(nxt*16384 + 12288, Bl, col0, k0 + 32); }
    }
    const int rb = cur * 16384;
    bf16x8 a_h[4], a_l[4];
#pragma unroll
    for (int m = 0; m < 4; ++m) {
      a_h[m] = *(const bf16x8*)&lds[rb + swz(wr*64 + m*16 + fr, kq)];
      if (!isV) a_l[m] = *(const bf16x8*)&lds[rb + 8192 + swz(wr*64 + m*16 + fr, kq)];
    }
#pragma unroll
    for (int n = 0; n < 4; ++n) {
      const bf16x8 b_h = *(const bf16x8*)&lds[rb + 4096 + swz(wc*64 + n*16 + fr, kq)];
#pragma unroll
      for (int m = 0; m < 4; ++m)
        acc[m][n] = __builtin_amdgcn_mfma_f32_16x16x32_bf16(a_h[m], b_h, acc[m][n], 0, 0, 0);
      if (!isV) {
        const bf16x8 b_l = *(const bf16x8*)&lds[rb + 12288 + swz(wc*64 + n*16 + fr, kq)];
#pragma unroll
        for (int m = 0; m < 4; ++m) {
          acc[m][n] = __builtin_amdgcn_mfma_f32_16x16x32_bf16(a_h[m], b_l, acc[m][n], 0, 0, 0);
          acc[m][n] = __builtin_amdgcn_mfma_f32_16x16x32_bf16(a_l[m], b_h, acc[m][n], 0, 0, 0);
        }
      }
    }
    __syncthreads();
    cur = nxt;
  }
#undef QSTAGE

  const float qscale = LOG2E / 32.0f;
  const int orow0 = row0 + wr * 64, ocol0 = col0 + wc * 64;
  const int kcls = col0 >> 10;           // 0=Q, 1=K, 2=V (uniform)

  if (kcls == 2) {
    // ---- V: on-chip transpose epilogue (R10). Staging LDS is free after
    // the loop's final __syncthreads. Tile [dc:128][tr:132-pad] u16 (33KB).
#pragma unroll
    for (int n = 0; n < 4; ++n) {
      const int dc = wc * 64 + n * 16 + fr;          // block-local col
      const float bs = biasP[ocol0 + n * 16 + fr];
#pragma unroll
      for (int m = 0; m < 4; ++m) {
        const int trb = wr * 64 + m * 16 + kq * 4;   // block-local row
#pragma unroll
        for (int j = 0; j < 4; ++j)
          lds[dc * 132 + trb + j] = f2bf(acc[m][n][j] * bs);
      }
    }
    __syncthreads();
    // each thread emits one full 128B VT line: d-row dr_, t-half half
    const int dr_ = tid >> 1, half = tid & 1;
    const int hh = ((col0 >> 6) & 15) + (dr_ >> 6);
    const int d = dr_ & 63;
    const int b = row0 >> 11, t0r = row0 & (T - 1);
    u16* dstp = VT + (((size_t)(b * NH + hh)) * HD + d) * T + t0r + half * 64;
    const int sbase = dr_ * 132 + half * 64;
#pragma unroll
    for (int q = 0; q < 8; ++q) {
      union { uint2 u2[2]; int4 v; } pkv;
      pkv.u2[0] = *(const uint2*)&lds[sbase + q * 8];
      pkv.u2[1] = *(const uint2*)&lds[sbase + q * 8 + 4];
      *(int4*)(dstp + q * 8) = pkv.v;
    }
    return;
  }

  // ---- Q/K: fused repack epilogue; lanes fr = 16 consecutive d.
#pragma unroll
  for (int n = 0; n < 4; ++n) {
    const int colp = ocol0 + n * 16 + fr;
    const int d = colp & 63, hh = (colp >> 6) & 15;
    const float bs = biasP[colp];
#pragma unroll
    for (int m = 0; m < 4; ++m) {
      const int rbase = orow0 + m * 16 + kq * 4;
#pragma unroll
      for (int j = 0; j < 4; ++j) {
        const int row = rbase + j;
        const int b = row >> 11, t = row & (T - 1);
        const size_t dst = (((size_t)(b * NH + hh)) * T + t) * HD + d;
        float v = acc[m][n][j] * bs;
        if (kcls == 0) {
          v *= qscale;
          const u16 hb = f2bf(v);
          Qh[dst] = hb; Ql[dst] = f2bf(v - bf2f(hb));
        } else {
          const u16 hb = f2bf(v);
          Kh[dst] = hb; Kl[dst] = f2bf(v - bf2f(hb));
        }
      }
    }
  }
}

// ---------------------------------------------------------------------------
// FFN2 with INTRA-BLOCK split-K (R8): y = ln1 + (h1 @ W2) * b2, fp32.
// 512 threads = 2 groups x 4 waves; group g runs the DEEP3 counted-vmcnt
// ring over K-half in its own 48KB LDS region (96KB total, 1 block/CU).
// Merge: group1 dumps acc to LDS, group0 adds + fuses ln1 residual + bias.
// ---------------------------------------------------------------------------
__global__ __launch_bounds__(512, 2) void mfma_ffn2(
    const u16* __restrict__ Ah, const u16* __restrict__ Bh,
    const u16* __restrict__ Res, const float* __restrict__ bias,
    float* __restrict__ Y)
{
  const int N = H, K = FF;
  __shared__ u16 lds[2 * 24576];        // 96KB: per-group 3-slot ring
  const int tid = threadIdx.x;
  const int bid = blockIdx.x;           // 256 blocks
  const int xcd = bid & 7;
  const int idx = bid >> 3;             // [0,32)
  const int row0 = (xcd * 4 + (idx & 3)) * 128;
  const int col0 = (idx >> 2) * 128;    // [0, 1024)
  const int wv8 = tid >> 6, lane = tid & 63;
  const int grp = wv8 >> 2, wv = wv8 & 3;
  const int wr = wv >> 1, wc = wv & 1;
  const int kq = lane >> 4, fr = lane & 15;
  const int kb = grp * (K >> 1);
  u16* gl = &lds[grp * 24576];

  f32x4 acc[4][4] = {};

#define GSTAGE2(lbase, gb, rowbase, kk) do { \
    _Pragma("unroll") \
    for (int t_ = 0; t_ < 2; ++t_) { \
      const int c_ = wv * 2 + t_; \
      const int idx_ = c_ * 64 + lane; \
      const int r_ = idx_ >> 2; \
      const int kq_ = (idx_ & 3) ^ ((r_ >> 1) & 3); \
      gload16((gb) + (size_t)((rowbase) + r_) * K + (kk) + kq_ * 8, \
              &gl[(lbase) + c_ * 512]); \
    } } while (0)

  const int nk = (K >> 1) >> 5;         // 64 steps per group
  GSTAGE2(0, Ah, row0, kb);            GSTAGE2(4096, Bh, col0, kb);
  GSTAGE2(8192, Ah, row0, kb + 32);    GSTAGE2(8192 + 4096, Bh, col0, kb + 32);
  WAITBAR4;
  int cslot = 0, islot = 2;
  for (int i = 0; i < nk; ++i) {
    if (i + 2 < nk) {
      const int kk = kb + (i + 2) * 32;
      GSTAGE2(islot * 8192, Ah, row0, kk);
      GSTAGE2(islot * 8192 + 4096, Bh, col0, kk);
      islot = (islot == 2) ? 0 : islot + 1;
    }
    const int rb = cslot * 8192;
    bf16x8 a_h[4];
#pragma unroll
    for (int m = 0; m < 4; ++m)
      a_h[m] = *(const bf16x8*)&gl[rb + swz(wr*64 + m*16 + fr, kq)];
#pragma unroll
    for (int n = 0; n < 4; ++n) {
      const bf16x8 b_h = *(const bf16x8*)&gl[rb + 4096 + swz(wc*64 + n*16 + fr, kq)];
#pragma unroll
      for (int m = 0; m < 4; ++m)
        acc[m][n] = __builtin_amdgcn_mfma_f32_16x16x32_bf16(a_h[m], b_h, acc[m][n], 0, 0, 0);
    }
    cslot = (cslot == 2) ? 0 : cslot + 1;
    if (i + 1 < nk) { if (i + 2 < nk) WAITBAR4; else WAITBAR0; }
  }
#undef GSTAGE2

  // ---- on-chip merge + fused residual epilogue ----
  __syncthreads();                      // all ring reads done (drains cnts)
  float* fm = (float*)lds;              // 24576 floats available
  const int base = wv * 4096;           // 16KB per wave-pair region
  if (grp == 1) {
#pragma unroll
    for (int m = 0; m < 4; ++m)
#pragma unroll
      for (int n = 0; n < 4; ++n)
        *(f32x4*)&fm[base + (m*4 + n)*256 + lane*4] = acc[m][n];
  }
  __syncthreads();
  if (grp == 0) {
    const int orow0 = row0 + wr * 64, ocol0 = col0 + wc * 64;
#pragma unroll
    for (int n = 0; n < 4; ++n) {
      const int col = ocol0 + n * 16 + fr;
      const float bs = bias[col];
#pragma unroll
      for (int m = 0; m < 4; ++m) {
        const f32x4 ob = *(const f32x4*)&fm[base + (m*4 + n)*256 + lane*4];
        const int rbase = orow0 + m * 16 + kq * 4;
#pragma unroll
        for (int j = 0; j < 4; ++j) {
          const size_t off = (size_t)(rbase + j) * N + col;
          Y[off] = bf2f(Res[off]) + (acc[m][n][j] + ob[j]) * bs;
        }
      }
    }
  }
}

// ---------------------------------------------------------------------------
// sigma: LDS K-row r holds key sigma(r) so that the QK^T C-layout hands each
// lane exactly the 8-consecutive-key fragments PV's B-operand needs.
// ---------------------------------------------------------------------------
__device__ __forceinline__ int sigma_k(int r) {
  return ((r >> 5) << 5) | (((r >> 2) & 3) << 3) | (((r >> 4) & 1) << 2) | (r & 3);
}

// ---------------------------------------------------------------------------
// MFMA flash attention, swapped-operand. 8 waves x 16 q-rows (512 threads),
// KV tile 64. K hi/lo + VT staged in LDS, 3-deep counted-vmcnt pipeline
// (24KB/slot, 72KB total). XCD-clustered grid; defer-max (THR=8); lsum via
// ones-A MFMA; setprio around MFMA clusters.
// 72KB LDS x 2 blocks/CU = 144KB <= 160KB -> 16 waves/CU (4/SIMD).
// VERIFIED 93us configuration (R1/R5).
// ---------------------------------------------------------------------------
__global__ __launch_bounds__(512, 4) void flash_attn_mfma(
    const u16* __restrict__ Qh, const u16* __restrict__ Ql,
    const u16* __restrict__ Kh, const u16* __restrict__ Kl,
    const u16* __restrict__ VT, float* __restrict__ Out)
{
  __shared__ u16 sm[3 * 12288];  // slot: KH [0,4K) | KL [4K,8K) | VT [8K,12K) u16
  // XCD-clustered decode: xcd = i&7 owns heads 4*xcd..4*xcd+3
  const int i = blockIdx.x;
  const int slot = i >> 3;
  const int bh = (i & 7) * 4 + (slot >> 4);
  const int row0 = (slot & 15) * 128;
  const int b = bh >> 4, h = bh & 15;
  const int tid = threadIdx.x, wave = tid >> 6, lane = tid & 63;
  const int fr = lane & 15, kq = lane >> 4;

  // Q fragments (B-operand: col=q=fr, k=d=kq*8 within ks*32); wave owns
  // q-rows [row0 + wave*16, +16)
  bf16x8 qh[2], ql[2];
  const size_t qoff = ((size_t)bh * T + row0 + wave*16 + fr) * HD + kq*8;
#pragma unroll
  for (int ks = 0; ks < 2; ++ks) {
    qh[ks] = *(const bf16x8*)(Qh + qoff + ks*32);
    ql[ks] = *(const bf16x8*)(Ql + qoff + ks*32);
  }

  bf16x8 ones8;
#pragma unroll
  for (int z = 0; z < 8; ++z) ones8[z] = (short)0x3F80;

  f32x4 o[4] = {};
  f32x4 oex = {};                      // lsum accumulator (all 4 rows equal)
  float m_ = -1e30f;

  // staging: wave w stages chunk w (1KB) of each of the 3 arrays (8 waves
  // cover the 8 chunks). Global pointers advance by a constant per KV tile.
  const int c_ = wave;
  const int r0_ = c_ * 8 + (lane >> 3), s_ = lane & 7;
  const int cd0 = s_ ^ (r0_ & 7);
  const int k0_ = sigma_k(r0_);
  const u16* pKh0 = Kh + ((size_t)bh*T + k0_)*HD + cd0*8;
  const u16* pKl0 = Kl + ((size_t)bh*T + k0_)*HD + cd0*8;
  const u16* pV0  = VT + ((size_t)bh*HD + r0_)*T + cd0*8;

#define FSTAGE(sb) do { \
    gload16(pKh0, &sm[(sb) + c_*512]); \
    gload16(pKl0, &sm[(sb) + 4096 + c_*512]); \
    gload16(pV0,  &sm[(sb) + 8192 + c_*512]); \
    pKh0 += 64*HD; pKl0 += 64*HD; pV0 += 64; \
  } while (0)

  FSTAGE(0);
  FSTAGE(12288);
  WAITBAR3;                  // tile 0 ready (3 loads/wave); tile 1 in flight
  int cslot = 0, islot = 2;

  const int NT = T / 64;
  for (int t = 0; t < NT; ++t) {
    if (t + 2 < NT) {
      FSTAGE(islot * 12288);
      islot = (islot == 2) ? 0 : islot + 1;
    }
    const u16* smb = &sm[cslot * 12288];

    // ---- QK^T (swapped): s[n], keys sigma(16n+4kq+jj), q=fr
    f32x4 s[4] = {};
    __builtin_amdgcn_s_setprio(1);
#pragma unroll
    for (int ks = 0; ks < 2; ++ks) {
#pragma unroll
      for (int n = 0; n < 4; ++n) {
        const int kr = n * 16 + fr;
        const int sl = ((ks*4 + kq) ^ (kr & 7)) * 8;
        const bf16x8 kh_ = *(const bf16x8*)&smb[kr*64 + sl];
        const bf16x8 kl_ = *(const bf16x8*)&smb[4096 + kr*64 + sl];
        s[n] = __builtin_amdgcn_mfma_f32_16x16x32_bf16(kh_, qh[ks], s[n], 0, 0, 0);
        s[n] = __builtin_amdgcn_mfma_f32_16x16x32_bf16(kl_, qh[ks], s[n], 0, 0, 0);
        s[n] = __builtin_amdgcn_mfma_f32_16x16x32_bf16(kh_, ql[ks], s[n], 0, 0, 0);
      }
    }
    __builtin_amdgcn_s_setprio(0);

    // ---- defer-max softmax (THR=8)
    const float g0 = m3(s[0][0], s[0][1], s[0][2]);
    const float g1 = m3(s[0][3], s[1][0], s[1][1]);
    const float g2 = m3(s[1][2], s[1][3], s[2][0]);
    const float g3 = m3(s[2][1], s[2][2], s[2][3]);
    const float g4 = m3(s[3][0], s[3][1], s[3][2]);
    float mx = fmaxf(m3(g0, g1, g2), m3(g3, g4, s[3][3]));
    mx = fmaxf(mx, __shfl_xor(mx, 16));
    mx = fmaxf(mx, __shfl_xor(mx, 32));
    if (!__all(mx <= m_ + 8.0f)) {      // record tile (~10%): rescale
      const float mn = fmaxf(m_, mx);
      const float fsc = exp2f(m_ - mn);
      m_ = mn;
#pragma unroll
      for (int n = 0; n < 4; ++n) {
        o[n][0] *= fsc; o[n][1] *= fsc;
        o[n][2] *= fsc; o[n][3] *= fsc;
      }
      oex[0] *= fsc; oex[1] *= fsc; oex[2] *= fsc; oex[3] *= fsc;
    }

    float p[4][4];
#pragma unroll
    for (int n = 0; n < 4; ++n)
#pragma unroll
      for (int jj = 0; jj < 4; ++jj)
        p[n][jj] = exp2f(s[n][jj] - m_);

    unsigned pk[4][2];
#pragma unroll
    for (int n = 0; n < 4; ++n) {
      pk[n][0] = cvt_pk_bf16(p[n][0], p[n][1]);
      pk[n][1] = cvt_pk_bf16(p[n][2], p[n][3]);
    }

    // ---- in-reg P -> PV (+ lsum MFMA); V^T fragments from LDS
    __builtin_amdgcn_s_setprio(1);
#pragma unroll
    for (int ks = 0; ks < 2; ++ks) {
      union { unsigned u[4]; bf16x8 v; } pb;
      pb.u[0] = pk[2*ks][0];   pb.u[1] = pk[2*ks][1];
      pb.u[2] = pk[2*ks+1][0]; pb.u[3] = pk[2*ks+1][1];
#pragma unroll
      for (int n = 0; n < 4; ++n) {
        const int dr = n * 16 + fr;
        const bf16x8 vf = *(const bf16x8*)&smb[8192 + dr*64 + (((ks*4 + kq) ^ (dr & 7)) * 8)];
        o[n] = __builtin_amdgcn_mfma_f32_16x16x32_bf16(vf, pb.v, o[n], 0, 0, 0);
      }
      oex = __builtin_amdgcn_mfma_f32_16x16x32_bf16(ones8, pb.v, oex, 0, 0, 0);
    }
    __builtin_amdgcn_s_setprio(0);

    cslot = (cslot == 2) ? 0 : cslot + 1;
    if (t + 1 < NT) { if (t + 2 < NT) WAITBAR3; else WAITBAR0; }
  }
#undef FSTAGE

  // ---- epilogue: O^T frag has q=fr, d = 16n + 4kq + jj (jj contiguous)
  {
    const float inv = 1.0f / oex[0];
    const size_t qrow = (size_t)b * T + row0 + wave*16 + fr;
#pragma unroll
    for (int n = 0; n < 4; ++n) {
      float4 ov;
      ov.x = o[n][0] * inv; ov.y = o[n][1] * inv;
      ov.z = o[n][2] * inv; ov.w = o[n][3] * inv;
      *(float4*)(Out + qrow * H + h * HD + n * 16 + kq * 4) = ov;
    }
  }
}

// ---------------------------------------------------------------------------
// out_bf16 = LN(a + b) * gamma + beta; ddof=1, eps on std.
// fp32 output dropped — the downstream residual is ffn-dominated
// (|ffn|~1e3 vs |ln1|~3) so bf16 rounding perturbs the final LN ~1e-5.
// ---------------------------------------------------------------------------
__global__ __launch_bounds__(256) void ln_residual(
    const float* __restrict__ A, const float* __restrict__ Bz,
    const float* __restrict__ gamma, const float* __restrict__ beta,
    u16* __restrict__ obf)
{
  const int row = blockIdx.x, tid = threadIdx.x;
  const int wave = tid >> 6, lane = tid & 63;
  const size_t off = (size_t)row * H + tid * 4;
  const float4 av = *(const float4*)(A + off);
  const float4 bv = *(const float4*)(Bz + off);
  float4 y; y.x = av.x + bv.x; y.y = av.y + bv.y; y.z = av.z + bv.z; y.w = av.w + bv.w;
  float s  = y.x + y.y + y.z + y.w;
  float ss = y.x*y.x + y.y*y.y + y.z*y.z + y.w*y.w;
#pragma unroll
  for (int o = 32; o >= 1; o >>= 1) { s += __shfl_xor(s, o); ss += __shfl_xor(ss, o); }
  __shared__ float red[2][4];
  if (lane == 0) { red[0][wave] = s; red[1][wave] = ss; }
  __syncthreads();
  s  = red[0][0] + red[0][1] + red[0][2] + red[0][3];
  ss = red[1][0] + red[1][1] + red[1][2] + red[1][3];
  const float mean = s * (1.0f / (float)H);
  float var = (ss - (float)H * mean * mean) * (1.0f / (float)(H - 1));
  var = fmaxf(var, 0.0f);
  const float inv = 1.0f / (sqrtf(var) + 1e-6f);
  const float4 gv = *(const float4*)(gamma + tid * 4);
  const float4 be = *(const float4*)(beta + tid * 4);
  float4 o;
  o.x = gv.x * (y.x - mean) * inv + be.x;
  o.y = gv.y * (y.y - mean) * inv + be.y;
  o.z = gv.z * (y.z - mean) * inv + be.z;
  o.w = gv.w * (y.w - mean) * inv + be.w;
  union { u16 s[4]; uint2 u; } pk;
  pk.s[0] = f2bf(o.x); pk.s[1] = f2bf(o.y); pk.s[2] = f2bf(o.z); pk.s[3] = f2bf(o.w);
  *(uint2*)(obf + off) = pk.u;
}

// ---------------------------------------------------------------------------
// final LN only: out = LN(y) * gamma + beta (y already has residual+bias)
// ---------------------------------------------------------------------------
__global__ __launch_bounds__(256) void ln_only(
    const float* __restrict__ Yv,
    const float* __restrict__ gamma, const float* __restrict__ beta,
    float* __restrict__ out)
{
  const int row = blockIdx.x, tid = threadIdx.x;
  const int wave = tid >> 6, lane = tid & 63;
  const size_t off = (size_t)row * H + tid * 4;
  const float4 y = *(const float4*)(Yv + off);
  float s  = y.x + y.y + y.z + y.w;
  float ss = y.x*y.x + y.y*y.y + y.z*y.z + y.w*y.w;
#pragma unroll
  for (int o = 32; o >= 1; o >>= 1) { s += __shfl_xor(s, o); ss += __shfl_xor(ss, o); }
  __shared__ float red[2][4];
  if (lane == 0) { red[0][wave] = s; red[1][wave] = ss; }
  __syncthreads();
  s  = red[0][0] + red[0][1] + red[0][2] + red[0][3];
  ss = red[1][0] + red[1][1] + red[1][2] + red[1][3];
  const float mean = s * (1.0f / (float)H);
  float var = (ss - (float)H * mean * mean) * (1.0f / (float)(H - 1));
  var = fmaxf(var, 0.0f);
  const float inv = 1.0f / (sqrtf(var) + 1e-6f);
  const float4 gv = *(const float4*)(gamma + tid * 4);
  const float4 be = *(const float4*)(beta + tid * 4);
  float4 o;
  o.x = gv.x * (y.x - mean) * inv + be.x;
  o.y = gv.y * (y.y - mean) * inv + be.y;
  o.z = gv.z * (y.z - mean) * inv + be.z;
  o.w = gv.w * (y.w - mean) * inv + be.w;
  *(float4*)(out + off) = o;
}

// ---------------------------------------------------------------------------
extern "C" void kernel_launch(void* const* d_in, const int* in_sizes, int n_in,
                              void* d_out, int out_size, void* d_ws, size_t ws_size,
                              hipStream_t stream)
{
  const float* x    = (const float*)d_in[0];
  const float* Wqkv = (const float*)d_in[1];
  const float* bqkv = (const float*)d_in[2];
  const float* W1   = (const float*)d_in[3];
  const float* b1   = (const float*)d_in[4];
  const float* W2   = (const float*)d_in[5];
  const float* b2   = (const float*)d_in[6];
  const float* g1   = (const float*)d_in[7];
  const float* be1  = (const float*)d_in[8];
  const float* g2   = (const float*)d_in[9];
  const float* be2  = (const float*)d_in[10];
  float* out = (float*)d_out;
  char* w = (char*)d_ws;

  // ---- workspace map (bytes); lifetime-audited (R6 lesson; R10 re-audit) -
  // region              offset     size    live steps
  // Qh    bf16          0          8.39M   2-3
  // Ql    bf16          8388608    8.39M   2-3
  // Khb   bf16          16777216   8.39M   2-3
  // Klb   bf16          25165824   8.39M   2-3
  // VTb   bf16          41943040   8.39M   2-3 (written directly by qkv)
  // h1b   bf16          0          33.55M  5-6 (over Q/K dead)
  // xh    bf16          52428800   8.39M   1-2
  // xl    bf16          60817408   8.39M   1-2
  // WqTh  bf16          69206016   6.29M   1-2
  // WqTl  bf16          75497472   6.29M   1-2
  // attn  fp32          102760448  16.78M  3-4
  // Y     fp32          102760448  16.78M  6-7 (over attn dead)
  // W1T   bf16          119537664  8.39M   1-5
  // W2T   bf16          127926272  8.39M   1-6
  // ln1b  bf16          136314880  8.39M   4-7
  // bqkvP fp32          144703488  12KB    1-2
  u16*   Qh    = (u16*)  (w + 0);
  u16*   Ql    = (u16*)  (w + 8388608);
  u16*   Khb   = (u16*)  (w + 16777216);
  u16*   Klb   = (u16*)  (w + 25165824);
  u16*   VTb   = (u16*)  (w + 41943040);
  u16*   h1b   = (u16*)  (w + 0);
  u16*   xh    = (u16*)  (w + 52428800);
  u16*   xl    = (u16*)  (w + 60817408);
  u16*   WqTh  = (u16*)  (w + 69206016);
  u16*   WqTl  = (u16*)  (w + 75497472);
  float* attn  = (float*)(w + 102760448);
  float* Yb    = (float*)(w + 102760448);
  u16*   W1T   = (u16*)  (w + 119537664);
  u16*   W2T   = (u16*)  (w + 127926272);
  u16*   ln1b  = (u16*)  (w + 136314880);
  float* bqkvP = (float*)(w + 144703488);

  // 1. preprocess: split x hi/lo + Wqkv^T (head-major perm) + W1^T + W2^T
  //    + bqkv permutation — one launch
  preprocess<<<6913, 256, 0, stream>>>(x, xh, xl, Wqkv, WqTh, WqTl,
                                       W1, W1T, W2, W2T, bqkv, bqkvP);
  // 2. QKV GEMM with fused repack + fused V-transpose -> Qh/Ql/Kh/Kl/VT
  mfma_qkv<<<24 * 32, 256, 0, stream>>>(xh, xl, WqTh, WqTl, bqkvP,
                                        Qh, Ql, Khb, Klb, VTb);
  // 3. attention (MFMA, swapped-operand, XCD-clustered, 8-wave, 3-deep) — R1
  flash_attn_mfma<<<512, 512, 0, stream>>>(Qh, Ql, Khb, Klb, VTb, attn);
  // 4. ln1 = LN(x + attn) -> bf16 only
  ln_residual<<<M_TOK, 256, 0, stream>>>(x, attn, g1, be1, ln1b);
  // 5. h1 = relu((ln1 @ W1) * b1) -> bf16  [XCD-chunked, 3-deep]
  mfma_gemm<1,1><<<32 * 32, 256, 0, stream>>>(ln1b, W1T, b1,
                                              nullptr, h1b, M_TOK, FF, H);
  // 6. y = ln1 + (h1 @ W2)*b2  [intra-block split-K, on-chip merge, fused res]
  mfma_ffn2<<<256, 512, 0, stream>>>(h1b, W2T, ln1b, b2, Yb);
  // 7. out = LN(y)
  ln_only<<<M_TOK, 256, 0, stream>>>(Yb, g2, be2, out);
}